// Round 3
// baseline (818.211 us; speedup 1.0000x reference)
//
#include <hip/hip_runtime.h>
#include <hip/hip_bf16.h>
#include <type_traits>

// CombineGraph forward. B=128,S=50,D=128,NODES=40000,SAMPLE=12,NNEI=8,HOP=2.
// Round 15: R13/R14 structure, spill actually fixed. Root cause of both
// regressions: LICM hoisted 32 loop-invariant B-frags (128 VGPR) + sess
// (32 VGPR) out of the phase-A unit loop -> ~240 live regs -> scratch
// spill (R14 WRITE_SIZE 117MB). Fix: asm memory clobber at loop top pins
// those loads inside the loop (L1-hot reloads), plain launch_bounds(256).

#define B 128
#define S 50
#define D 128
#define SAMPLE 12
#define NNEI 8
#define NODES 40000
#define NSC (NODES - 1)
#define LEAK 0.2f
#define TEMPV 0.5f
#define MUV 0.1f
#define NEG_BIG -3.0e38f

typedef const float* fpp;
typedef float* fpw;
typedef unsigned short u16;
typedef __attribute__((ext_vector_type(8))) short bfrag8;
typedef __attribute__((ext_vector_type(4))) float f32x4;

__device__ __forceinline__ float sigm(float x) { return 1.f / (1.f + __expf(-x)); }
__device__ __forceinline__ float tanh_f(float x) { return 1.f - 2.f / (__expf(2.f * x) + 1.f); }
__device__ __forceinline__ float leaky(float x) { return x >= 0.f ? x : LEAK * x; }
__device__ __forceinline__ u16 f2bf(float v) {
  __hip_bfloat16 h = __float2bfloat16(v);
  return *reinterpret_cast<u16*>(&h);
}
__device__ __forceinline__ float lde(const float* p, long i) { return p[i]; }
__device__ __forceinline__ float lde(const u16* p, long i) {
  union { unsigned int u; float f; } c;
  c.u = ((unsigned int)p[i]) << 16;
  return c.f;
}
__device__ __forceinline__ float bfu(short s) {
  union { unsigned u; float f; } c;
  c.u = ((unsigned)(unsigned short)s) << 16;
  return c.f;
}

// Load one MFMA A-fragment (8 contiguous k) of emb row `row` at k-offset koff.
template <typename ET>
__device__ __forceinline__ bfrag8 load_frag(const ET* __restrict__ emb, long row, int koff) {
  if constexpr (sizeof(ET) == 2) {
    return *(const bfrag8*)(const void*)(emb + row * D + koff);
  } else {
    const float* s = (const float*)(emb + row * D + koff);
    float4 lo = *(const float4*)s;
    float4 hi = *(const float4*)(s + 4);
    bfrag8 b;
    b[0] = (short)f2bf(lo.x); b[1] = (short)f2bf(lo.y);
    b[2] = (short)f2bf(lo.z); b[3] = (short)f2bf(lo.w);
    b[4] = (short)f2bf(hi.x); b[5] = (short)f2bf(hi.y);
    b[6] = (short)f2bf(hi.z); b[7] = (short)f2bf(hi.w);
    return b;
  }
}

__device__ __forceinline__ bfrag8 scale8(bfrag8 r, float4 sa, float4 sb) {
  bfrag8 o;
  o[0] = (short)f2bf(bfu(r[0]) * sa.x); o[1] = (short)f2bf(bfu(r[1]) * sa.y);
  o[2] = (short)f2bf(bfu(r[2]) * sa.z); o[3] = (short)f2bf(bfu(r[3]) * sa.w);
  o[4] = (short)f2bf(bfu(r[4]) * sb.x); o[5] = (short)f2bf(bfu(r[5]) * sb.y);
  o[6] = (short)f2bf(bfu(r[6]) * sb.z); o[7] = (short)f2bf(bfu(r[7]) * sb.w);
  return o;
}

// ---------------------------------------------------------------------------
// KPREP_EMB: emb fp32 -> bf16 copy in ws (4 elems/thread).
__global__ __launch_bounds__(256) void kprep_emb(fpp emb, u16* __restrict__ out) {
  long i = ((long)blockIdx.x * 256 + threadIdx.x) * 4;
  if (i + 3 >= (long)NODES * D) return;
  float4 v = *(const float4*)(emb + i);
  out[i + 0] = f2bf(v.x); out[i + 1] = f2bf(v.y);
  out[i + 2] = f2bf(v.z); out[i + 3] = f2bf(v.w);
}

// ---------------------------------------------------------------------------
// KPREP4: four weight tensors -> bf16 B-fragment order.
__global__ __launch_bounds__(256) void kprep4(fpp gw1, fpp gw3,
                                              u16* __restrict__ p1a,
                                              u16* __restrict__ p1b,
                                              u16* __restrict__ p3a,
                                              u16* __restrict__ p3b) {
  int i = blockIdx.x * 256 + threadIdx.x;
  fpp W; u16* dst; int KS;
  if (i < 16384)      { W = gw1;             dst = p1a; KS = 4; }
  else if (i < 32768) { W = gw1 + 129 * 128; dst = p1b; KS = 4; i -= 16384; }
  else if (i < 65536) { W = gw3;             dst = p3a; KS = 8; i -= 32768; }
  else                { W = gw3 + 256 * 128; dst = p3b; KS = 8; i -= 65536; }
  int e = i & 7;
  int lane = (i >> 3) & 63;
  int rest = i >> 9;
  int ks = rest % KS, nt = rest / KS;
  int k = ks * 32 + ((lane >> 4) << 3) + e;
  int n = (nt << 4) + (lane & 15);
  dst[i] = f2bf(W[(long)k * 128 + n]);
}

// ---------------------------------------------------------------------------
// K1: h = emb[inputs]; hf1/hf2 pools; attr gate. Block per (b,s), 128 thr.
template <typename ET>
__global__ __launch_bounds__(128) void k1_gather(
    const int* __restrict__ inputs, const int* __restrict__ as0,
    const int* __restrict__ as1, const int* __restrict__ ss0,
    const int* __restrict__ ss1, const ET* __restrict__ emb, fpp attr_w,
    fpw h, fpw hf1, fpw hf2, float* __restrict__ mi, fpw xA, fpw mir) {
  int bs = blockIdx.x;
  int d = threadIdx.x;
  __shared__ float h_s[D], hf1_s[D];
  int inp = inputs[bs];
  float hv = lde(emb, (long)inp * D + d);
  const int* lists[4] = {as0, as1, ss0, ss1};
  float p[4];
#pragma unroll
  for (int l = 0; l < 4; l++) {
    float sum = 0.f, cnt = 0.f;
    const int* L = lists[l] + (long)bs * NNEI;
#pragma unroll
    for (int n = 0; n < NNEI; n++) {
      int idx = L[n];
      if (idx != 0) { sum += lde(emb, (long)idx * D + d); cnt += 1.f; }
    }
    p[l] = sum / (cnt + 1e-8f);
  }
  float hf1v = 0.5f * (p[0] + p[1]);
  float hf2v = 0.5f * (p[2] + p[3]);
  h_s[d] = hv;
  hf1_s[d] = hf1v;
  __syncthreads();
  float acc = 0.f;
  for (int k = 0; k < D; k++)
    acc += h_s[k] * attr_w[(long)k * D + d] + hf1_s[k] * attr_w[(long)(D + k) * D + d];
  float g = sigm(acc);
  float hfv = g * hv + (1.f - g) * hf1v;
  long o = (long)bs * D + d;
  h[o] = hv; hf1[o] = hf1v; hf2[o] = hf2v; xA[o] = hv; mir[o] = hfv;
  if (d == 0) mi[bs] = (inp != 0) ? 1.f : 0.f;
}

// ---------------------------------------------------------------------------
// K2: sess[b,:] = sum_s emb[item[b,s]]*mi / sum_s mi
__global__ __launch_bounds__(128) void k2_sess(const int* __restrict__ inputs,
                                               const int* __restrict__ item,
                                               fpp emb, fpw sess) {
  int b = blockIdx.x;
  int d = threadIdx.x;
  float acc = 0.f, ms = 0.f;
  for (int s = 0; s < S; s++) {
    int inp = inputs[b * S + s];
    float m = (inp != 0) ? 1.f : 0.f;
    int it = item[b * S + s];
    acc += emb[(long)it * D + d] * m;
    ms += m;
  }
  sess[(long)b * D + d] = acc / ms;
}

// ---------------------------------------------------------------------------
// KG: 2-hop global branch — 256 thr / 4 waves, units processed in parallel.
// Phase A: wave w owns units {w, w+4, w+8, (w+12)}; per unit: A-frags loaded
// direct from global into registers, MFMA over all 8 col-tiles, in-wave shfl
// reductions + softmax, agg via per-wave LDS scratch. asm memory clobber at
// loop top prevents LICM from hoisting 160 VGPRs of loop-invariant loads.
template <typename ET>
__global__ __launch_bounds__(256) void kG_global(
    const int* __restrict__ inputs, const int* __restrict__ adj_all,
    fpp num, const ET* __restrict__ emb, fpp sess,
    fpp W1a, fpp W2a, fpp W1b, fpp W2b, fpp W3b,
    const u16* __restrict__ p1a, const u16* __restrict__ p1b,
    const u16* __restrict__ p3a, fpw hg) {
  int bs = blockIdx.x;
  int b = bs / S;
  int t = threadIdx.x;
  int lane = t & 63;
  int w = t >> 6;
  int q = lane >> 4;
  int mrow = lane & 15;

  __shared__ int n1_l[12];
  __shared__ int idx_l[160];
  __shared__ __align__(16) float nw_l[160];
  __shared__ int svidx_l[16];
  __shared__ __align__(16) u16 nvs_l[4][16 * 136];  // per-wave raw-row scratch
  __shared__ __align__(16) u16 agg_l[16 * 136];     // agg rows (13 used)
  __shared__ __align__(16) float ev_l[16 * 132];    // rows 0..12; 14/15 scratch
  __shared__ float red_l[64];
  __shared__ __align__(16) float agg1_l[128];

  int src0 = inputs[bs];
  if (t < 12) n1_l[t] = adj_all[(long)src0 * SAMPLE + t];
  if (t < 204) ((unsigned*)agg_l)[884 + t] = 0;  // zero agg rows 13..15
  __syncthreads();
  if (t < 156) {
    int u = (t * 683) >> 13;  // t/12 for t<156
    int j = t - u * 12;
    int su = u ? n1_l[u - 1] : src0;
    idx_l[t] = adj_all[(long)su * SAMPLE + j];
    nw_l[t] = num[(long)su * SAMPLE + j];
  } else if (t < 160) {
    idx_l[t] = 0; nw_l[t] = 0.f;
  } else if (t < 176) {
    int m = t - 160;
    svidx_l[m] = (m == 0) ? src0 : (m <= 12 ? n1_l[m - 1] : 0);
  }
  __syncthreads();

  const float* sessb = sess + (long)b * D;
  float wl8[8], w28[8];
#pragma unroll
  for (int nt = 0; nt < 8; nt++) {
    int col = nt * 16 + mrow;
    wl8[nt] = W1a[(long)D * D + col];
    w28[nt] = W2a[col];
  }
  u16* nvsw = nvs_l[w];

  // ---- Phase A -----------------------------------------------------------
  for (int u = w; u < 13; u += 4) {
    // Anti-LICM fence: keeps the 32 p1a B-frag loads + 8 sess loads inside
    // the loop (L1-hot) instead of hoisted into ~160 live VGPRs (spill).
    asm volatile("" ::: "memory");
    bfrag8 rawA[4];
    {
      long ridx = idx_l[u * 12 + (mrow < 12 ? mrow : 0)];
#pragma unroll
      for (int ks = 0; ks < 4; ks++) rawA[ks] = load_frag(emb, ridx, ks * 32 + q * 8);
    }
    f32x4 acc[8];
#pragma unroll
    for (int nt = 0; nt < 8; nt++) acc[nt] = (f32x4){0.f, 0.f, 0.f, 0.f};
#pragma unroll
    for (int ks = 0; ks < 4; ks++) {
      float4 sa = *(const float4*)(sessb + ks * 32 + q * 8);
      float4 sb = *(const float4*)(sessb + ks * 32 + q * 8 + 4);
      bfrag8 a = scale8(rawA[ks], sa, sb);
      const u16* pb = p1a + ks * 512 + lane * 8;
#pragma unroll
      for (int nt = 0; nt < 8; nt++)
        acc[nt] = __builtin_amdgcn_mfma_f32_16x16x32_bf16(
            a, *(const bfrag8*)(pb + nt * 2048), acc[nt], 0, 0, 0);
    }
    float4 nwq = *(const float4*)(nw_l + u * 12 + q * 4);
    float lp[4] = {0.f, 0.f, 0.f, 0.f};
#pragma unroll
    for (int nt = 0; nt < 8; nt++) {
      lp[0] += leaky(acc[nt][0] + nwq.x * wl8[nt]) * w28[nt];
      lp[1] += leaky(acc[nt][1] + nwq.y * wl8[nt]) * w28[nt];
      lp[2] += leaky(acc[nt][2] + nwq.z * wl8[nt]) * w28[nt];
      lp[3] += leaky(acc[nt][3] + nwq.w * wl8[nt]) * w28[nt];
    }
#pragma unroll
    for (int off = 1; off <= 8; off <<= 1)
#pragma unroll
      for (int i = 0; i < 4; i++) lp[i] += __shfl_xor(lp[i], off, 64);
    // softmax over the unit's 12 rows (rows q*4+i; q==3 = pad)
    float m4 = (q < 3) ? fmaxf(fmaxf(lp[0], lp[1]), fmaxf(lp[2], lp[3])) : NEG_BIG;
    m4 = fmaxf(m4, __shfl_xor(m4, 16, 64));
    m4 = fmaxf(m4, __shfl_xor(m4, 32, 64));
    float e0 = 0.f, e1 = 0.f, e2 = 0.f, e3 = 0.f, ssum = 0.f;
    if (q < 3) {
      e0 = __expf(lp[0] - m4); e1 = __expf(lp[1] - m4);
      e2 = __expf(lp[2] - m4); e3 = __expf(lp[3] - m4);
      ssum = e0 + e1 + e2 + e3;
    }
    ssum += __shfl_xor(ssum, 16, 64);
    ssum += __shfl_xor(ssum, 32, 64);
    float inv = 1.f / ssum;
    float al[4] = {e0 * inv, e1 * inv, e2 * inv, e3 * inv};
    float aj[12];
#pragma unroll
    for (int j = 0; j < 12; j++) aj[j] = __shfl(al[j & 3], (j >> 2) << 4, 64);
    // stage raw rows in per-wave scratch, then alpha-weighted agg per d-pair
#pragma unroll
    for (int ks = 0; ks < 4; ks++)
      *(bfrag8*)(nvsw + mrow * 136 + ks * 32 + q * 8) = rawA[ks];
    float a0 = 0.f, a1 = 0.f;
#pragma unroll
    for (int j = 0; j < 12; j++) {
      unsigned pv = *(const unsigned*)(nvsw + j * 136 + lane * 2);
      union { unsigned u; float f; } lo, hi;
      lo.u = pv << 16; hi.u = pv & 0xffff0000u;
      a0 += aj[j] * lo.f; a1 += aj[j] * hi.f;
    }
    unsigned pk = ((unsigned)f2bf(a1) << 16) | (unsigned)f2bf(a0);
    *(unsigned*)(agg_l + u * 136 + lane * 2) = pk;
  }
  __syncthreads();

  // ---- Phase B: [sv|agg] (13x256) @ W3a -> ev (tanh); wave owns 2 col-tiles
  {
    long svr = svidx_l[mrow];
    f32x4 accB[2];
    accB[0] = (f32x4){0.f, 0.f, 0.f, 0.f};
    accB[1] = (f32x4){0.f, 0.f, 0.f, 0.f};
#pragma unroll
    for (int ks = 0; ks < 4; ks++) {
      bfrag8 a = load_frag(emb, svr, ks * 32 + q * 8);
      const u16* pb = p3a + ks * 512 + lane * 8;
#pragma unroll
      for (int n = 0; n < 2; n++)
        accB[n] = __builtin_amdgcn_mfma_f32_16x16x32_bf16(
            a, *(const bfrag8*)(pb + (w * 2 + n) * 4096), accB[n], 0, 0, 0);
    }
#pragma unroll
    for (int ks = 4; ks < 8; ks++) {
      bfrag8 a = *(const bfrag8*)(agg_l + mrow * 136 + (ks - 4) * 32 + q * 8);
      const u16* pb = p3a + ks * 512 + lane * 8;
#pragma unroll
      for (int n = 0; n < 2; n++)
        accB[n] = __builtin_amdgcn_mfma_f32_16x16x32_bf16(
            a, *(const bfrag8*)(pb + (w * 2 + n) * 4096), accB[n], 0, 0, 0);
    }
#pragma unroll
    for (int n = 0; n < 2; n++) {
      int col = (w * 2 + n) * 16 + mrow;
#pragma unroll
      for (int i = 0; i < 4; i++) {
        int row = q * 4 + i;
        if (row < 13) ev_l[row * 132 + col] = tanh_f(accB[n][i]);
      }
    }
  }
  __syncthreads();

  // ---- Phase C: hop-1 unit; wave owns 2 col-tiles, cross-wave via red_l --
  {
    float wlB[2], w2B[2];
#pragma unroll
    for (int n = 0; n < 2; n++) {
      int col = (w * 2 + n) * 16 + mrow;
      wlB[n] = W1b[(long)D * D + col];
      w2B[n] = W2b[col];
    }
    int rr = 1 + (mrow < 12 ? mrow : 0);
    f32x4 accC[2];
    accC[0] = (f32x4){0.f, 0.f, 0.f, 0.f};
    accC[1] = (f32x4){0.f, 0.f, 0.f, 0.f};
#pragma unroll
    for (int ks = 0; ks < 4; ks++) {
      float4 sa = *(const float4*)(sessb + ks * 32 + q * 8);
      float4 sb = *(const float4*)(sessb + ks * 32 + q * 8 + 4);
      float4 lo = *(const float4*)(ev_l + rr * 132 + ks * 32 + q * 8);
      float4 hi = *(const float4*)(ev_l + rr * 132 + ks * 32 + q * 8 + 4);
      bfrag8 a;
      a[0] = (short)f2bf(lo.x * sa.x); a[1] = (short)f2bf(lo.y * sa.y);
      a[2] = (short)f2bf(lo.z * sa.z); a[3] = (short)f2bf(lo.w * sa.w);
      a[4] = (short)f2bf(hi.x * sb.x); a[5] = (short)f2bf(hi.y * sb.y);
      a[6] = (short)f2bf(hi.z * sb.z); a[7] = (short)f2bf(hi.w * sb.w);
      const u16* pb = p1b + ks * 512 + lane * 8;
#pragma unroll
      for (int n = 0; n < 2; n++)
        accC[n] = __builtin_amdgcn_mfma_f32_16x16x32_bf16(
            a, *(const bfrag8*)(pb + (w * 2 + n) * 2048), accC[n], 0, 0, 0);
    }
    float4 nwq0 = *(const float4*)(nw_l + q * 4);
    float lp2[4] = {0.f, 0.f, 0.f, 0.f};
#pragma unroll
    for (int n = 0; n < 2; n++) {
      lp2[0] += leaky(accC[n][0] + nwq0.x * wlB[n]) * w2B[n];
      lp2[1] += leaky(accC[n][1] + nwq0.y * wlB[n]) * w2B[n];
      lp2[2] += leaky(accC[n][2] + nwq0.z * wlB[n]) * w2B[n];
      lp2[3] += leaky(accC[n][3] + nwq0.w * wlB[n]) * w2B[n];
    }
#pragma unroll
    for (int off = 1; off <= 8; off <<= 1)
#pragma unroll
      for (int i = 0; i < 4; i++) lp2[i] += __shfl_xor(lp2[i], off, 64);
    if (mrow == 0) {
#pragma unroll
      for (int i = 0; i < 4; i++) red_l[w * 16 + q * 4 + i] = lp2[i];
    }
  }
  __syncthreads();
  {
    float lg[12];
#pragma unroll
    for (int j = 0; j < 12; j++)
      lg[j] = red_l[j] + red_l[16 + j] + red_l[32 + j] + red_l[48 + j];
    float mx = lg[0];
#pragma unroll
    for (int j = 1; j < 12; j++) mx = fmaxf(mx, lg[j]);
    float se = 0.f;
#pragma unroll
    for (int j = 0; j < 12; j++) { lg[j] = __expf(lg[j] - mx); se += lg[j]; }
    float invc = 1.f / se;
    if (t < 128) {
      float ag = 0.f;
#pragma unroll
      for (int j = 0; j < 12; j++) ag += lg[j] * invc * ev_l[(1 + j) * 132 + t];
      agg1_l[t] = ag;
    }
  }
  __syncthreads();
  // final [ev0 | agg1] @ W3b in f32 (same precision as the measured version)
  {
    int d = t & 127, hh = t >> 7;
    const float* av = hh ? agg1_l : ev_l;  // ev row 0 occupies ev_l[0..127]
    const float* Wp = W3b + (hh ? (long)128 * D : 0) + d;
    float accf = 0.f;
#pragma unroll 4
    for (int k = 0; k < 128; k++) accf += av[k] * Wp[(long)k * D];
    ev_l[(14 + hh) * 132 + d] = accf;  // rows 14/15 = scratch, disjoint
  }
  __syncthreads();
  if (t < 128) hg[(long)bs * D + t] = tanh_f(ev_l[14 * 132 + t] + ev_l[15 * 132 + t]);
}

// ---------------------------------------------------------------------------
// K5AB: fused local-attention + mirror gate (+highway on fin=1). 128 thr.
__global__ __launch_bounds__(128) void k5ab(fpp x, const int* __restrict__ adj,
                                            fpp a_loc, fpp w1, fpp w2,
                                            fpw xout, fpw mir,
                                            fpp hw, fpp h, fpw x_dot,
                                            float* __restrict__ h_local,
                                            int fin) {
  int b = blockIdx.x / S;
  int row = blockIdx.x % S;
  int tid = threadIdx.x;
  __shared__ float xi_s[D];
  __shared__ float ak_s[4][D];
  __shared__ float alpha_s[S];
  __shared__ float part_s[4][2][64];
  long idx = ((long)b * S + row) * D + tid;
  xi_s[tid] = x[idx];
#pragma unroll
  for (int k = 0; k < 4; k++) ak_s[k][tid] = a_loc[(long)k * D + tid];
  __syncthreads();
  {
    int j = tid & 63, hf = tid >> 6;
    float a0 = 0.f, a1 = 0.f, a2 = 0.f, a3 = 0.f;
    if (j < S) {
      const float* xj = x + ((long)b * S + j) * D + hf * 64;
      int off = hf * 64;
      for (int dd = 0; dd < 64; dd++) {
        float prod = xi_s[off + dd] * xj[dd];
        a0 += prod * ak_s[0][off + dd];
        a1 += prod * ak_s[1][off + dd];
        a2 += prod * ak_s[2][off + dd];
        a3 += prod * ak_s[3][off + dd];
      }
    }
    part_s[0][hf][j] = a0; part_s[1][hf][j] = a1;
    part_s[2][hf][j] = a2; part_s[3][hf][j] = a3;
  }
  __syncthreads();
  if (tid < 64) {
    int j = tid;
    float att;
    if (j < S) {
      float acc0 = part_s[0][0][j] + part_s[0][1][j];
      float acc1 = part_s[1][0][j] + part_s[1][1][j];
      float acc2 = part_s[2][0][j] + part_s[2][1][j];
      float acc3 = part_s[3][0][j] + part_s[3][1][j];
      int av = adj[((long)b * S + row) * S + j];
      att = -9e15f;  // reference's own sentinel
      if (av == 1) att = leaky(acc0);
      else if (av == 2) att = leaky(acc1);
      else if (av == 3) att = leaky(acc2);
      else if (av == 4) att = leaky(acc3);
    } else {
      att = NEG_BIG;
    }
    float mx = att;
#pragma unroll
    for (int o = 32; o > 0; o >>= 1) mx = fmaxf(mx, __shfl_xor(mx, o, 64));
    float e = __expf(att - mx);
    float ssum = e;
#pragma unroll
    for (int o = 32; o > 0; o >>= 1) ssum += __shfl_xor(ssum, o, 64);
    if (j < S) alpha_s[j] = e / ssum;
  }
  __syncthreads();
  float xn = 0.f;
  for (int j = 0; j < S; j++) xn += alpha_s[j] * x[((long)b * S + j) * D + tid];
  float mv = mir[idx];
  ak_s[0][tid] = xn;
  ak_s[1][tid] = mv;
  __syncthreads();
  float a2m = 0.f;
  for (int k = 0; k < D; k++)
    a2m += ak_s[0][k] * w1[(long)k * D + tid] + ak_s[1][k] * w2[(long)k * D + tid];
  float g = sigm(a2m);
  float xg = g * xn + (1.f - g) * mv;
  if (!fin) {
    xout[idx] = xg;
    mir[idx] = g * mv + (1.f - g) * xn;
    return;
  }
  float hv = h[idx];
  ak_s[2][tid] = hv;
  ak_s[3][tid] = xg;
  __syncthreads();
  float a3m = 0.f;
  for (int k = 0; k < D; k++)
    a3m += ak_s[2][k] * hw[(long)k * D + tid] + ak_s[3][k] * hw[(long)(D + k) * D + tid];
  float gh = sigm(a3m);
  float xd = gh * hv + (1.f - gh) * xg;
  x_dot[idx] = xd;
  if (row == S - 1) h_local[(long)b * D + tid] = xd;
}

// ---------------------------------------------------------------------------
// K7: simi loss. Block per (b,i), 128 threads (split-dot). atomicAdd to ws.
__global__ __launch_bounds__(128) void k7_simi(fpp hf1, fpp hf2,
                                               const int* __restrict__ simi_mask,
                                               float* __restrict__ loss) {
  int b = blockIdx.x / S;
  int i = blockIdx.x % S;
  int t = threadIdx.x;
  __shared__ float hi_s[D];
  __shared__ float part_s[2][64];
  hi_s[t] = hf1[((long)b * S + i) * D + t];
  __syncthreads();
  {
    int j = t & 63, hf = t >> 6;
    float acc = 0.f;
    if (j < S) {
      const float* r = hf2 + ((long)b * S + j) * D + hf * 64;
      int off = hf * 64;
      for (int dd = 0; dd < 64; dd++) acc += hi_s[off + dd] * r[dd];
    }
    part_s[hf][j] = acc;
  }
  __syncthreads();
  if (t < 64) {
    int j = t;
    float sim = (j < S) ? (part_s[0][j] + part_s[1][j]) * (1.0f / TEMPV) : NEG_BIG;
    float mx = sim;
#pragma unroll
    for (int o = 32; o > 0; o >>= 1) mx = fmaxf(mx, __shfl_xor(mx, o, 64));
    float e = __expf(sim - mx);
    float ssum = e;
#pragma unroll
    for (int o = 32; o > 0; o >>= 1) ssum += __shfl_xor(ssum, o, 64);
    float contrib = 0.f;
    if (j < S) {
      float p = e / ssum;
      float l = -__logf(p + 1e-8f);
      if (simi_mask[((long)b * S + i) * S + j] == 1) contrib = l;
    }
#pragma unroll
    for (int o = 32; o > 0; o >>= 1) contrib += __shfl_xor(contrib, o, 64);
    if (j == 0) atomicAdd(loss, contrib);
  }
}

// ---------------------------------------------------------------------------
// K8: GLU epilogue per batch, 512 threads = 4 s-groups (serial 50 -> 13).
__global__ __launch_bounds__(512) void k8_glu(
    fpp hg, fpp x_dot, fpp pos, fpp h_local, const float* __restrict__ mi,
    fpp glu1, fpp glu2, fpp glu4, fpp glu4b, fpp w_s, fpp gate_w, fpw zh) {
  int b = blockIdx.x;
  int t = threadIdx.x;
  int d = t & 127;
  int g = t >> 7;   // s-group 0..3
  __shared__ float hs_s[D], hl_s[D];
  __shared__ float hp_g[4][D], part[4][D], zg_g[4][D];
  __shared__ float red2[4][2];
  float msf = 0.f;
  for (int s = 0; s < S; s++) msf += mi[b * S + s];
  float hsacc = 0.f;
  for (int s = g * 13; s < min(S, g * 13 + 13); s++)
    hsacc += hg[((long)b * S + s) * D + d] * mi[b * S + s];
  part[g][d] = hsacc;
  if (g == 1) hl_s[d] = h_local[(long)b * D + d];
  __syncthreads();
  if (g == 0) hs_s[d] = (part[0][d] + part[1][d] + part[2][d] + part[3][d]) / msf;
  __syncthreads();
  float c = glu4b[d];
  for (int k = 0; k < D; k++)
    c += hs_s[k] * glu2[(long)k * D + d] + hl_s[k] * glu4[(long)k * D + d];
  float wsd = w_s[d];
  float zg = 0.f;
  for (int it = 0; it < 13; it++) {
    int s = g * 13 + it;
    bool act = s < S;
    float hp = 0.f;
    if (act) {
      hp = x_dot[((long)b * S + s) * D + d] + pos[(long)s * D + d];
      hp_g[g][d] = hp;
    }
    __syncthreads();
    if (act) {
      float acc = c;
      for (int k = 0; k < D; k++) acc += hp_g[g][k] * glu1[(long)k * D + d];
      float v = sigm(acc) * wsd;
#pragma unroll
      for (int o = 32; o > 0; o >>= 1) v += __shfl_down(v, o, 64);
      if ((t & 63) == 0) red2[g][(t >> 6) & 1] = v;
    }
    __syncthreads();
    if (act) {
      float beta = (red2[g][0] + red2[g][1]) * mi[b * S + s];
      zg += beta * hp;
    }
    __syncthreads();
  }
  zg_g[g][d] = zg;
  __syncthreads();
  if (g == 0) {
    float zgf = zg_g[0][d] + zg_g[1][d] + zg_g[2][d] + zg_g[3][d];
    hp_g[0][d] = zgf;
  }
  __syncthreads();
  if (g == 0) {
    float zgf = hp_g[0][d];
    float acc = 0.f;
    for (int k = 0; k < D; k++)
      acc += hp_g[0][k] * gate_w[(long)k * D + d] +
             hl_s[k] * gate_w[(long)(D + k) * D + d];
    float gf = sigm(acc) * MUV;
    zh[(long)b * D + d] = gf * hl_s[d] + (1.f - gf) * zgf;
  }
}

// ---------------------------------------------------------------------------
// K9: scores = zh(128x128) @ emb[1:]^T via bf16 MFMA. Template on emb dtype
// (bf16 path loads B-frags directly, no converts).
template <typename ET>
__global__ __launch_bounds__(256) void k9_scores(fpp zh, const ET* __restrict__ emb,
                                                 fpp loss, float* __restrict__ out) {
  int t = threadIdx.x;
  if (blockIdx.x == 0 && t == 0) out[0] = loss[0] * (1.0f / (float)B);
  int lane = t & 63;
  int w = t >> 6;
  int q = lane >> 4;
  int mrow = lane & 15;
  long n = (long)blockIdx.x * 64 + w * 16 + mrow;
  bool valid = n < NSC;
  long nrow = valid ? (n + 1) : 1;
  bfrag8 bfr[4];
#pragma unroll
  for (int ks = 0; ks < 4; ks++) {
    if constexpr (sizeof(ET) == 2) {
      bfr[ks] = *(const bfrag8*)(const void*)(emb + nrow * D + ks * 32 + q * 8);
    } else {
      const float* src = (const float*)(emb + nrow * D + ks * 32 + q * 8);
      float4 lo = *(const float4*)src;
      float4 hi = *(const float4*)(src + 4);
      bfrag8 bb;
      bb[0] = (short)f2bf(lo.x); bb[1] = (short)f2bf(lo.y);
      bb[2] = (short)f2bf(lo.z); bb[3] = (short)f2bf(lo.w);
      bb[4] = (short)f2bf(hi.x); bb[5] = (short)f2bf(hi.y);
      bb[6] = (short)f2bf(hi.z); bb[7] = (short)f2bf(hi.w);
      bfr[ks] = bb;
    }
  }
#pragma unroll
  for (int mt = 0; mt < 8; mt++) {
    f32x4 acc = (f32x4){0.f, 0.f, 0.f, 0.f};
#pragma unroll
    for (int ks = 0; ks < 4; ks++) {
      const float* za = zh + (long)(mt * 16 + mrow) * D + ks * 32 + q * 8;
      float4 lo = *(const float4*)za;
      float4 hi = *(const float4*)(za + 4);
      bfrag8 a;
      a[0] = (short)f2bf(lo.x); a[1] = (short)f2bf(lo.y);
      a[2] = (short)f2bf(lo.z); a[3] = (short)f2bf(lo.w);
      a[4] = (short)f2bf(hi.x); a[5] = (short)f2bf(hi.y);
      a[6] = (short)f2bf(hi.z); a[7] = (short)f2bf(hi.w);
      acc = __builtin_amdgcn_mfma_f32_16x16x32_bf16(a, bfr[ks], acc, 0, 0, 0);
    }
    if (valid) {
#pragma unroll
      for (int i = 0; i < 4; i++) {
        int m = mt * 16 + q * 4 + i;
        out[1 + (long)m * NSC + n] = acc[i];
      }
    }
  }
}

// ---------------------------------------------------------------------------
extern "C" void kernel_launch(void* const* d_in, const int* in_sizes, int n_in,
                              void* d_out, int out_size, void* d_ws, size_t ws_size,
                              hipStream_t stream) {
  (void)in_sizes; (void)n_in; (void)out_size;
  const int* inputs = (const int*)d_in[0];
  const int* adj = (const int*)d_in[1];
  const int* item = (const int*)d_in[2];
  const int* simi_mask = (const int*)d_in[3];
  const int* as0 = (const int*)d_in[4];
  const int* as1 = (const int*)d_in[5];
  const int* ss0 = (const int*)d_in[6];
  const int* ss1 = (const int*)d_in[7];
  // d_in[8]: last_item_mask — structurally [:, -1]; hardcoded in k5ab(fin).
  const int* adj_all = (const int*)d_in[9];
  fpp num = (fpp)d_in[10];
  fpp emb = (fpp)d_in[11];
  fpp pos = (fpp)d_in[12];
  fpp a_local = (fpp)d_in[13];
  fpp mir_w1 = (fpp)d_in[14];
  fpp mir_w2 = (fpp)d_in[15];
  fpp gw1 = (fpp)d_in[16];
  fpp gw2 = (fpp)d_in[17];
  fpp gw3 = (fpp)d_in[18];
  fpp attr_w = (fpp)d_in[19];
  fpp highway_w = (fpp)d_in[20];
  fpp glu1 = (fpp)d_in[21];
  fpp glu2 = (fpp)d_in[22];
  fpp glu4 = (fpp)d_in[23];
  fpp glu4b = (fpp)d_in[24];
  fpp w_s = (fpp)d_in[25];
  fpp gate_w = (fpp)d_in[26];

  // fp32 scratch inside d_out: 6 * 819200 = 4,915,200 elts <= 5,119,873.
  float* ob = (float*)d_out;
  constexpr long BSD_ = (long)B * S * D;  // 819200
  fpw s_h = ob + 0 * BSD_;
  fpw s_hf1 = ob + 1 * BSD_;  // later x_dot
  fpw s_hf2 = ob + 2 * BSD_;  // later h_global
  fpw s_mir = ob + 3 * BSD_;
  fpw s_xA = ob + 4 * BSD_;
  fpw s_xB = ob + 5 * BSD_;

  // d_ws layout: small fp32 state (loss at ws[0]) .. float 72000; prepped
  // weight frags (196,608 B) at byte 288,000; bf16 emb (10.24 MB, guarded)
  // at byte 491,520.
  float* ws = (float*)d_ws;
  float* w_loss = ws + 0;
  float* w_mi = ws + 16;                // B*S
  float* w_sess = w_mi + (long)B * S;   // B*D
  float* w_hl = w_sess + (long)B * D;   // B*D
  float* w_zh = w_hl + (long)B * D;     // B*D
  u16* p1a = (u16*)(ws + 72000);
  u16* p1b = (u16*)(ws + 72000 + 8192);
  u16* p3a = (u16*)(ws + 72000 + 16384);
  u16* p3b = (u16*)(ws + 72000 + 32768);
  u16* embbf = (u16*)((char*)d_ws + 491520);
  bool useBF = ws_size >= (size_t)12 * 1024 * 1024;

  hipMemsetAsync((void*)w_loss, 0, sizeof(float), stream);

  kprep4<<<384, 256, 0, stream>>>(gw1, gw3, p1a, p1b, p3a, p3b);
  if (useBF)
    kprep_emb<<<(NODES * D / 4 + 255) / 256, 256, 0, stream>>>(emb, embbf);

  if (useBF)
    k1_gather<u16><<<B * S, 128, 0, stream>>>(inputs, as0, as1, ss0, ss1,
                                              embbf, attr_w, s_h, s_hf1, s_hf2,
                                              w_mi, s_xA, s_mir);
  else
    k1_gather<float><<<B * S, 128, 0, stream>>>(inputs, as0, as1, ss0, ss1,
                                                emb, attr_w, s_h, s_hf1, s_hf2,
                                                w_mi, s_xA, s_mir);
  // k7 consumes hf1/hf2 before kG reuses the hf2 slot as h_global.
  k7_simi<<<B * S, 128, 0, stream>>>(s_hf1, s_hf2, simi_mask, w_loss);
  k2_sess<<<B, 128, 0, stream>>>(inputs, item, emb, w_sess);
  if (useBF)
    kG_global<u16><<<B * S, 256, 0, stream>>>(inputs, adj_all, num, embbf,
                                              w_sess, gw1, gw2,
                                              gw1 + 129 * 128, gw2 + 128,
                                              gw3 + 256 * 128, p1a, p1b, p3a,
                                              s_hf2 /* h_global */);
  else
    kG_global<float><<<B * S, 256, 0, stream>>>(inputs, adj_all, num, emb,
                                                w_sess, gw1, gw2,
                                                gw1 + 129 * 128, gw2 + 128,
                                                gw3 + 256 * 128, p1a, p1b, p3a,
                                                s_hf2 /* h_global */);
  k5ab<<<B * S, 128, 0, stream>>>(s_xA, adj, a_local, mir_w1, mir_w2,
                                  s_xB, s_mir, highway_w, s_h, s_hf1, w_hl, 0);
  k5ab<<<B * S, 128, 0, stream>>>(s_xB, adj, a_local + 4 * D,
                                  mir_w1 + (long)D * D, mir_w2 + (long)D * D,
                                  s_xA, s_mir, highway_w, s_h,
                                  s_hf1 /* x_dot */, w_hl, 1);
  k8_glu<<<B, 512, 0, stream>>>(s_hf2 /* h_global */, s_hf1 /* x_dot */, pos,
                                w_hl, w_mi, glu1, glu2, glu4, glu4b, w_s,
                                gate_w, w_zh);
  if (useBF)
    k9_scores<u16><<<(NSC + 63) / 64, 256, 0, stream>>>(w_zh, embbf, w_loss,
                                                        (float*)d_out);
  else
    k9_scores<float><<<(NSC + 63) / 64, 256, 0, stream>>>(w_zh, emb, w_loss,
                                                          (float*)d_out);
}

// Round 4
// 739.766 us; speedup vs baseline: 1.1060x; 1.1060x over previous
//
#include <hip/hip_runtime.h>
#include <hip/hip_bf16.h>
#include <type_traits>

// CombineGraph forward. B=128,S=50,D=128,NODES=40000,SAMPLE=12,NNEI=8,HOP=2.
// Round 16: kG split for gather-MLP. Phase A -> kGA_unit: one wave per
// (bs,unit) = 83,200 independent blocks (grid-level latency hiding; agg rows
// -> ws as bf16, bit-identical to the verified R15 math). Phases B/C ->
// kGB_post per bs. Needs ws >= 32 MiB for the 21.3MB agg buffer; otherwise
// falls back to the measured-best monolithic R7 kG (272us).

#define B 128
#define S 50
#define D 128
#define SAMPLE 12
#define NNEI 8
#define NODES 40000
#define NSC (NODES - 1)
#define LEAK 0.2f
#define TEMPV 0.5f
#define MUV 0.1f
#define NEG_BIG -3.0e38f

typedef const float* fpp;
typedef float* fpw;
typedef unsigned short u16;
typedef __attribute__((ext_vector_type(8))) short bfrag8;
typedef __attribute__((ext_vector_type(4))) float f32x4;

__device__ __forceinline__ float sigm(float x) { return 1.f / (1.f + __expf(-x)); }
__device__ __forceinline__ float tanh_f(float x) { return 1.f - 2.f / (__expf(2.f * x) + 1.f); }
__device__ __forceinline__ float leaky(float x) { return x >= 0.f ? x : LEAK * x; }
__device__ __forceinline__ u16 f2bf(float v) {
  __hip_bfloat16 h = __float2bfloat16(v);
  return *reinterpret_cast<u16*>(&h);
}
__device__ __forceinline__ float lde(const float* p, long i) { return p[i]; }
__device__ __forceinline__ float lde(const u16* p, long i) {
  union { unsigned int u; float f; } c;
  c.u = ((unsigned int)p[i]) << 16;
  return c.f;
}
__device__ __forceinline__ float bfu(short s) {
  union { unsigned u; float f; } c;
  c.u = ((unsigned)(unsigned short)s) << 16;
  return c.f;
}

// Load one MFMA A-fragment (8 contiguous k) of emb row `row` at k-offset koff.
template <typename ET>
__device__ __forceinline__ bfrag8 load_frag(const ET* __restrict__ emb, long row, int koff) {
  if constexpr (sizeof(ET) == 2) {
    return *(const bfrag8*)(const void*)(emb + row * D + koff);
  } else {
    const float* s = (const float*)(emb + row * D + koff);
    float4 lo = *(const float4*)s;
    float4 hi = *(const float4*)(s + 4);
    bfrag8 b;
    b[0] = (short)f2bf(lo.x); b[1] = (short)f2bf(lo.y);
    b[2] = (short)f2bf(lo.z); b[3] = (short)f2bf(lo.w);
    b[4] = (short)f2bf(hi.x); b[5] = (short)f2bf(hi.y);
    b[6] = (short)f2bf(hi.z); b[7] = (short)f2bf(hi.w);
    return b;
  }
}

__device__ __forceinline__ bfrag8 scale8(bfrag8 r, float4 sa, float4 sb) {
  bfrag8 o;
  o[0] = (short)f2bf(bfu(r[0]) * sa.x); o[1] = (short)f2bf(bfu(r[1]) * sa.y);
  o[2] = (short)f2bf(bfu(r[2]) * sa.z); o[3] = (short)f2bf(bfu(r[3]) * sa.w);
  o[4] = (short)f2bf(bfu(r[4]) * sb.x); o[5] = (short)f2bf(bfu(r[5]) * sb.y);
  o[6] = (short)f2bf(bfu(r[6]) * sb.z); o[7] = (short)f2bf(bfu(r[7]) * sb.w);
  return o;
}

// ---------------------------------------------------------------------------
// KPREP_EMB: emb fp32 -> bf16 copy in ws (4 elems/thread).
__global__ __launch_bounds__(256) void kprep_emb(fpp emb, u16* __restrict__ out) {
  long i = ((long)blockIdx.x * 256 + threadIdx.x) * 4;
  if (i + 3 >= (long)NODES * D) return;
  float4 v = *(const float4*)(emb + i);
  out[i + 0] = f2bf(v.x); out[i + 1] = f2bf(v.y);
  out[i + 2] = f2bf(v.z); out[i + 3] = f2bf(v.w);
}

// ---------------------------------------------------------------------------
// KPREP4: four weight tensors -> bf16 B-fragment order.
__global__ __launch_bounds__(256) void kprep4(fpp gw1, fpp gw3,
                                              u16* __restrict__ p1a,
                                              u16* __restrict__ p1b,
                                              u16* __restrict__ p3a,
                                              u16* __restrict__ p3b) {
  int i = blockIdx.x * 256 + threadIdx.x;
  fpp W; u16* dst; int KS;
  if (i < 16384)      { W = gw1;             dst = p1a; KS = 4; }
  else if (i < 32768) { W = gw1 + 129 * 128; dst = p1b; KS = 4; i -= 16384; }
  else if (i < 65536) { W = gw3;             dst = p3a; KS = 8; i -= 32768; }
  else                { W = gw3 + 256 * 128; dst = p3b; KS = 8; i -= 65536; }
  int e = i & 7;
  int lane = (i >> 3) & 63;
  int rest = i >> 9;
  int ks = rest % KS, nt = rest / KS;
  int k = ks * 32 + ((lane >> 4) << 3) + e;
  int n = (nt << 4) + (lane & 15);
  dst[i] = f2bf(W[(long)k * 128 + n]);
}

// ---------------------------------------------------------------------------
// K1: h = emb[inputs]; hf1/hf2 pools; attr gate. Block per (b,s), 128 thr.
template <typename ET>
__global__ __launch_bounds__(128) void k1_gather(
    const int* __restrict__ inputs, const int* __restrict__ as0,
    const int* __restrict__ as1, const int* __restrict__ ss0,
    const int* __restrict__ ss1, const ET* __restrict__ emb, fpp attr_w,
    fpw h, fpw hf1, fpw hf2, float* __restrict__ mi, fpw xA, fpw mir) {
  int bs = blockIdx.x;
  int d = threadIdx.x;
  __shared__ float h_s[D], hf1_s[D];
  int inp = inputs[bs];
  float hv = lde(emb, (long)inp * D + d);
  const int* lists[4] = {as0, as1, ss0, ss1};
  float p[4];
#pragma unroll
  for (int l = 0; l < 4; l++) {
    float sum = 0.f, cnt = 0.f;
    const int* L = lists[l] + (long)bs * NNEI;
#pragma unroll
    for (int n = 0; n < NNEI; n++) {
      int idx = L[n];
      if (idx != 0) { sum += lde(emb, (long)idx * D + d); cnt += 1.f; }
    }
    p[l] = sum / (cnt + 1e-8f);
  }
  float hf1v = 0.5f * (p[0] + p[1]);
  float hf2v = 0.5f * (p[2] + p[3]);
  h_s[d] = hv;
  hf1_s[d] = hf1v;
  __syncthreads();
  float acc = 0.f;
  for (int k = 0; k < D; k++)
    acc += h_s[k] * attr_w[(long)k * D + d] + hf1_s[k] * attr_w[(long)(D + k) * D + d];
  float g = sigm(acc);
  float hfv = g * hv + (1.f - g) * hf1v;
  long o = (long)bs * D + d;
  h[o] = hv; hf1[o] = hf1v; hf2[o] = hf2v; xA[o] = hv; mir[o] = hfv;
  if (d == 0) mi[bs] = (inp != 0) ? 1.f : 0.f;
}

// ---------------------------------------------------------------------------
// K2: sess[b,:] = sum_s emb[item[b,s]]*mi / sum_s mi
__global__ __launch_bounds__(128) void k2_sess(const int* __restrict__ inputs,
                                               const int* __restrict__ item,
                                               fpp emb, fpw sess) {
  int b = blockIdx.x;
  int d = threadIdx.x;
  float acc = 0.f, ms = 0.f;
  for (int s = 0; s < S; s++) {
    int inp = inputs[b * S + s];
    float m = (inp != 0) ? 1.f : 0.f;
    int it = item[b * S + s];
    acc += emb[(long)it * D + d] * m;
    ms += m;
  }
  sess[(long)b * D + d] = acc / ms;
}

// ---------------------------------------------------------------------------
// KGA: one phase-A unit per 64-thread block. grid = B*S*13 (u fast for L2
// locality on n1/sess). Writes agg row (bf16, bit-identical to R15 LDS path)
// to aggws[(bs*13+u)*128].
template <typename ET>
__global__ __launch_bounds__(64) void kGA_unit(
    const int* __restrict__ inputs, const int* __restrict__ adj_all,
    fpp num, const ET* __restrict__ emb, fpp sess,
    fpp W1a, fpp W2a, const u16* __restrict__ p1a,
    u16* __restrict__ aggws) {
  int gb = blockIdx.x;
  int bs = gb / 13;
  int u = gb - bs * 13;
  int b = bs / S;
  int lane = threadIdx.x;
  int q = lane >> 4;
  int mrow = lane & 15;

  __shared__ __align__(16) u16 nvs[16 * 136];

  int src0 = inputs[bs];
  int srcu = (u == 0) ? src0 : adj_all[(long)src0 * SAMPLE + (u - 1)];
  int rid = adj_all[(long)srcu * SAMPLE + (mrow < 12 ? mrow : 0)];
  float nwq[4];
#pragma unroll
  for (int i = 0; i < 4; i++)
    nwq[i] = (q < 3) ? num[(long)srcu * SAMPLE + q * 4 + i] : 0.f;

  const float* sessb = sess + (long)b * D;
  bfrag8 rawA[4], sA[4];
#pragma unroll
  for (int ks = 0; ks < 4; ks++)
    rawA[ks] = load_frag(emb, (long)rid, ks * 32 + q * 8);
#pragma unroll
  for (int ks = 0; ks < 4; ks++)
    *(bfrag8*)(nvs + mrow * 136 + ks * 32 + q * 8) = rawA[ks];
#pragma unroll
  for (int ks = 0; ks < 4; ks++) {
    float4 sa = *(const float4*)(sessb + ks * 32 + q * 8);
    float4 sb = *(const float4*)(sessb + ks * 32 + q * 8 + 4);
    sA[ks] = scale8(rawA[ks], sa, sb);
  }
  float wl8[8], w28[8];
#pragma unroll
  for (int nt = 0; nt < 8; nt++) {
    int col = nt * 16 + mrow;
    wl8[nt] = W1a[(long)D * D + col];
    w28[nt] = W2a[col];
  }
  float lp[4] = {0.f, 0.f, 0.f, 0.f};
#pragma unroll
  for (int nt = 0; nt < 8; nt++) {
    f32x4 acc = (f32x4){0.f, 0.f, 0.f, 0.f};
#pragma unroll
    for (int ks = 0; ks < 4; ks++)
      acc = __builtin_amdgcn_mfma_f32_16x16x32_bf16(
          sA[ks], *(const bfrag8*)(p1a + ks * 512 + lane * 8 + nt * 2048), acc, 0, 0, 0);
    lp[0] += leaky(acc[0] + nwq[0] * wl8[nt]) * w28[nt];
    lp[1] += leaky(acc[1] + nwq[1] * wl8[nt]) * w28[nt];
    lp[2] += leaky(acc[2] + nwq[2] * wl8[nt]) * w28[nt];
    lp[3] += leaky(acc[3] + nwq[3] * wl8[nt]) * w28[nt];
  }
#pragma unroll
  for (int off = 1; off <= 8; off <<= 1)
#pragma unroll
    for (int i = 0; i < 4; i++) lp[i] += __shfl_xor(lp[i], off, 64);
  float m4 = (q < 3) ? fmaxf(fmaxf(lp[0], lp[1]), fmaxf(lp[2], lp[3])) : NEG_BIG;
  m4 = fmaxf(m4, __shfl_xor(m4, 16, 64));
  m4 = fmaxf(m4, __shfl_xor(m4, 32, 64));
  float e0 = 0.f, e1 = 0.f, e2 = 0.f, e3 = 0.f, ssum = 0.f;
  if (q < 3) {
    e0 = __expf(lp[0] - m4); e1 = __expf(lp[1] - m4);
    e2 = __expf(lp[2] - m4); e3 = __expf(lp[3] - m4);
    ssum = e0 + e1 + e2 + e3;
  }
  ssum += __shfl_xor(ssum, 16, 64);
  ssum += __shfl_xor(ssum, 32, 64);
  float inv = 1.f / ssum;
  float al[4] = {e0 * inv, e1 * inv, e2 * inv, e3 * inv};
  float aj[12];
#pragma unroll
  for (int j = 0; j < 12; j++) aj[j] = __shfl(al[j & 3], (j >> 2) << 4, 64);
  float a0 = 0.f, a1 = 0.f;
#pragma unroll
  for (int j = 0; j < 12; j++) {
    unsigned pv = *(const unsigned*)(nvs + j * 136 + lane * 2);
    union { unsigned u; float f; } lo, hi;
    lo.u = pv << 16; hi.u = pv & 0xffff0000u;
    a0 += aj[j] * lo.f; a1 += aj[j] * hi.f;
  }
  unsigned pk = ((unsigned)f2bf(a1) << 16) | (unsigned)f2bf(a0);
  *(unsigned*)(aggws + ((long)bs * 13 + u) * 128 + lane * 2) = pk;
}

// ---------------------------------------------------------------------------
// KGB: phases B/C + final per bs (256 thr, ported verbatim from R15; agg
// rows read coalesced from aggws, zero frags for rows 13..15).
template <typename ET>
__global__ __launch_bounds__(256) void kGB_post(
    const int* __restrict__ inputs, const int* __restrict__ adj_all,
    fpp num, const ET* __restrict__ emb, fpp sess,
    fpp W1b, fpp W2b, fpp W3b,
    const u16* __restrict__ p1b, const u16* __restrict__ p3a,
    const u16* __restrict__ aggws, fpw hg) {
  int bs = blockIdx.x;
  int b = bs / S;
  int t = threadIdx.x;
  int lane = t & 63;
  int w = t >> 6;
  int q = lane >> 4;
  int mrow = lane & 15;

  __shared__ int svidx_l[16];
  __shared__ __align__(16) float ev_l[16 * 132];
  __shared__ float red_l[64];
  __shared__ __align__(16) float agg1_l[128];

  int src0 = inputs[bs];
  if (t < 16)
    svidx_l[t] = (t == 0) ? src0 : (t <= 12 ? adj_all[(long)src0 * SAMPLE + t - 1] : 0);
  __syncthreads();
  const float* sessb = sess + (long)b * D;

  // ---- Phase B: [sv|agg] (13x256) @ W3a -> ev (tanh); wave owns 2 col-tiles
  {
    long svr = svidx_l[mrow];
    f32x4 accB[2];
    accB[0] = (f32x4){0.f, 0.f, 0.f, 0.f};
    accB[1] = (f32x4){0.f, 0.f, 0.f, 0.f};
#pragma unroll
    for (int ks = 0; ks < 4; ks++) {
      bfrag8 a = load_frag(emb, svr, ks * 32 + q * 8);
      const u16* pb = p3a + ks * 512 + lane * 8;
#pragma unroll
      for (int n = 0; n < 2; n++)
        accB[n] = __builtin_amdgcn_mfma_f32_16x16x32_bf16(
            a, *(const bfrag8*)(pb + (w * 2 + n) * 4096), accB[n], 0, 0, 0);
    }
#pragma unroll
    for (int ks = 4; ks < 8; ks++) {
      bfrag8 a;
      if (mrow < 13)
        a = *(const bfrag8*)(aggws + ((long)bs * 13 + mrow) * 128 + (ks - 4) * 32 + q * 8);
      else
        a = (bfrag8){0, 0, 0, 0, 0, 0, 0, 0};
      const u16* pb = p3a + ks * 512 + lane * 8;
#pragma unroll
      for (int n = 0; n < 2; n++)
        accB[n] = __builtin_amdgcn_mfma_f32_16x16x32_bf16(
            a, *(const bfrag8*)(pb + (w * 2 + n) * 4096), accB[n], 0, 0, 0);
    }
#pragma unroll
    for (int n = 0; n < 2; n++) {
      int col = (w * 2 + n) * 16 + mrow;
#pragma unroll
      for (int i = 0; i < 4; i++) {
        int row = q * 4 + i;
        if (row < 13) ev_l[row * 132 + col] = tanh_f(accB[n][i]);
      }
    }
  }
  __syncthreads();

  // ---- Phase C: hop-1 unit; wave owns 2 col-tiles, cross-wave via red_l --
  {
    float wlB[2], w2B[2];
#pragma unroll
    for (int n = 0; n < 2; n++) {
      int col = (w * 2 + n) * 16 + mrow;
      wlB[n] = W1b[(long)D * D + col];
      w2B[n] = W2b[col];
    }
    int rr = 1 + (mrow < 12 ? mrow : 0);
    f32x4 accC[2];
    accC[0] = (f32x4){0.f, 0.f, 0.f, 0.f};
    accC[1] = (f32x4){0.f, 0.f, 0.f, 0.f};
#pragma unroll
    for (int ks = 0; ks < 4; ks++) {
      float4 sa = *(const float4*)(sessb + ks * 32 + q * 8);
      float4 sb = *(const float4*)(sessb + ks * 32 + q * 8 + 4);
      float4 lo = *(const float4*)(ev_l + rr * 132 + ks * 32 + q * 8);
      float4 hi = *(const float4*)(ev_l + rr * 132 + ks * 32 + q * 8 + 4);
      bfrag8 a;
      a[0] = (short)f2bf(lo.x * sa.x); a[1] = (short)f2bf(lo.y * sa.y);
      a[2] = (short)f2bf(lo.z * sa.z); a[3] = (short)f2bf(lo.w * sa.w);
      a[4] = (short)f2bf(hi.x * sb.x); a[5] = (short)f2bf(hi.y * sb.y);
      a[6] = (short)f2bf(hi.z * sb.z); a[7] = (short)f2bf(hi.w * sb.w);
      const u16* pb = p1b + ks * 512 + lane * 8;
#pragma unroll
      for (int n = 0; n < 2; n++)
        accC[n] = __builtin_amdgcn_mfma_f32_16x16x32_bf16(
            a, *(const bfrag8*)(pb + (w * 2 + n) * 2048), accC[n], 0, 0, 0);
    }
    float4 nwq0;
    if (q < 3) {
      nwq0.x = num[(long)src0 * SAMPLE + q * 4 + 0];
      nwq0.y = num[(long)src0 * SAMPLE + q * 4 + 1];
      nwq0.z = num[(long)src0 * SAMPLE + q * 4 + 2];
      nwq0.w = num[(long)src0 * SAMPLE + q * 4 + 3];
    } else {
      nwq0.x = nwq0.y = nwq0.z = nwq0.w = 0.f;
    }
    float lp2[4] = {0.f, 0.f, 0.f, 0.f};
#pragma unroll
    for (int n = 0; n < 2; n++) {
      lp2[0] += leaky(accC[n][0] + nwq0.x * wlB[n]) * w2B[n];
      lp2[1] += leaky(accC[n][1] + nwq0.y * wlB[n]) * w2B[n];
      lp2[2] += leaky(accC[n][2] + nwq0.z * wlB[n]) * w2B[n];
      lp2[3] += leaky(accC[n][3] + nwq0.w * wlB[n]) * w2B[n];
    }
#pragma unroll
    for (int off = 1; off <= 8; off <<= 1)
#pragma unroll
      for (int i = 0; i < 4; i++) lp2[i] += __shfl_xor(lp2[i], off, 64);
    if (mrow == 0) {
#pragma unroll
      for (int i = 0; i < 4; i++) red_l[w * 16 + q * 4 + i] = lp2[i];
    }
  }
  __syncthreads();
  {
    float lg[12];
#pragma unroll
    for (int j = 0; j < 12; j++)
      lg[j] = red_l[j] + red_l[16 + j] + red_l[32 + j] + red_l[48 + j];
    float mx = lg[0];
#pragma unroll
    for (int j = 1; j < 12; j++) mx = fmaxf(mx, lg[j]);
    float se = 0.f;
#pragma unroll
    for (int j = 0; j < 12; j++) { lg[j] = __expf(lg[j] - mx); se += lg[j]; }
    float invc = 1.f / se;
    if (t < 128) {
      float ag = 0.f;
#pragma unroll
      for (int j = 0; j < 12; j++) ag += lg[j] * invc * ev_l[(1 + j) * 132 + t];
      agg1_l[t] = ag;
    }
  }
  __syncthreads();
  {
    int d = t & 127, hh = t >> 7;
    const float* av = hh ? agg1_l : ev_l;
    const float* Wp = W3b + (hh ? (long)128 * D : 0) + d;
    float accf = 0.f;
#pragma unroll 4
    for (int k = 0; k < 128; k++) accf += av[k] * Wp[(long)k * D];
    ev_l[(14 + hh) * 132 + d] = accf;
  }
  __syncthreads();
  if (t < 128) hg[(long)bs * D + t] = tanh_f(ev_l[14 * 132 + t] + ev_l[15 * 132 + t]);
}

// ---------------------------------------------------------------------------
// KG_MONO: R7/R0 monolithic kG (measured 272us) — fallback when ws is too
// small for the split path's agg buffer.
template <typename ET>
__global__ __launch_bounds__(128) void kG_mono(
    const int* __restrict__ inputs, const int* __restrict__ adj_all,
    fpp num, const ET* __restrict__ emb, fpp sess,
    fpp W1a, fpp W2a, fpp W1b, fpp W2b, fpp W3b,
    const u16* __restrict__ p1a, const u16* __restrict__ p1b,
    const u16* __restrict__ p3a, fpw hg) {
  int bs = blockIdx.x;
  int b = bs / S;
  int d = threadIdx.x;
  int lane = d & 63;
  int w = d >> 6;
  int q = lane >> 4;
  int mrow = lane & 15;

  __shared__ __align__(16) u16 nvs_l[16 * 136];
  __shared__ __align__(16) u16 svagg_l[16 * 264];
  __shared__ __align__(16) float ev_l[13 * 128];
  __shared__ __align__(16) float agg1_l[128];
  __shared__ float red_l[2][16];
  __shared__ float nw_l[16];

#pragma unroll
  for (int r = 12; r < 16; r++) {
    nvs_l[r * 136 + d] = 0;
    if (d < 8) nvs_l[r * 136 + 128 + d] = 0;
  }
#pragma unroll
  for (int r = 13; r < 16; r++) {
    svagg_l[r * 264 + d] = 0;
    svagg_l[r * 264 + 128 + d] = 0;
    if (d < 8) svagg_l[r * 264 + 256 + d] = 0;
  }

  float sess_d = sess[(long)b * D + d];
  int src0 = __builtin_amdgcn_readfirstlane(inputs[bs]);
  int n1[SAMPLE];
#pragma unroll
  for (int j = 0; j < SAMPLE; j++)
    n1[j] = __builtin_amdgcn_readfirstlane(adj_all[(long)src0 * SAMPLE + j]);
  svagg_l[0 * 264 + d] = f2bf(lde(emb, (long)src0 * D + d));

  float w2A[4], wlA[4], w2B[4], wlB[4];
#pragma unroll
  for (int nt = 0; nt < 4; nt++) {
    int col = (w * 4 + nt) * 16 + mrow;
    w2A[nt] = W2a[col];
    wlA[nt] = W1a[(long)D * D + col];
    w2B[nt] = W2b[col];
    wlB[nt] = W1b[(long)D * D + col];
  }

  // ---- Phase A: 13 hop-0 units, prefetch-pipelined ----------------------
  float pre[SAMPLE], pnw = 0.f;
  {
#pragma unroll
    for (int j = 0; j < SAMPLE; j++)
      pre[j] = lde(emb, (long)n1[j] * D + d);
    if (d < SAMPLE) pnw = num[(long)src0 * SAMPLE + d];
  }
  for (int u = 0; u < 13; u++) {
    if (d < SAMPLE) nw_l[d] = pnw;
    float nvreg[SAMPLE];
#pragma unroll
    for (int j = 0; j < SAMPLE; j++) {
      nvreg[j] = pre[j];
      nvs_l[j * 136 + d] = f2bf(pre[j] * sess_d);
    }
    if (u == 0) {
#pragma unroll
      for (int j = 0; j < SAMPLE; j++)
        svagg_l[(1 + j) * 264 + d] = f2bf(nvreg[j]);
    }
    __syncthreads();
    if (u < 12) {
      int srcn = n1[u];
#pragma unroll
      for (int j = 0; j < SAMPLE; j++) {
        int nj = __builtin_amdgcn_readfirstlane(adj_all[(long)srcn * SAMPLE + j]);
        pre[j] = lde(emb, (long)nj * D + d);
      }
      if (d < SAMPLE) pnw = num[(long)srcn * SAMPLE + d];
    }
    f32x4 acc[4];
#pragma unroll
    for (int nt = 0; nt < 4; nt++) acc[nt] = (f32x4){0.f, 0.f, 0.f, 0.f};
#pragma unroll
    for (int ks = 0; ks < 4; ks++) {
      bfrag8 a = *(const bfrag8*)(nvs_l + mrow * 136 + q * 8 + ks * 32);
      const u16* pb = p1a + (w * 16 + ks) * 512 + lane * 8;
#pragma unroll
      for (int nt = 0; nt < 4; nt++) {
        bfrag8 bb = *(const bfrag8*)(pb + nt * 2048);
        acc[nt] = __builtin_amdgcn_mfma_f32_16x16x32_bf16(a, bb, acc[nt], 0, 0, 0);
      }
    }
    float lp[4] = {0.f, 0.f, 0.f, 0.f};
    float nwq[4];
#pragma unroll
    for (int i = 0; i < 4; i++) nwq[i] = (q < 3) ? nw_l[q * 4 + i] : 0.f;
#pragma unroll
    for (int nt = 0; nt < 4; nt++)
#pragma unroll
      for (int i = 0; i < 4; i++)
        lp[i] += leaky(acc[nt][i] + nwq[i] * wlA[nt]) * w2A[nt];
#pragma unroll
    for (int off = 1; off <= 8; off <<= 1)
#pragma unroll
      for (int i = 0; i < 4; i++) lp[i] += __shfl_xor(lp[i], off, 64);
    if (mrow == 0 && q < 3) {
#pragma unroll
      for (int i = 0; i < 4; i++) red_l[w][q * 4 + i] = lp[i];
    }
    __syncthreads();
    float lg[SAMPLE];
#pragma unroll
    for (int j = 0; j < SAMPLE; j++) lg[j] = red_l[0][j] + red_l[1][j];
    float mx = lg[0];
#pragma unroll
    for (int j = 1; j < SAMPLE; j++) mx = fmaxf(mx, lg[j]);
    float se = 0.f;
#pragma unroll
    for (int j = 0; j < SAMPLE; j++) { lg[j] = __expf(lg[j] - mx); se += lg[j]; }
    float inv = 1.f / se;
    float aggd = 0.f;
#pragma unroll
    for (int j = 0; j < SAMPLE; j++) aggd += lg[j] * inv * nvreg[j];
    svagg_l[u * 264 + 128 + d] = f2bf(aggd);
  }
  __syncthreads();

  // ---- Phase B ----------------------------------------------------------
  {
    f32x4 accB[4];
#pragma unroll
    for (int nt = 0; nt < 4; nt++) accB[nt] = (f32x4){0.f, 0.f, 0.f, 0.f};
#pragma unroll
    for (int ks = 0; ks < 8; ks++) {
      bfrag8 a = *(const bfrag8*)(svagg_l + mrow * 264 + q * 8 + ks * 32);
      const u16* pb = p3a + (w * 32 + ks) * 512 + lane * 8;
#pragma unroll
      for (int nt = 0; nt < 4; nt++) {
        bfrag8 bb = *(const bfrag8*)(pb + nt * 4096);
        accB[nt] = __builtin_amdgcn_mfma_f32_16x16x32_bf16(a, bb, accB[nt], 0, 0, 0);
      }
    }
#pragma unroll
    for (int nt = 0; nt < 4; nt++) {
      int col = (w * 4 + nt) * 16 + mrow;
#pragma unroll
      for (int i = 0; i < 4; i++) {
        int u2 = q * 4 + i;
        if (u2 < 13) ev_l[u2 * 128 + col] = tanh_f(accB[nt][i]);
      }
    }
    __syncthreads();
  }

  // ---- Phase C ----------------------------------------------------------
  {
    float evreg[SAMPLE];
#pragma unroll
    for (int j = 0; j < SAMPLE; j++) {
      float e = ev_l[(1 + j) * 128 + d];
      evreg[j] = e;
      nvs_l[j * 136 + d] = f2bf(e * sess_d);
    }
    if (d < SAMPLE) nw_l[d] = num[(long)src0 * SAMPLE + d];
    __syncthreads();

    f32x4 acc[4];
#pragma unroll
    for (int nt = 0; nt < 4; nt++) acc[nt] = (f32x4){0.f, 0.f, 0.f, 0.f};
#pragma unroll
    for (int ks = 0; ks < 4; ks++) {
      bfrag8 a = *(const bfrag8*)(nvs_l + mrow * 136 + q * 8 + ks * 32);
      const u16* pb = p1b + (w * 16 + ks) * 512 + lane * 8;
#pragma unroll
      for (int nt = 0; nt < 4; nt++) {
        bfrag8 bb = *(const bfrag8*)(pb + nt * 2048);
        acc[nt] = __builtin_amdgcn_mfma_f32_16x16x32_bf16(a, bb, acc[nt], 0, 0, 0);
      }
    }
    float lp[4] = {0.f, 0.f, 0.f, 0.f};
    float nwq[4];
#pragma unroll
    for (int i = 0; i < 4; i++) nwq[i] = (q < 3) ? nw_l[q * 4 + i] : 0.f;
#pragma unroll
    for (int nt = 0; nt < 4; nt++)
#pragma unroll
      for (int i = 0; i < 4; i++)
        lp[i] += leaky(acc[nt][i] + nwq[i] * wlB[nt]) * w2B[nt];
#pragma unroll
    for (int off = 1; off <= 8; off <<= 1)
#pragma unroll
      for (int i = 0; i < 4; i++) lp[i] += __shfl_xor(lp[i], off, 64);
    if (mrow == 0 && q < 3) {
#pragma unroll
      for (int i = 0; i < 4; i++) red_l[w][q * 4 + i] = lp[i];
    }
    __syncthreads();

    float lg[SAMPLE];
#pragma unroll
    for (int j = 0; j < SAMPLE; j++) lg[j] = red_l[0][j] + red_l[1][j];
    float mx = lg[0];
#pragma unroll
    for (int j = 1; j < SAMPLE; j++) mx = fmaxf(mx, lg[j]);
    float se = 0.f;
#pragma unroll
    for (int j = 0; j < SAMPLE; j++) { lg[j] = __expf(lg[j] - mx); se += lg[j]; }
    float inv = 1.f / se;
    float agg1d = 0.f;
#pragma unroll
    for (int j = 0; j < SAMPLE; j++) agg1d += lg[j] * inv * evreg[j];
    agg1_l[d] = agg1d;
    __syncthreads();

    float accf = 0.f;
#pragma unroll 4
    for (int k4 = 0; k4 < 32; k4++) {
      float4 a4 = *(const float4*)&ev_l[4 * k4];
      float4 g4 = *(const float4*)&agg1_l[4 * k4];
      accf += a4.x * W3b[(4 * k4 + 0) * D + d] + a4.y * W3b[(4 * k4 + 1) * D + d] +
              a4.z * W3b[(4 * k4 + 2) * D + d] + a4.w * W3b[(4 * k4 + 3) * D + d] +
              g4.x * W3b[(D + 4 * k4 + 0) * D + d] + g4.y * W3b[(D + 4 * k4 + 1) * D + d] +
              g4.z * W3b[(D + 4 * k4 + 2) * D + d] + g4.w * W3b[(D + 4 * k4 + 3) * D + d];
    }
    hg[(long)bs * D + d] = tanh_f(accf);
  }
}

// ---------------------------------------------------------------------------
// K5AB: fused local-attention + mirror gate (+highway on fin=1). 128 thr.
__global__ __launch_bounds__(128) void k5ab(fpp x, const int* __restrict__ adj,
                                            fpp a_loc, fpp w1, fpp w2,
                                            fpw xout, fpw mir,
                                            fpp hw, fpp h, fpw x_dot,
                                            float* __restrict__ h_local,
                                            int fin) {
  int b = blockIdx.x / S;
  int row = blockIdx.x % S;
  int tid = threadIdx.x;
  __shared__ float xi_s[D];
  __shared__ float ak_s[4][D];
  __shared__ float alpha_s[S];
  __shared__ float part_s[4][2][64];
  long idx = ((long)b * S + row) * D + tid;
  xi_s[tid] = x[idx];
#pragma unroll
  for (int k = 0; k < 4; k++) ak_s[k][tid] = a_loc[(long)k * D + tid];
  __syncthreads();
  {
    int j = tid & 63, hf = tid >> 6;
    float a0 = 0.f, a1 = 0.f, a2 = 0.f, a3 = 0.f;
    if (j < S) {
      const float* xj = x + ((long)b * S + j) * D + hf * 64;
      int off = hf * 64;
      for (int dd = 0; dd < 64; dd++) {
        float prod = xi_s[off + dd] * xj[dd];
        a0 += prod * ak_s[0][off + dd];
        a1 += prod * ak_s[1][off + dd];
        a2 += prod * ak_s[2][off + dd];
        a3 += prod * ak_s[3][off + dd];
      }
    }
    part_s[0][hf][j] = a0; part_s[1][hf][j] = a1;
    part_s[2][hf][j] = a2; part_s[3][hf][j] = a3;
  }
  __syncthreads();
  if (tid < 64) {
    int j = tid;
    float att;
    if (j < S) {
      float acc0 = part_s[0][0][j] + part_s[0][1][j];
      float acc1 = part_s[1][0][j] + part_s[1][1][j];
      float acc2 = part_s[2][0][j] + part_s[2][1][j];
      float acc3 = part_s[3][0][j] + part_s[3][1][j];
      int av = adj[((long)b * S + row) * S + j];
      att = -9e15f;  // reference's own sentinel
      if (av == 1) att = leaky(acc0);
      else if (av == 2) att = leaky(acc1);
      else if (av == 3) att = leaky(acc2);
      else if (av == 4) att = leaky(acc3);
    } else {
      att = NEG_BIG;
    }
    float mx = att;
#pragma unroll
    for (int o = 32; o > 0; o >>= 1) mx = fmaxf(mx, __shfl_xor(mx, o, 64));
    float e = __expf(att - mx);
    float ssum = e;
#pragma unroll
    for (int o = 32; o > 0; o >>= 1) ssum += __shfl_xor(ssum, o, 64);
    if (j < S) alpha_s[j] = e / ssum;
  }
  __syncthreads();
  float xn = 0.f;
  for (int j = 0; j < S; j++) xn += alpha_s[j] * x[((long)b * S + j) * D + tid];
  float mv = mir[idx];
  ak_s[0][tid] = xn;
  ak_s[1][tid] = mv;
  __syncthreads();
  float a2m = 0.f;
  for (int k = 0; k < D; k++)
    a2m += ak_s[0][k] * w1[(long)k * D + tid] + ak_s[1][k] * w2[(long)k * D + tid];
  float g = sigm(a2m);
  float xg = g * xn + (1.f - g) * mv;
  if (!fin) {
    xout[idx] = xg;
    mir[idx] = g * mv + (1.f - g) * xn;
    return;
  }
  float hv = h[idx];
  ak_s[2][tid] = hv;
  ak_s[3][tid] = xg;
  __syncthreads();
  float a3m = 0.f;
  for (int k = 0; k < D; k++)
    a3m += ak_s[2][k] * hw[(long)k * D + tid] + ak_s[3][k] * hw[(long)(D + k) * D + tid];
  float gh = sigm(a3m);
  float xd = gh * hv + (1.f - gh) * xg;
  x_dot[idx] = xd;
  if (row == S - 1) h_local[(long)b * D + tid] = xd;
}

// ---------------------------------------------------------------------------
// K7: simi loss. Block per (b,i), 128 threads (split-dot). atomicAdd to ws.
__global__ __launch_bounds__(128) void k7_simi(fpp hf1, fpp hf2,
                                               const int* __restrict__ simi_mask,
                                               float* __restrict__ loss) {
  int b = blockIdx.x / S;
  int i = blockIdx.x % S;
  int t = threadIdx.x;
  __shared__ float hi_s[D];
  __shared__ float part_s[2][64];
  hi_s[t] = hf1[((long)b * S + i) * D + t];
  __syncthreads();
  {
    int j = t & 63, hf = t >> 6;
    float acc = 0.f;
    if (j < S) {
      const float* r = hf2 + ((long)b * S + j) * D + hf * 64;
      int off = hf * 64;
      for (int dd = 0; dd < 64; dd++) acc += hi_s[off + dd] * r[dd];
    }
    part_s[hf][j] = acc;
  }
  __syncthreads();
  if (t < 64) {
    int j = t;
    float sim = (j < S) ? (part_s[0][j] + part_s[1][j]) * (1.0f / TEMPV) : NEG_BIG;
    float mx = sim;
#pragma unroll
    for (int o = 32; o > 0; o >>= 1) mx = fmaxf(mx, __shfl_xor(mx, o, 64));
    float e = __expf(sim - mx);
    float ssum = e;
#pragma unroll
    for (int o = 32; o > 0; o >>= 1) ssum += __shfl_xor(ssum, o, 64);
    float contrib = 0.f;
    if (j < S) {
      float p = e / ssum;
      float l = -__logf(p + 1e-8f);
      if (simi_mask[((long)b * S + i) * S + j] == 1) contrib = l;
    }
#pragma unroll
    for (int o = 32; o > 0; o >>= 1) contrib += __shfl_xor(contrib, o, 64);
    if (j == 0) atomicAdd(loss, contrib);
  }
}

// ---------------------------------------------------------------------------
// K8: GLU epilogue per batch, 512 threads = 4 s-groups (serial 50 -> 13).
__global__ __launch_bounds__(512) void k8_glu(
    fpp hg, fpp x_dot, fpp pos, fpp h_local, const float* __restrict__ mi,
    fpp glu1, fpp glu2, fpp glu4, fpp glu4b, fpp w_s, fpp gate_w, fpw zh) {
  int b = blockIdx.x;
  int t = threadIdx.x;
  int d = t & 127;
  int g = t >> 7;   // s-group 0..3
  __shared__ float hs_s[D], hl_s[D];
  __shared__ float hp_g[4][D], part[4][D], zg_g[4][D];
  __shared__ float red2[4][2];
  float msf = 0.f;
  for (int s = 0; s < S; s++) msf += mi[b * S + s];
  float hsacc = 0.f;
  for (int s = g * 13; s < min(S, g * 13 + 13); s++)
    hsacc += hg[((long)b * S + s) * D + d] * mi[b * S + s];
  part[g][d] = hsacc;
  if (g == 1) hl_s[d] = h_local[(long)b * D + d];
  __syncthreads();
  if (g == 0) hs_s[d] = (part[0][d] + part[1][d] + part[2][d] + part[3][d]) / msf;
  __syncthreads();
  float c = glu4b[d];
  for (int k = 0; k < D; k++)
    c += hs_s[k] * glu2[(long)k * D + d] + hl_s[k] * glu4[(long)k * D + d];
  float wsd = w_s[d];
  float zg = 0.f;
  for (int it = 0; it < 13; it++) {
    int s = g * 13 + it;
    bool act = s < S;
    float hp = 0.f;
    if (act) {
      hp = x_dot[((long)b * S + s) * D + d] + pos[(long)s * D + d];
      hp_g[g][d] = hp;
    }
    __syncthreads();
    if (act) {
      float acc = c;
      for (int k = 0; k < D; k++) acc += hp_g[g][k] * glu1[(long)k * D + d];
      float v = sigm(acc) * wsd;
#pragma unroll
      for (int o = 32; o > 0; o >>= 1) v += __shfl_down(v, o, 64);
      if ((t & 63) == 0) red2[g][(t >> 6) & 1] = v;
    }
    __syncthreads();
    if (act) {
      float beta = (red2[g][0] + red2[g][1]) * mi[b * S + s];
      zg += beta * hp;
    }
    __syncthreads();
  }
  zg_g[g][d] = zg;
  __syncthreads();
  if (g == 0) {
    float zgf = zg_g[0][d] + zg_g[1][d] + zg_g[2][d] + zg_g[3][d];
    hp_g[0][d] = zgf;
  }
  __syncthreads();
  if (g == 0) {
    float zgf = hp_g[0][d];
    float acc = 0.f;
    for (int k = 0; k < D; k++)
      acc += hp_g[0][k] * gate_w[(long)k * D + d] +
             hl_s[k] * gate_w[(long)(D + k) * D + d];
    float gf = sigm(acc) * MUV;
    zh[(long)b * D + d] = gf * hl_s[d] + (1.f - gf) * zgf;
  }
}

// ---------------------------------------------------------------------------
// K9: scores = zh(128x128) @ emb[1:]^T via bf16 MFMA. Template on emb dtype
// (bf16 path loads B-frags directly, no converts).
template <typename ET>
__global__ __launch_bounds__(256) void k9_scores(fpp zh, const ET* __restrict__ emb,
                                                 fpp loss, float* __restrict__ out) {
  int t = threadIdx.x;
  if (blockIdx.x == 0 && t == 0) out[0] = loss[0] * (1.0f / (float)B);
  int lane = t & 63;
  int w = t >> 6;
  int q = lane >> 4;
  int mrow = lane & 15;
  long n = (long)blockIdx.x * 64 + w * 16 + mrow;
  bool valid = n < NSC;
  long nrow = valid ? (n + 1) : 1;
  bfrag8 bfr[4];
#pragma unroll
  for (int ks = 0; ks < 4; ks++) {
    if constexpr (sizeof(ET) == 2) {
      bfr[ks] = *(const bfrag8*)(const void*)(emb + nrow * D + ks * 32 + q * 8);
    } else {
      const float* src = (const float*)(emb + nrow * D + ks * 32 + q * 8);
      float4 lo = *(const float4*)src;
      float4 hi = *(const float4*)(src + 4);
      bfrag8 bb;
      bb[0] = (short)f2bf(lo.x); bb[1] = (short)f2bf(lo.y);
      bb[2] = (short)f2bf(lo.z); bb[3] = (short)f2bf(lo.w);
      bb[4] = (short)f2bf(hi.x); bb[5] = (short)f2bf(hi.y);
      bb[6] = (short)f2bf(hi.z); bb[7] = (short)f2bf(hi.w);
      bfr[ks] = bb;
    }
  }
#pragma unroll
  for (int mt = 0; mt < 8; mt++) {
    f32x4 acc = (f32x4){0.f, 0.f, 0.f, 0.f};
#pragma unroll
    for (int ks = 0; ks < 4; ks++) {
      const float* za = zh + (long)(mt * 16 + mrow) * D + ks * 32 + q * 8;
      float4 lo = *(const float4*)za;
      float4 hi = *(const float4*)(za + 4);
      bfrag8 a;
      a[0] = (short)f2bf(lo.x); a[1] = (short)f2bf(lo.y);
      a[2] = (short)f2bf(lo.z); a[3] = (short)f2bf(lo.w);
      a[4] = (short)f2bf(hi.x); a[5] = (short)f2bf(hi.y);
      a[6] = (short)f2bf(hi.z); a[7] = (short)f2bf(hi.w);
      acc = __builtin_amdgcn_mfma_f32_16x16x32_bf16(a, bfr[ks], acc, 0, 0, 0);
    }
    if (valid) {
#pragma unroll
      for (int i = 0; i < 4; i++) {
        int m = mt * 16 + q * 4 + i;
        out[1 + (long)m * NSC + n] = acc[i];
      }
    }
  }
}

// ---------------------------------------------------------------------------
extern "C" void kernel_launch(void* const* d_in, const int* in_sizes, int n_in,
                              void* d_out, int out_size, void* d_ws, size_t ws_size,
                              hipStream_t stream) {
  (void)in_sizes; (void)n_in; (void)out_size;
  const int* inputs = (const int*)d_in[0];
  const int* adj = (const int*)d_in[1];
  const int* item = (const int*)d_in[2];
  const int* simi_mask = (const int*)d_in[3];
  const int* as0 = (const int*)d_in[4];
  const int* as1 = (const int*)d_in[5];
  const int* ss0 = (const int*)d_in[6];
  const int* ss1 = (const int*)d_in[7];
  // d_in[8]: last_item_mask — structurally [:, -1]; hardcoded in k5ab(fin).
  const int* adj_all = (const int*)d_in[9];
  fpp num = (fpp)d_in[10];
  fpp emb = (fpp)d_in[11];
  fpp pos = (fpp)d_in[12];
  fpp a_local = (fpp)d_in[13];
  fpp mir_w1 = (fpp)d_in[14];
  fpp mir_w2 = (fpp)d_in[15];
  fpp gw1 = (fpp)d_in[16];
  fpp gw2 = (fpp)d_in[17];
  fpp gw3 = (fpp)d_in[18];
  fpp attr_w = (fpp)d_in[19];
  fpp highway_w = (fpp)d_in[20];
  fpp glu1 = (fpp)d_in[21];
  fpp glu2 = (fpp)d_in[22];
  fpp glu4 = (fpp)d_in[23];
  fpp glu4b = (fpp)d_in[24];
  fpp w_s = (fpp)d_in[25];
  fpp gate_w = (fpp)d_in[26];

  // fp32 scratch inside d_out: 6 * 819200 = 4,915,200 elts <= 5,119,873.
  float* ob = (float*)d_out;
  constexpr long BSD_ = (long)B * S * D;  // 819200
  fpw s_h = ob + 0 * BSD_;
  fpw s_hf1 = ob + 1 * BSD_;  // later x_dot
  fpw s_hf2 = ob + 2 * BSD_;  // later h_global
  fpw s_mir = ob + 3 * BSD_;
  fpw s_xA = ob + 4 * BSD_;
  fpw s_xB = ob + 5 * BSD_;

  // d_ws layout: small fp32 state (loss at ws[0]) .. float 72000; prepped
  // weight frags at byte 288,000; bf16 emb (10.24 MB) at byte 491,520;
  // split-kG agg buffer (21.3 MB bf16) at byte 10,731,520 (guarded).
  float* ws = (float*)d_ws;
  float* w_loss = ws + 0;
  float* w_mi = ws + 16;                // B*S
  float* w_sess = w_mi + (long)B * S;   // B*D
  float* w_hl = w_sess + (long)B * D;   // B*D
  float* w_zh = w_hl + (long)B * D;     // B*D
  u16* p1a = (u16*)(ws + 72000);
  u16* p1b = (u16*)(ws + 72000 + 8192);
  u16* p3a = (u16*)(ws + 72000 + 16384);
  u16* p3b = (u16*)(ws + 72000 + 32768);
  u16* embbf = (u16*)((char*)d_ws + 491520);
  u16* aggws = (u16*)((char*)d_ws + 10731520);
  bool useBF = ws_size >= (size_t)12 * 1024 * 1024;
  // split path needs bytes through 10,731,520 + 10,649,600*2 = 32,030,720
  bool useSplit = useBF && ws_size >= ((size_t)32 << 20);

  hipMemsetAsync((void*)w_loss, 0, sizeof(float), stream);

  kprep4<<<384, 256, 0, stream>>>(gw1, gw3, p1a, p1b, p3a, p3b);
  if (useBF)
    kprep_emb<<<(NODES * D / 4 + 255) / 256, 256, 0, stream>>>(emb, embbf);

  if (useBF)
    k1_gather<u16><<<B * S, 128, 0, stream>>>(inputs, as0, as1, ss0, ss1,
                                              embbf, attr_w, s_h, s_hf1, s_hf2,
                                              w_mi, s_xA, s_mir);
  else
    k1_gather<float><<<B * S, 128, 0, stream>>>(inputs, as0, as1, ss0, ss1,
                                                emb, attr_w, s_h, s_hf1, s_hf2,
                                                w_mi, s_xA, s_mir);
  // k7 consumes hf1/hf2 before kG reuses the hf2 slot as h_global.
  k7_simi<<<B * S, 128, 0, stream>>>(s_hf1, s_hf2, simi_mask, w_loss);
  k2_sess<<<B, 128, 0, stream>>>(inputs, item, emb, w_sess);

  if (useSplit) {
    kGA_unit<u16><<<B * S * 13, 64, 0, stream>>>(inputs, adj_all, num, embbf,
                                                 w_sess, gw1, gw2, p1a, aggws);
    kGB_post<u16><<<B * S, 256, 0, stream>>>(inputs, adj_all, num, embbf,
                                             w_sess, gw1 + 129 * 128, gw2 + 128,
                                             gw3 + 256 * 128, p1b, p3a, aggws,
                                             s_hf2 /* h_global */);
  } else if (useBF) {
    kG_mono<u16><<<B * S, 128, 0, stream>>>(inputs, adj_all, num, embbf,
                                            w_sess, gw1, gw2,
                                            gw1 + 129 * 128, gw2 + 128,
                                            gw3 + 256 * 128, p1a, p1b, p3a,
                                            s_hf2 /* h_global */);
  } else {
    kG_mono<float><<<B * S, 128, 0, stream>>>(inputs, adj_all, num, emb,
                                              w_sess, gw1, gw2,
                                              gw1 + 129 * 128, gw2 + 128,
                                              gw3 + 256 * 128, p1a, p1b, p3a,
                                              s_hf2 /* h_global */);
  }

  k5ab<<<B * S, 128, 0, stream>>>(s_xA, adj, a_local, mir_w1, mir_w2,
                                  s_xB, s_mir, highway_w, s_h, s_hf1, w_hl, 0);
  k5ab<<<B * S, 128, 0, stream>>>(s_xB, adj, a_local + 4 * D,
                                  mir_w1 + (long)D * D, mir_w2 + (long)D * D,
                                  s_xA, s_mir, highway_w, s_h,
                                  s_hf1 /* x_dot */, w_hl, 1);
  k8_glu<<<B, 512, 0, stream>>>(s_hf2 /* h_global */, s_hf1 /* x_dot */, pos,
                                w_hl, w_mi, glu1, glu2, glu4, glu4b, w_s,
                                gate_w, w_zh);
  if (useBF)
    k9_scores<u16><<<(NSC + 63) / 64, 256, 0, stream>>>(w_zh, embbf, w_loss,
                                                        (float*)d_out);
  else
    k9_scores<float><<<(NSC + 63) / 64, 256, 0, stream>>>(w_zh, emb, w_loss,
                                                          (float*)d_out);
}

// Round 5
// 679.868 us; speedup vs baseline: 1.2035x; 1.0881x over previous
//
#include <hip/hip_runtime.h>
#include <hip/hip_bf16.h>
#include <type_traits>

// CombineGraph forward. B=128,S=50,D=128,NODES=40000,SAMPLE=12,NNEI=8,HOP=2.
// Round 17: exploit inter-kernel parallelism. The pipeline's independent
// chains (kG global branch | k5ab local chain | k7 loss) are fused into two
// mega-launches with block-range routing:
//   kF1 = kGA (2 units/wave: B-frags shared, traffic halved) U k5ab0 U k7
//   kF2 = kGB (128-thr port of verified mono phases B/C) U k5ab1
// All arithmetic bodies are verbatim from harness-verified kernels.

#define B 128
#define S 50
#define D 128
#define SAMPLE 12
#define NNEI 8
#define NODES 40000
#define NSC (NODES - 1)
#define LEAK 0.2f
#define TEMPV 0.5f
#define MUV 0.1f
#define NEG_BIG -3.0e38f
#define NUNITS (B * S * 13)  // 83200
#define NGA (NUNITS / 4)     // 20800 blocks, 128 thr = 2 waves x 2 units

typedef const float* fpp;
typedef float* fpw;
typedef unsigned short u16;
typedef __attribute__((ext_vector_type(8))) short bfrag8;
typedef __attribute__((ext_vector_type(4))) float f32x4;

__device__ __forceinline__ float sigm(float x) { return 1.f / (1.f + __expf(-x)); }
__device__ __forceinline__ float tanh_f(float x) { return 1.f - 2.f / (__expf(2.f * x) + 1.f); }
__device__ __forceinline__ float leaky(float x) { return x >= 0.f ? x : LEAK * x; }
__device__ __forceinline__ u16 f2bf(float v) {
  __hip_bfloat16 h = __float2bfloat16(v);
  return *reinterpret_cast<u16*>(&h);
}
__device__ __forceinline__ float lde(const float* p, long i) { return p[i]; }
__device__ __forceinline__ float lde(const u16* p, long i) {
  union { unsigned int u; float f; } c;
  c.u = ((unsigned int)p[i]) << 16;
  return c.f;
}
__device__ __forceinline__ float bfu(short s) {
  union { unsigned u; float f; } c;
  c.u = ((unsigned)(unsigned short)s) << 16;
  return c.f;
}

template <typename ET>
__device__ __forceinline__ bfrag8 load_frag(const ET* __restrict__ emb, long row, int koff) {
  if constexpr (sizeof(ET) == 2) {
    return *(const bfrag8*)(const void*)(emb + row * D + koff);
  } else {
    const float* s = (const float*)(emb + row * D + koff);
    float4 lo = *(const float4*)s;
    float4 hi = *(const float4*)(s + 4);
    bfrag8 b;
    b[0] = (short)f2bf(lo.x); b[1] = (short)f2bf(lo.y);
    b[2] = (short)f2bf(lo.z); b[3] = (short)f2bf(lo.w);
    b[4] = (short)f2bf(hi.x); b[5] = (short)f2bf(hi.y);
    b[6] = (short)f2bf(hi.z); b[7] = (short)f2bf(hi.w);
    return b;
  }
}

__device__ __forceinline__ bfrag8 scale8(bfrag8 r, float4 sa, float4 sb) {
  bfrag8 o;
  o[0] = (short)f2bf(bfu(r[0]) * sa.x); o[1] = (short)f2bf(bfu(r[1]) * sa.y);
  o[2] = (short)f2bf(bfu(r[2]) * sa.z); o[3] = (short)f2bf(bfu(r[3]) * sa.w);
  o[4] = (short)f2bf(bfu(r[4]) * sb.x); o[5] = (short)f2bf(bfu(r[5]) * sb.y);
  o[6] = (short)f2bf(bfu(r[6]) * sb.z); o[7] = (short)f2bf(bfu(r[7]) * sb.w);
  return o;
}

// --------------------------- LDS overlays ---------------------------------
struct __align__(16) SMk5 { float xi[D]; float ak[4][D]; float alpha[56]; float part[4][2][64]; };
struct __align__(16) SMk7 { float hi[D]; float part[2][64]; };
struct __align__(16) SMga { u16 nvs[2][2][16 * 136]; };  // [wave][unit]
struct __align__(16) SMgb {
  u16 nvs[16 * 136];
  float ev[13 * 128];
  float agg1[128];
  float red[2][16];
  float nw[16];
  int svidx[16];
};
union __align__(16) SMF1 { SMk5 a; SMk7 b; SMga c; };
union __align__(16) SMF2 { SMk5 a; SMgb d; };

// ---------------------------------------------------------------------------
// KPREP_EMB: emb fp32 -> bf16 copy in ws (4 elems/thread).
__global__ __launch_bounds__(256) void kprep_emb(fpp emb, u16* __restrict__ out) {
  long i = ((long)blockIdx.x * 256 + threadIdx.x) * 4;
  if (i + 3 >= (long)NODES * D) return;
  float4 v = *(const float4*)(emb + i);
  out[i + 0] = f2bf(v.x); out[i + 1] = f2bf(v.y);
  out[i + 2] = f2bf(v.z); out[i + 3] = f2bf(v.w);
}

// ---------------------------------------------------------------------------
// KPREP4: four weight tensors -> bf16 B-fragment order.
__global__ __launch_bounds__(256) void kprep4(fpp gw1, fpp gw3,
                                              u16* __restrict__ p1a,
                                              u16* __restrict__ p1b,
                                              u16* __restrict__ p3a,
                                              u16* __restrict__ p3b) {
  int i = blockIdx.x * 256 + threadIdx.x;
  fpp W; u16* dst; int KS;
  if (i < 16384)      { W = gw1;             dst = p1a; KS = 4; }
  else if (i < 32768) { W = gw1 + 129 * 128; dst = p1b; KS = 4; i -= 16384; }
  else if (i < 65536) { W = gw3;             dst = p3a; KS = 8; i -= 32768; }
  else                { W = gw3 + 256 * 128; dst = p3b; KS = 8; i -= 65536; }
  int e = i & 7;
  int lane = (i >> 3) & 63;
  int rest = i >> 9;
  int ks = rest % KS, nt = rest / KS;
  int k = ks * 32 + ((lane >> 4) << 3) + e;
  int n = (nt << 4) + (lane & 15);
  dst[i] = f2bf(W[(long)k * 128 + n]);
}

// ---------------------------------------------------------------------------
// K1: h = emb[inputs]; hf1/hf2 pools; attr gate. Block per (b,s), 128 thr.
template <typename ET>
__global__ __launch_bounds__(128) void k1_gather(
    const int* __restrict__ inputs, const int* __restrict__ as0,
    const int* __restrict__ as1, const int* __restrict__ ss0,
    const int* __restrict__ ss1, const ET* __restrict__ emb, fpp attr_w,
    fpw h, fpw hf1, fpw hf2, float* __restrict__ mi, fpw xA, fpw mir) {
  int bs = blockIdx.x;
  int d = threadIdx.x;
  __shared__ float h_s[D], hf1_s[D];
  int inp = inputs[bs];
  float hv = lde(emb, (long)inp * D + d);
  const int* lists[4] = {as0, as1, ss0, ss1};
  float p[4];
#pragma unroll
  for (int l = 0; l < 4; l++) {
    float sum = 0.f, cnt = 0.f;
    const int* L = lists[l] + (long)bs * NNEI;
#pragma unroll
    for (int n = 0; n < NNEI; n++) {
      int idx = L[n];
      if (idx != 0) { sum += lde(emb, (long)idx * D + d); cnt += 1.f; }
    }
    p[l] = sum / (cnt + 1e-8f);
  }
  float hf1v = 0.5f * (p[0] + p[1]);
  float hf2v = 0.5f * (p[2] + p[3]);
  h_s[d] = hv;
  hf1_s[d] = hf1v;
  __syncthreads();
  float acc = 0.f;
  for (int k = 0; k < D; k++)
    acc += h_s[k] * attr_w[(long)k * D + d] + hf1_s[k] * attr_w[(long)(D + k) * D + d];
  float g = sigm(acc);
  float hfv = g * hv + (1.f - g) * hf1v;
  long o = (long)bs * D + d;
  h[o] = hv; hf1[o] = hf1v; hf2[o] = hf2v; xA[o] = hv; mir[o] = hfv;
  if (d == 0) mi[bs] = (inp != 0) ? 1.f : 0.f;
}

// ---------------------------------------------------------------------------
// K2: sess[b,:] = sum_s emb[item[b,s]]*mi / sum_s mi
__global__ __launch_bounds__(128) void k2_sess(const int* __restrict__ inputs,
                                               const int* __restrict__ item,
                                               fpp emb, fpw sess) {
  int b = blockIdx.x;
  int d = threadIdx.x;
  float acc = 0.f, ms = 0.f;
  for (int s = 0; s < S; s++) {
    int inp = inputs[b * S + s];
    float m = (inp != 0) ? 1.f : 0.f;
    int it = item[b * S + s];
    acc += emb[(long)it * D + d] * m;
    ms += m;
  }
  sess[(long)b * D + d] = acc / ms;
}

// ---------------------------------------------------------------------------
// dev_kga2: TWO phase-A units per wave (B-frags loaded once, used twice).
// Per-unit math verbatim from the verified R16 kGA_unit.
template <typename ET>
__device__ __forceinline__ void dev_kga2(
    u16* __restrict__ nvs0, u16* __restrict__ nvs1,
    const int* __restrict__ inputs, const int* __restrict__ adj_all, fpp num,
    const ET* __restrict__ emb, fpp sess, fpp W1a, fpp W2a,
    const u16* __restrict__ p1a, u16* __restrict__ aggws, int gu0, int lane) {
  int q = lane >> 4;
  int mrow = lane & 15;
  float wl8[8], w28[8];
#pragma unroll
  for (int nt = 0; nt < 8; nt++) {
    int col = nt * 16 + mrow;
    wl8[nt] = W1a[(long)D * D + col];
    w28[nt] = W2a[col];
  }
  bfrag8 sA[2][4];
  float nwq[2][4];
#pragma unroll
  for (int g = 0; g < 2; g++) {
    int gu = gu0 + g;
    int bs = gu / 13;
    int u = gu - bs * 13;
    int b = bs / S;
    int src0 = inputs[bs];
    int srcu = (u == 0) ? src0 : adj_all[(long)src0 * SAMPLE + (u - 1)];
    int rid = adj_all[(long)srcu * SAMPLE + (mrow < 12 ? mrow : 0)];
#pragma unroll
    for (int i = 0; i < 4; i++)
      nwq[g][i] = (q < 3) ? num[(long)srcu * SAMPLE + q * 4 + i] : 0.f;
    const float* sessb = sess + (long)b * D;
    u16* nb = g ? nvs1 : nvs0;
    bfrag8 raw[4];
#pragma unroll
    for (int ks = 0; ks < 4; ks++)
      raw[ks] = load_frag(emb, (long)rid, ks * 32 + q * 8);
#pragma unroll
    for (int ks = 0; ks < 4; ks++)
      *(bfrag8*)(nb + mrow * 136 + ks * 32 + q * 8) = raw[ks];
#pragma unroll
    for (int ks = 0; ks < 4; ks++) {
      float4 sa = *(const float4*)(sessb + ks * 32 + q * 8);
      float4 sb = *(const float4*)(sessb + ks * 32 + q * 8 + 4);
      sA[g][ks] = scale8(raw[ks], sa, sb);
    }
  }
  float lp[2][4] = {{0.f, 0.f, 0.f, 0.f}, {0.f, 0.f, 0.f, 0.f}};
#pragma unroll
  for (int nt = 0; nt < 8; nt++) {
    f32x4 acc0 = (f32x4){0.f, 0.f, 0.f, 0.f};
    f32x4 acc1 = (f32x4){0.f, 0.f, 0.f, 0.f};
#pragma unroll
    for (int ks = 0; ks < 4; ks++) {
      bfrag8 bb = *(const bfrag8*)(p1a + ks * 512 + lane * 8 + nt * 2048);
      acc0 = __builtin_amdgcn_mfma_f32_16x16x32_bf16(sA[0][ks], bb, acc0, 0, 0, 0);
      acc1 = __builtin_amdgcn_mfma_f32_16x16x32_bf16(sA[1][ks], bb, acc1, 0, 0, 0);
    }
#pragma unroll
    for (int i = 0; i < 4; i++) {
      lp[0][i] += leaky(acc0[i] + nwq[0][i] * wl8[nt]) * w28[nt];
      lp[1][i] += leaky(acc1[i] + nwq[1][i] * wl8[nt]) * w28[nt];
    }
  }
#pragma unroll
  for (int off = 1; off <= 8; off <<= 1)
#pragma unroll
    for (int g = 0; g < 2; g++)
#pragma unroll
      for (int i = 0; i < 4; i++) lp[g][i] += __shfl_xor(lp[g][i], off, 64);
#pragma unroll
  for (int g = 0; g < 2; g++) {
    float m4 = (q < 3) ? fmaxf(fmaxf(lp[g][0], lp[g][1]), fmaxf(lp[g][2], lp[g][3]))
                       : NEG_BIG;
    m4 = fmaxf(m4, __shfl_xor(m4, 16, 64));
    m4 = fmaxf(m4, __shfl_xor(m4, 32, 64));
    float e0 = 0.f, e1 = 0.f, e2 = 0.f, e3 = 0.f, ssum = 0.f;
    if (q < 3) {
      e0 = __expf(lp[g][0] - m4); e1 = __expf(lp[g][1] - m4);
      e2 = __expf(lp[g][2] - m4); e3 = __expf(lp[g][3] - m4);
      ssum = e0 + e1 + e2 + e3;
    }
    ssum += __shfl_xor(ssum, 16, 64);
    ssum += __shfl_xor(ssum, 32, 64);
    float inv = 1.f / ssum;
    float al[4] = {e0 * inv, e1 * inv, e2 * inv, e3 * inv};
    float aj[12];
#pragma unroll
    for (int j = 0; j < 12; j++) aj[j] = __shfl(al[j & 3], (j >> 2) << 4, 64);
    const u16* nb = g ? nvs1 : nvs0;
    float a0 = 0.f, a1 = 0.f;
#pragma unroll
    for (int j = 0; j < 12; j++) {
      unsigned pv = *(const unsigned*)(nb + j * 136 + lane * 2);
      union { unsigned u; float f; } lo, hi;
      lo.u = pv << 16; hi.u = pv & 0xffff0000u;
      a0 += aj[j] * lo.f; a1 += aj[j] * hi.f;
    }
    unsigned pk = ((unsigned)f2bf(a1) << 16) | (unsigned)f2bf(a0);
    *(unsigned*)(aggws + (long)(gu0 + g) * 128 + lane * 2) = pk;
  }
}

// ---------------------------------------------------------------------------
// dev_kgb: phases B/C + final per bs at 128 thr — the verified mono phase-B/C
// code with phase-B A-frags redirected to emb rows (sv) and aggws (agg).
template <typename ET>
__device__ __forceinline__ void dev_kgb(
    SMgb& sm, const int* __restrict__ inputs, const int* __restrict__ adj_all,
    fpp num, const ET* __restrict__ emb, fpp sess, fpp W1b, fpp W2b, fpp W3b,
    const u16* __restrict__ p1b, const u16* __restrict__ p3a,
    const u16* __restrict__ aggws, fpw hg, int bs) {
  int b = bs / S;
  int d = threadIdx.x;
  int lane = d & 63;
  int w = d >> 6;
  int q = lane >> 4;
  int mrow = lane & 15;

#pragma unroll
  for (int r = 12; r < 16; r++) {
    sm.nvs[r * 136 + d] = 0;
    if (d < 8) sm.nvs[r * 136 + 128 + d] = 0;
  }
  int src0 = inputs[bs];
  if (d < 16)
    sm.svidx[d] = (d == 0) ? src0 : (d <= 12 ? adj_all[(long)src0 * SAMPLE + d - 1] : 0);
  if (d < SAMPLE) sm.nw[d] = num[(long)src0 * SAMPLE + d];
  float sess_d = sess[(long)b * D + d];
  __syncthreads();

  // ---- Phase B: [sv|agg] (13x256) @ W3a -> ev (tanh); wave owns 4 col-tiles
  {
    long svr = sm.svidx[mrow];
    f32x4 accB[4];
#pragma unroll
    for (int nt = 0; nt < 4; nt++) accB[nt] = (f32x4){0.f, 0.f, 0.f, 0.f};
#pragma unroll
    for (int ks = 0; ks < 4; ks++) {
      bfrag8 a = (bfrag8){0, 0, 0, 0, 0, 0, 0, 0};
      if (mrow < 13) a = load_frag(emb, svr, ks * 32 + q * 8);
      const u16* pb = p3a + (w * 32 + ks) * 512 + lane * 8;
#pragma unroll
      for (int nt = 0; nt < 4; nt++)
        accB[nt] = __builtin_amdgcn_mfma_f32_16x16x32_bf16(
            a, *(const bfrag8*)(pb + nt * 4096), accB[nt], 0, 0, 0);
    }
#pragma unroll
    for (int ks = 4; ks < 8; ks++) {
      bfrag8 a = (bfrag8){0, 0, 0, 0, 0, 0, 0, 0};
      if (mrow < 13)
        a = *(const bfrag8*)(aggws + ((long)bs * 13 + mrow) * 128 + (ks - 4) * 32 + q * 8);
      const u16* pb = p3a + (w * 32 + ks) * 512 + lane * 8;
#pragma unroll
      for (int nt = 0; nt < 4; nt++)
        accB[nt] = __builtin_amdgcn_mfma_f32_16x16x32_bf16(
            a, *(const bfrag8*)(pb + nt * 4096), accB[nt], 0, 0, 0);
    }
#pragma unroll
    for (int nt = 0; nt < 4; nt++) {
      int col = (w * 4 + nt) * 16 + mrow;
#pragma unroll
      for (int i = 0; i < 4; i++) {
        int u2 = q * 4 + i;
        if (u2 < 13) sm.ev[u2 * 128 + col] = tanh_f(accB[nt][i]);
      }
    }
  }
  __syncthreads();

  // ---- Phase C: hop-1 unit (mono verbatim) ------------------------------
  {
    float w2B[4], wlB[4];
#pragma unroll
    for (int nt = 0; nt < 4; nt++) {
      int col = (w * 4 + nt) * 16 + mrow;
      w2B[nt] = W2b[col];
      wlB[nt] = W1b[(long)D * D + col];
    }
    float evreg[SAMPLE];
#pragma unroll
    for (int j = 0; j < SAMPLE; j++) {
      float e = sm.ev[(1 + j) * 128 + d];
      evreg[j] = e;
      sm.nvs[j * 136 + d] = f2bf(e * sess_d);
    }
    __syncthreads();

    f32x4 acc[4];
#pragma unroll
    for (int nt = 0; nt < 4; nt++) acc[nt] = (f32x4){0.f, 0.f, 0.f, 0.f};
#pragma unroll
    for (int ks = 0; ks < 4; ks++) {
      bfrag8 a = *(const bfrag8*)(sm.nvs + mrow * 136 + q * 8 + ks * 32);
      const u16* pb = p1b + (w * 16 + ks) * 512 + lane * 8;
#pragma unroll
      for (int nt = 0; nt < 4; nt++) {
        bfrag8 bb = *(const bfrag8*)(pb + nt * 2048);
        acc[nt] = __builtin_amdgcn_mfma_f32_16x16x32_bf16(a, bb, acc[nt], 0, 0, 0);
      }
    }
    float lp[4] = {0.f, 0.f, 0.f, 0.f};
    float nwq[4];
#pragma unroll
    for (int i = 0; i < 4; i++) nwq[i] = (q < 3) ? sm.nw[q * 4 + i] : 0.f;
#pragma unroll
    for (int nt = 0; nt < 4; nt++)
#pragma unroll
      for (int i = 0; i < 4; i++)
        lp[i] += leaky(acc[nt][i] + nwq[i] * wlB[nt]) * w2B[nt];
#pragma unroll
    for (int off = 1; off <= 8; off <<= 1)
#pragma unroll
      for (int i = 0; i < 4; i++) lp[i] += __shfl_xor(lp[i], off, 64);
    if (mrow == 0 && q < 3) {
#pragma unroll
      for (int i = 0; i < 4; i++) sm.red[w][q * 4 + i] = lp[i];
    }
    __syncthreads();

    float lg[SAMPLE];
#pragma unroll
    for (int j = 0; j < SAMPLE; j++) lg[j] = sm.red[0][j] + sm.red[1][j];
    float mx = lg[0];
#pragma unroll
    for (int j = 1; j < SAMPLE; j++) mx = fmaxf(mx, lg[j]);
    float se = 0.f;
#pragma unroll
    for (int j = 0; j < SAMPLE; j++) { lg[j] = __expf(lg[j] - mx); se += lg[j]; }
    float inv = 1.f / se;
    float agg1d = 0.f;
#pragma unroll
    for (int j = 0; j < SAMPLE; j++) agg1d += lg[j] * inv * evreg[j];
    sm.agg1[d] = agg1d;
    __syncthreads();

    float accf = 0.f;
#pragma unroll 4
    for (int k4 = 0; k4 < 32; k4++) {
      float4 a4 = *(const float4*)&sm.ev[4 * k4];
      float4 g4 = *(const float4*)&sm.agg1[4 * k4];
      accf += a4.x * W3b[(4 * k4 + 0) * D + d] + a4.y * W3b[(4 * k4 + 1) * D + d] +
              a4.z * W3b[(4 * k4 + 2) * D + d] + a4.w * W3b[(4 * k4 + 3) * D + d] +
              g4.x * W3b[(D + 4 * k4 + 0) * D + d] + g4.y * W3b[(D + 4 * k4 + 1) * D + d] +
              g4.z * W3b[(D + 4 * k4 + 2) * D + d] + g4.w * W3b[(D + 4 * k4 + 3) * D + d];
    }
    hg[(long)bs * D + d] = tanh_f(accf);
  }
}

// ---------------------------------------------------------------------------
// dev_k5ab: fused local-attention + mirror gate (+highway on fin=1).
__device__ __forceinline__ void dev_k5ab(SMk5& sm, fpp x, const int* __restrict__ adj,
                                         fpp a_loc, fpp w1, fpp w2, fpw xout,
                                         fpw mir, fpp hw, fpp h, fpw x_dot,
                                         float* __restrict__ h_local, int bs, int fin) {
  int b = bs / S;
  int row = bs % S;
  int tid = threadIdx.x;
  long idx = ((long)b * S + row) * D + tid;
  sm.xi[tid] = x[idx];
#pragma unroll
  for (int k = 0; k < 4; k++) sm.ak[k][tid] = a_loc[(long)k * D + tid];
  __syncthreads();
  {
    int j = tid & 63, hf = tid >> 6;
    float a0 = 0.f, a1 = 0.f, a2 = 0.f, a3 = 0.f;
    if (j < S) {
      const float* xj = x + ((long)b * S + j) * D + hf * 64;
      int off = hf * 64;
      for (int dd = 0; dd < 64; dd++) {
        float prod = sm.xi[off + dd] * xj[dd];
        a0 += prod * sm.ak[0][off + dd];
        a1 += prod * sm.ak[1][off + dd];
        a2 += prod * sm.ak[2][off + dd];
        a3 += prod * sm.ak[3][off + dd];
      }
    }
    sm.part[0][hf][j] = a0; sm.part[1][hf][j] = a1;
    sm.part[2][hf][j] = a2; sm.part[3][hf][j] = a3;
  }
  __syncthreads();
  if (tid < 64) {
    int j = tid;
    float att;
    if (j < S) {
      float acc0 = sm.part[0][0][j] + sm.part[0][1][j];
      float acc1 = sm.part[1][0][j] + sm.part[1][1][j];
      float acc2 = sm.part[2][0][j] + sm.part[2][1][j];
      float acc3 = sm.part[3][0][j] + sm.part[3][1][j];
      int av = adj[((long)b * S + row) * S + j];
      att = -9e15f;  // reference's own sentinel
      if (av == 1) att = leaky(acc0);
      else if (av == 2) att = leaky(acc1);
      else if (av == 3) att = leaky(acc2);
      else if (av == 4) att = leaky(acc3);
    } else {
      att = NEG_BIG;
    }
    float mx = att;
#pragma unroll
    for (int o = 32; o > 0; o >>= 1) mx = fmaxf(mx, __shfl_xor(mx, o, 64));
    float e = __expf(att - mx);
    float ssum = e;
#pragma unroll
    for (int o = 32; o > 0; o >>= 1) ssum += __shfl_xor(ssum, o, 64);
    if (j < S) sm.alpha[j] = e / ssum;
  }
  __syncthreads();
  float xn = 0.f;
  for (int j = 0; j < S; j++) xn += sm.alpha[j] * x[((long)b * S + j) * D + tid];
  float mv = mir[idx];
  sm.ak[0][tid] = xn;
  sm.ak[1][tid] = mv;
  __syncthreads();
  float a2m = 0.f;
  for (int k = 0; k < D; k++)
    a2m += sm.ak[0][k] * w1[(long)k * D + tid] + sm.ak[1][k] * w2[(long)k * D + tid];
  float g = sigm(a2m);
  float xg = g * xn + (1.f - g) * mv;
  if (!fin) {
    xout[idx] = xg;
    mir[idx] = g * mv + (1.f - g) * xn;
    return;
  }
  float hv = h[idx];
  sm.ak[2][tid] = hv;
  sm.ak[3][tid] = xg;
  __syncthreads();
  float a3m = 0.f;
  for (int k = 0; k < D; k++)
    a3m += sm.ak[2][k] * hw[(long)k * D + tid] + sm.ak[3][k] * hw[(long)(D + k) * D + tid];
  float gh = sigm(a3m);
  float xd = gh * hv + (1.f - gh) * xg;
  x_dot[idx] = xd;
  if (row == S - 1) h_local[(long)b * D + tid] = xd;
}

// ---------------------------------------------------------------------------
// dev_k7: simi loss per (b,i). atomicAdd to ws.
__device__ __forceinline__ void dev_k7(SMk7& sm, fpp hf1, fpp hf2,
                                       const int* __restrict__ simi_mask,
                                       float* __restrict__ loss, int bs) {
  int b = bs / S;
  int i = bs % S;
  int t = threadIdx.x;
  sm.hi[t] = hf1[((long)b * S + i) * D + t];
  __syncthreads();
  {
    int j = t & 63, hf = t >> 6;
    float acc = 0.f;
    if (j < S) {
      const float* r = hf2 + ((long)b * S + j) * D + hf * 64;
      int off = hf * 64;
      for (int dd = 0; dd < 64; dd++) acc += sm.hi[off + dd] * r[dd];
    }
    sm.part[hf][j] = acc;
  }
  __syncthreads();
  if (t < 64) {
    int j = t;
    float sim = (j < S) ? (sm.part[0][j] + sm.part[1][j]) * (1.0f / TEMPV) : NEG_BIG;
    float mx = sim;
#pragma unroll
    for (int o = 32; o > 0; o >>= 1) mx = fmaxf(mx, __shfl_xor(mx, o, 64));
    float e = __expf(sim - mx);
    float ssum = e;
#pragma unroll
    for (int o = 32; o > 0; o >>= 1) ssum += __shfl_xor(ssum, o, 64);
    float contrib = 0.f;
    if (j < S) {
      float p = e / ssum;
      float l = -__logf(p + 1e-8f);
      if (simi_mask[((long)b * S + i) * S + j] == 1) contrib = l;
    }
#pragma unroll
    for (int o = 32; o > 0; o >>= 1) contrib += __shfl_xor(contrib, o, 64);
    if (j == 0) atomicAdd(loss, contrib);
  }
}

// ---------------------------------------------------------------------------
// Fused launch 1: kGA (2 units/wave) U k5ab pass0 U k7.
template <typename ET>
__global__ __launch_bounds__(128) void kF1(
    const int* __restrict__ inputs, const int* __restrict__ adj_all, fpp num,
    const ET* __restrict__ emb, fpp sess, fpp W1a, fpp W2a,
    const u16* __restrict__ p1a, u16* __restrict__ aggws,
    fpp xA, const int* __restrict__ adj, fpp a_loc, fpp mw1, fpp mw2,
    fpw xB, fpw mir,
    fpp hf1, fpp hf2, const int* __restrict__ simi_mask,
    float* __restrict__ loss) {
  __shared__ SMF1 sm;
  int bid = blockIdx.x;
  if (bid < NGA) {
    int t = threadIdx.x;
    int w = t >> 6, lane = t & 63;
    dev_kga2<ET>(sm.c.nvs[w][0], sm.c.nvs[w][1], inputs, adj_all, num, emb,
                 sess, W1a, W2a, p1a, aggws, bid * 4 + w * 2, lane);
  } else if (bid < NGA + B * S) {
    dev_k5ab(sm.a, xA, adj, a_loc, mw1, mw2, xB, mir, nullptr, nullptr,
             nullptr, nullptr, bid - NGA, 0);
  } else {
    dev_k7(sm.b, hf1, hf2, simi_mask, loss, bid - NGA - B * S);
  }
}

// ---------------------------------------------------------------------------
// Fused launch 2: kGB U k5ab pass1 (fin).
template <typename ET>
__global__ __launch_bounds__(128) void kF2(
    const int* __restrict__ inputs, const int* __restrict__ adj_all, fpp num,
    const ET* __restrict__ emb, fpp sess, fpp W1b, fpp W2b, fpp W3b,
    const u16* __restrict__ p1b, const u16* __restrict__ p3a,
    const u16* __restrict__ aggws, fpw hg,
    fpp xB, const int* __restrict__ adj, fpp a_loc2, fpp mw1b, fpp mw2b,
    fpw mir, fpp hw, fpp h, fpw x_dot, float* __restrict__ h_local) {
  __shared__ SMF2 sm;
  int bid = blockIdx.x;
  if (bid < B * S) {
    dev_kgb<ET>(sm.d, inputs, adj_all, num, emb, sess, W1b, W2b, W3b, p1b,
                p3a, aggws, hg, bid);
  } else {
    dev_k5ab(sm.a, xB, adj, a_loc2, mw1b, mw2b, nullptr, mir, hw, h, x_dot,
             h_local, bid - B * S, 1);
  }
}

// ---------------------------------------------------------------------------
// Standalone wrappers (fallback path).
__global__ __launch_bounds__(128) void k5ab(fpp x, const int* __restrict__ adj,
                                            fpp a_loc, fpp w1, fpp w2,
                                            fpw xout, fpw mir,
                                            fpp hw, fpp h, fpw x_dot,
                                            float* __restrict__ h_local,
                                            int fin) {
  __shared__ SMk5 sm;
  dev_k5ab(sm, x, adj, a_loc, w1, w2, xout, mir, hw, h, x_dot, h_local,
           blockIdx.x, fin);
}

__global__ __launch_bounds__(128) void k7_simi(fpp hf1, fpp hf2,
                                               const int* __restrict__ simi_mask,
                                               float* __restrict__ loss) {
  __shared__ SMk7 sm;
  dev_k7(sm, hf1, hf2, simi_mask, loss, blockIdx.x);
}

// ---------------------------------------------------------------------------
// KG_MONO: verified monolithic kG (fallback when ws too small for split).
template <typename ET>
__global__ __launch_bounds__(128) void kG_mono(
    const int* __restrict__ inputs, const int* __restrict__ adj_all,
    fpp num, const ET* __restrict__ emb, fpp sess,
    fpp W1a, fpp W2a, fpp W1b, fpp W2b, fpp W3b,
    const u16* __restrict__ p1a, const u16* __restrict__ p1b,
    const u16* __restrict__ p3a, fpw hg) {
  int bs = blockIdx.x;
  int b = bs / S;
  int d = threadIdx.x;
  int lane = d & 63;
  int w = d >> 6;
  int q = lane >> 4;
  int mrow = lane & 15;

  __shared__ __align__(16) u16 nvs_l[16 * 136];
  __shared__ __align__(16) u16 svagg_l[16 * 264];
  __shared__ __align__(16) float ev_l[13 * 128];
  __shared__ __align__(16) float agg1_l[128];
  __shared__ float red_l[2][16];
  __shared__ float nw_l[16];

#pragma unroll
  for (int r = 12; r < 16; r++) {
    nvs_l[r * 136 + d] = 0;
    if (d < 8) nvs_l[r * 136 + 128 + d] = 0;
  }
#pragma unroll
  for (int r = 13; r < 16; r++) {
    svagg_l[r * 264 + d] = 0;
    svagg_l[r * 264 + 128 + d] = 0;
    if (d < 8) svagg_l[r * 264 + 256 + d] = 0;
  }

  float sess_d = sess[(long)b * D + d];
  int src0 = __builtin_amdgcn_readfirstlane(inputs[bs]);
  int n1[SAMPLE];
#pragma unroll
  for (int j = 0; j < SAMPLE; j++)
    n1[j] = __builtin_amdgcn_readfirstlane(adj_all[(long)src0 * SAMPLE + j]);
  svagg_l[0 * 264 + d] = f2bf(lde(emb, (long)src0 * D + d));

  float w2A[4], wlA[4], w2B[4], wlB[4];
#pragma unroll
  for (int nt = 0; nt < 4; nt++) {
    int col = (w * 4 + nt) * 16 + mrow;
    w2A[nt] = W2a[col];
    wlA[nt] = W1a[(long)D * D + col];
    w2B[nt] = W2b[col];
    wlB[nt] = W1b[(long)D * D + col];
  }

  float pre[SAMPLE], pnw = 0.f;
  {
#pragma unroll
    for (int j = 0; j < SAMPLE; j++)
      pre[j] = lde(emb, (long)n1[j] * D + d);
    if (d < SAMPLE) pnw = num[(long)src0 * SAMPLE + d];
  }
  for (int u = 0; u < 13; u++) {
    if (d < SAMPLE) nw_l[d] = pnw;
    float nvreg[SAMPLE];
#pragma unroll
    for (int j = 0; j < SAMPLE; j++) {
      nvreg[j] = pre[j];
      nvs_l[j * 136 + d] = f2bf(pre[j] * sess_d);
    }
    if (u == 0) {
#pragma unroll
      for (int j = 0; j < SAMPLE; j++)
        svagg_l[(1 + j) * 264 + d] = f2bf(nvreg[j]);
    }
    __syncthreads();
    if (u < 12) {
      int srcn = n1[u];
#pragma unroll
      for (int j = 0; j < SAMPLE; j++) {
        int nj = __builtin_amdgcn_readfirstlane(adj_all[(long)srcn * SAMPLE + j]);
        pre[j] = lde(emb, (long)nj * D + d);
      }
      if (d < SAMPLE) pnw = num[(long)srcn * SAMPLE + d];
    }
    f32x4 acc[4];
#pragma unroll
    for (int nt = 0; nt < 4; nt++) acc[nt] = (f32x4){0.f, 0.f, 0.f, 0.f};
#pragma unroll
    for (int ks = 0; ks < 4; ks++) {
      bfrag8 a = *(const bfrag8*)(nvs_l + mrow * 136 + q * 8 + ks * 32);
      const u16* pb = p1a + (w * 16 + ks) * 512 + lane * 8;
#pragma unroll
      for (int nt = 0; nt < 4; nt++) {
        bfrag8 bb = *(const bfrag8*)(pb + nt * 2048);
        acc[nt] = __builtin_amdgcn_mfma_f32_16x16x32_bf16(a, bb, acc[nt], 0, 0, 0);
      }
    }
    float lp[4] = {0.f, 0.f, 0.f, 0.f};
    float nwq[4];
#pragma unroll
    for (int i = 0; i < 4; i++) nwq[i] = (q < 3) ? nw_l[q * 4 + i] : 0.f;
#pragma unroll
    for (int nt = 0; nt < 4; nt++)
#pragma unroll
      for (int i = 0; i < 4; i++)
        lp[i] += leaky(acc[nt][i] + nwq[i] * wlA[nt]) * w2A[nt];
#pragma unroll
    for (int off = 1; off <= 8; off <<= 1)
#pragma unroll
      for (int i = 0; i < 4; i++) lp[i] += __shfl_xor(lp[i], off, 64);
    if (mrow == 0 && q < 3) {
#pragma unroll
      for (int i = 0; i < 4; i++) red_l[w][q * 4 + i] = lp[i];
    }
    __syncthreads();
    float lg[SAMPLE];
#pragma unroll
    for (int j = 0; j < SAMPLE; j++) lg[j] = red_l[0][j] + red_l[1][j];
    float mx = lg[0];
#pragma unroll
    for (int j = 1; j < SAMPLE; j++) mx = fmaxf(mx, lg[j]);
    float se = 0.f;
#pragma unroll
    for (int j = 0; j < SAMPLE; j++) { lg[j] = __expf(lg[j] - mx); se += lg[j]; }
    float inv = 1.f / se;
    float aggd = 0.f;
#pragma unroll
    for (int j = 0; j < SAMPLE; j++) aggd += lg[j] * inv * nvreg[j];
    svagg_l[u * 264 + 128 + d] = f2bf(aggd);
  }
  __syncthreads();

  {
    f32x4 accB[4];
#pragma unroll
    for (int nt = 0; nt < 4; nt++) accB[nt] = (f32x4){0.f, 0.f, 0.f, 0.f};
#pragma unroll
    for (int ks = 0; ks < 8; ks++) {
      bfrag8 a = *(const bfrag8*)(svagg_l + mrow * 264 + q * 8 + ks * 32);
      const u16* pb = p3a + (w * 32 + ks) * 512 + lane * 8;
#pragma unroll
      for (int nt = 0; nt < 4; nt++) {
        bfrag8 bb = *(const bfrag8*)(pb + nt * 4096);
        accB[nt] = __builtin_amdgcn_mfma_f32_16x16x32_bf16(a, bb, accB[nt], 0, 0, 0);
      }
    }
#pragma unroll
    for (int nt = 0; nt < 4; nt++) {
      int col = (w * 4 + nt) * 16 + mrow;
#pragma unroll
      for (int i = 0; i < 4; i++) {
        int u2 = q * 4 + i;
        if (u2 < 13) ev_l[u2 * 128 + col] = tanh_f(accB[nt][i]);
      }
    }
    __syncthreads();
  }

  {
    float evreg[SAMPLE];
#pragma unroll
    for (int j = 0; j < SAMPLE; j++) {
      float e = ev_l[(1 + j) * 128 + d];
      evreg[j] = e;
      nvs_l[j * 136 + d] = f2bf(e * sess_d);
    }
    if (d < SAMPLE) nw_l[d] = num[(long)src0 * SAMPLE + d];
    __syncthreads();

    f32x4 acc[4];
#pragma unroll
    for (int nt = 0; nt < 4; nt++) acc[nt] = (f32x4){0.f, 0.f, 0.f, 0.f};
#pragma unroll
    for (int ks = 0; ks < 4; ks++) {
      bfrag8 a = *(const bfrag8*)(nvs_l + mrow * 136 + q * 8 + ks * 32);
      const u16* pb = p1b + (w * 16 + ks) * 512 + lane * 8;
#pragma unroll
      for (int nt = 0; nt < 4; nt++) {
        bfrag8 bb = *(const bfrag8*)(pb + nt * 2048);
        acc[nt] = __builtin_amdgcn_mfma_f32_16x16x32_bf16(a, bb, acc[nt], 0, 0, 0);
      }
    }
    float lp[4] = {0.f, 0.f, 0.f, 0.f};
    float nwq[4];
#pragma unroll
    for (int i = 0; i < 4; i++) nwq[i] = (q < 3) ? nw_l[q * 4 + i] : 0.f;
#pragma unroll
    for (int nt = 0; nt < 4; nt++)
#pragma unroll
      for (int i = 0; i < 4; i++)
        lp[i] += leaky(acc[nt][i] + nwq[i] * wlB[nt]) * w2B[nt];
#pragma unroll
    for (int off = 1; off <= 8; off <<= 1)
#pragma unroll
      for (int i = 0; i < 4; i++) lp[i] += __shfl_xor(lp[i], off, 64);
    if (mrow == 0 && q < 3) {
#pragma unroll
      for (int i = 0; i < 4; i++) red_l[w][q * 4 + i] = lp[i];
    }
    __syncthreads();

    float lg[SAMPLE];
#pragma unroll
    for (int j = 0; j < SAMPLE; j++) lg[j] = red_l[0][j] + red_l[1][j];
    float mx = lg[0];
#pragma unroll
    for (int j = 1; j < SAMPLE; j++) mx = fmaxf(mx, lg[j]);
    float se = 0.f;
#pragma unroll
    for (int j = 0; j < SAMPLE; j++) { lg[j] = __expf(lg[j] - mx); se += lg[j]; }
    float inv = 1.f / se;
    float agg1d = 0.f;
#pragma unroll
    for (int j = 0; j < SAMPLE; j++) agg1d += lg[j] * inv * evreg[j];
    agg1_l[d] = agg1d;
    __syncthreads();

    float accf = 0.f;
#pragma unroll 4
    for (int k4 = 0; k4 < 32; k4++) {
      float4 a4 = *(const float4*)&ev_l[4 * k4];
      float4 g4 = *(const float4*)&agg1_l[4 * k4];
      accf += a4.x * W3b[(4 * k4 + 0) * D + d] + a4.y * W3b[(4 * k4 + 1) * D + d] +
              a4.z * W3b[(4 * k4 + 2) * D + d] + a4.w * W3b[(4 * k4 + 3) * D + d] +
              g4.x * W3b[(D + 4 * k4 + 0) * D + d] + g4.y * W3b[(D + 4 * k4 + 1) * D + d] +
              g4.z * W3b[(D + 4 * k4 + 2) * D + d] + g4.w * W3b[(D + 4 * k4 + 3) * D + d];
    }
    hg[(long)bs * D + d] = tanh_f(accf);
  }
}

// ---------------------------------------------------------------------------
// K8: GLU epilogue per batch, 512 threads = 4 s-groups (serial 50 -> 13).
__global__ __launch_bounds__(512) void k8_glu(
    fpp hg, fpp x_dot, fpp pos, fpp h_local, const float* __restrict__ mi,
    fpp glu1, fpp glu2, fpp glu4, fpp glu4b, fpp w_s, fpp gate_w, fpw zh) {
  int b = blockIdx.x;
  int t = threadIdx.x;
  int d = t & 127;
  int g = t >> 7;   // s-group 0..3
  __shared__ float hs_s[D], hl_s[D];
  __shared__ float hp_g[4][D], part[4][D], zg_g[4][D];
  __shared__ float red2[4][2];
  float msf = 0.f;
  for (int s = 0; s < S; s++) msf += mi[b * S + s];
  float hsacc = 0.f;
  for (int s = g * 13; s < min(S, g * 13 + 13); s++)
    hsacc += hg[((long)b * S + s) * D + d] * mi[b * S + s];
  part[g][d] = hsacc;
  if (g == 1) hl_s[d] = h_local[(long)b * D + d];
  __syncthreads();
  if (g == 0) hs_s[d] = (part[0][d] + part[1][d] + part[2][d] + part[3][d]) / msf;
  __syncthreads();
  float c = glu4b[d];
  for (int k = 0; k < D; k++)
    c += hs_s[k] * glu2[(long)k * D + d] + hl_s[k] * glu4[(long)k * D + d];
  float wsd = w_s[d];
  float zg = 0.f;
  for (int it = 0; it < 13; it++) {
    int s = g * 13 + it;
    bool act = s < S;
    float hp = 0.f;
    if (act) {
      hp = x_dot[((long)b * S + s) * D + d] + pos[(long)s * D + d];
      hp_g[g][d] = hp;
    }
    __syncthreads();
    if (act) {
      float acc = c;
      for (int k = 0; k < D; k++) acc += hp_g[g][k] * glu1[(long)k * D + d];
      float v = sigm(acc) * wsd;
#pragma unroll
      for (int o = 32; o > 0; o >>= 1) v += __shfl_down(v, o, 64);
      if ((t & 63) == 0) red2[g][(t >> 6) & 1] = v;
    }
    __syncthreads();
    if (act) {
      float beta = (red2[g][0] + red2[g][1]) * mi[b * S + s];
      zg += beta * hp;
    }
    __syncthreads();
  }
  zg_g[g][d] = zg;
  __syncthreads();
  if (g == 0) {
    float zgf = zg_g[0][d] + zg_g[1][d] + zg_g[2][d] + zg_g[3][d];
    hp_g[0][d] = zgf;
  }
  __syncthreads();
  if (g == 0) {
    float zgf = hp_g[0][d];
    float acc = 0.f;
    for (int k = 0; k < D; k++)
      acc += hp_g[0][k] * gate_w[(long)k * D + d] +
             hl_s[k] * gate_w[(long)(D + k) * D + d];
    float gf = sigm(acc) * MUV;
    zh[(long)b * D + d] = gf * hl_s[d] + (1.f - gf) * zgf;
  }
}

// ---------------------------------------------------------------------------
// K9: scores = zh(128x128) @ emb[1:]^T via bf16 MFMA.
template <typename ET>
__global__ __launch_bounds__(256) void k9_scores(fpp zh, const ET* __restrict__ emb,
                                                 fpp loss, float* __restrict__ out) {
  int t = threadIdx.x;
  if (blockIdx.x == 0 && t == 0) out[0] = loss[0] * (1.0f / (float)B);
  int lane = t & 63;
  int w = t >> 6;
  int q = lane >> 4;
  int mrow = lane & 15;
  long n = (long)blockIdx.x * 64 + w * 16 + mrow;
  bool valid = n < NSC;
  long nrow = valid ? (n + 1) : 1;
  bfrag8 bfr[4];
#pragma unroll
  for (int ks = 0; ks < 4; ks++) {
    if constexpr (sizeof(ET) == 2) {
      bfr[ks] = *(const bfrag8*)(const void*)(emb + nrow * D + ks * 32 + q * 8);
    } else {
      const float* src = (const float*)(emb + nrow * D + ks * 32 + q * 8);
      float4 lo = *(const float4*)src;
      float4 hi = *(const float4*)(src + 4);
      bfrag8 bb;
      bb[0] = (short)f2bf(lo.x); bb[1] = (short)f2bf(lo.y);
      bb[2] = (short)f2bf(lo.z); bb[3] = (short)f2bf(lo.w);
      bb[4] = (short)f2bf(hi.x); bb[5] = (short)f2bf(hi.y);
      bb[6] = (short)f2bf(hi.z); bb[7] = (short)f2bf(hi.w);
      bfr[ks] = bb;
    }
  }
#pragma unroll
  for (int mt = 0; mt < 8; mt++) {
    f32x4 acc = (f32x4){0.f, 0.f, 0.f, 0.f};
#pragma unroll
    for (int ks = 0; ks < 4; ks++) {
      const float* za = zh + (long)(mt * 16 + mrow) * D + ks * 32 + q * 8;
      float4 lo = *(const float4*)za;
      float4 hi = *(const float4*)(za + 4);
      bfrag8 a;
      a[0] = (short)f2bf(lo.x); a[1] = (short)f2bf(lo.y);
      a[2] = (short)f2bf(lo.z); a[3] = (short)f2bf(lo.w);
      a[4] = (short)f2bf(hi.x); a[5] = (short)f2bf(hi.y);
      a[6] = (short)f2bf(hi.z); a[7] = (short)f2bf(hi.w);
      acc = __builtin_amdgcn_mfma_f32_16x16x32_bf16(a, bfr[ks], acc, 0, 0, 0);
    }
    if (valid) {
#pragma unroll
      for (int i = 0; i < 4; i++) {
        int m = mt * 16 + q * 4 + i;
        out[1 + (long)m * NSC + n] = acc[i];
      }
    }
  }
}

// ---------------------------------------------------------------------------
extern "C" void kernel_launch(void* const* d_in, const int* in_sizes, int n_in,
                              void* d_out, int out_size, void* d_ws, size_t ws_size,
                              hipStream_t stream) {
  (void)in_sizes; (void)n_in; (void)out_size;
  const int* inputs = (const int*)d_in[0];
  const int* adj = (const int*)d_in[1];
  const int* item = (const int*)d_in[2];
  const int* simi_mask = (const int*)d_in[3];
  const int* as0 = (const int*)d_in[4];
  const int* as1 = (const int*)d_in[5];
  const int* ss0 = (const int*)d_in[6];
  const int* ss1 = (const int*)d_in[7];
  // d_in[8]: last_item_mask — structurally [:, -1]; hardcoded in k5ab(fin).
  const int* adj_all = (const int*)d_in[9];
  fpp num = (fpp)d_in[10];
  fpp emb = (fpp)d_in[11];
  fpp pos = (fpp)d_in[12];
  fpp a_local = (fpp)d_in[13];
  fpp mir_w1 = (fpp)d_in[14];
  fpp mir_w2 = (fpp)d_in[15];
  fpp gw1 = (fpp)d_in[16];
  fpp gw2 = (fpp)d_in[17];
  fpp gw3 = (fpp)d_in[18];
  fpp attr_w = (fpp)d_in[19];
  fpp highway_w = (fpp)d_in[20];
  fpp glu1 = (fpp)d_in[21];
  fpp glu2 = (fpp)d_in[22];
  fpp glu4 = (fpp)d_in[23];
  fpp glu4b = (fpp)d_in[24];
  fpp w_s = (fpp)d_in[25];
  fpp gate_w = (fpp)d_in[26];

  // fp32 scratch inside d_out: 6 * 819200 = 4,915,200 elts <= 5,119,873.
  float* ob = (float*)d_out;
  constexpr long BSD_ = (long)B * S * D;  // 819200
  fpw s_h = ob + 0 * BSD_;
  fpw s_hf1 = ob + 1 * BSD_;  // later x_dot
  fpw s_hf2 = ob + 2 * BSD_;  // later h_global
  fpw s_mir = ob + 3 * BSD_;
  fpw s_xA = ob + 4 * BSD_;
  fpw s_xB = ob + 5 * BSD_;

  // d_ws layout: small fp32 state (loss at ws[0]) .. float 72000; prepped
  // weight frags at byte 288,000; bf16 emb (10.24 MB) at byte 491,520;
  // split-kG agg buffer (21.3 MB bf16) at byte 10,731,520 (guarded).
  float* ws = (float*)d_ws;
  float* w_loss = ws + 0;
  float* w_mi = ws + 16;                // B*S
  float* w_sess = w_mi + (long)B * S;   // B*D
  float* w_hl = w_sess + (long)B * D;   // B*D
  float* w_zh = w_hl + (long)B * D;     // B*D
  u16* p1a = (u16*)(ws + 72000);
  u16* p1b = (u16*)(ws + 72000 + 8192);
  u16* p3a = (u16*)(ws + 72000 + 16384);
  u16* p3b = (u16*)(ws + 72000 + 32768);
  u16* embbf = (u16*)((char*)d_ws + 491520);
  u16* aggws = (u16*)((char*)d_ws + 10731520);
  bool useBF = ws_size >= (size_t)12 * 1024 * 1024;
  bool useSplit = useBF && ws_size >= ((size_t)32 << 20);

  hipMemsetAsync((void*)w_loss, 0, sizeof(float), stream);

  kprep4<<<384, 256, 0, stream>>>(gw1, gw3, p1a, p1b, p3a, p3b);
  if (useBF)
    kprep_emb<<<(NODES * D / 4 + 255) / 256, 256, 0, stream>>>(emb, embbf);

  if (useBF)
    k1_gather<u16><<<B * S, 128, 0, stream>>>(inputs, as0, as1, ss0, ss1,
                                              embbf, attr_w, s_h, s_hf1, s_hf2,
                                              w_mi, s_xA, s_mir);
  else
    k1_gather<float><<<B * S, 128, 0, stream>>>(inputs, as0, as1, ss0, ss1,
                                                emb, attr_w, s_h, s_hf1, s_hf2,
                                                w_mi, s_xA, s_mir);
  k2_sess<<<B, 128, 0, stream>>>(inputs, item, emb, w_sess);

  if (useSplit) {
    // kF1: kGA (units, 2/wave) first for earliest latency issue, then k5ab0,
    // then k7 (consumes hf1/hf2 before kF2's kGB overwrites the hf2 slot).
    kF1<u16><<<NGA + 2 * B * S, 128, 0, stream>>>(
        inputs, adj_all, num, embbf, w_sess, gw1, gw2, p1a, aggws,
        s_xA, adj, a_local, mir_w1, mir_w2, s_xB, s_mir,
        s_hf1, s_hf2, simi_mask, w_loss);
    kF2<u16><<<2 * B * S, 128, 0, stream>>>(
        inputs, adj_all, num, embbf, w_sess, gw1 + 129 * 128, gw2 + 128,
        gw3 + 256 * 128, p1b, p3a, aggws, s_hf2 /* h_global */,
        s_xB, adj, a_local + 4 * D, mir_w1 + (long)D * D,
        mir_w2 + (long)D * D, s_mir, highway_w, s_h, s_hf1 /* x_dot */, w_hl);
  } else {
    // Fallback: verified mono path.
    k7_simi<<<B * S, 128, 0, stream>>>(s_hf1, s_hf2, simi_mask, w_loss);
    if (useBF)
      kG_mono<u16><<<B * S, 128, 0, stream>>>(inputs, adj_all, num, embbf,
                                              w_sess, gw1, gw2,
                                              gw1 + 129 * 128, gw2 + 128,
                                              gw3 + 256 * 128, p1a, p1b, p3a,
                                              s_hf2 /* h_global */);
    else
      kG_mono<float><<<B * S, 128, 0, stream>>>(inputs, adj_all, num, emb,
                                                w_sess, gw1, gw2,
                                                gw1 + 129 * 128, gw2 + 128,
                                                gw3 + 256 * 128, p1a, p1b,
                                                p3a, s_hf2 /* h_global */);
    k5ab<<<B * S, 128, 0, stream>>>(s_xA, adj, a_local, mir_w1, mir_w2,
                                    s_xB, s_mir, highway_w, s_h, s_hf1, w_hl, 0);
    k5ab<<<B * S, 128, 0, stream>>>(s_xB, adj, a_local + 4 * D,
                                    mir_w1 + (long)D * D, mir_w2 + (long)D * D,
                                    s_xA, s_mir, highway_w, s_h,
                                    s_hf1 /* x_dot */, w_hl, 1);
  }

  k8_glu<<<B, 512, 0, stream>>>(s_hf2 /* h_global */, s_hf1 /* x_dot */, pos,
                                w_hl, w_mi, glu1, glu2, glu4, glu4b, w_s,
                                gate_w, w_zh);
  if (useBF)
    k9_scores<u16><<<(NSC + 63) / 64, 256, 0, stream>>>(w_zh, embbf, w_loss,
                                                        (float*)d_out);
  else
    k9_scores<float><<<(NSC + 63) / 64, 256, 0, stream>>>(w_zh, emb, w_loss,
                                                          (float*)d_out);
}

// Round 6
// 665.076 us; speedup vs baseline: 1.2303x; 1.0222x over previous
//
#include <hip/hip_runtime.h>
#include <hip/hip_bf16.h>
#include <type_traits>

// CombineGraph forward. B=128,S=50,D=128,NODES=40000,SAMPLE=12,NNEI=8,HOP=2.
// Round 18: same verified bodies as R17; scheduling-level changes only.
//  - kF1/kF2 block-type INTERLEAVE (13 GA + 8 {k5ab,k7} per 21-group; kGB/k5ab1
//    even/odd) so latency-bound GA waves and VALU-bound attention waves are
//    co-resident on every CU for the whole dispatch (m114 pipe overlap).
//  - GA LDS scratch cut 16->12 rows (predicated store): union 17408->13056 B,
//    9 -> 12 blocks/CU.
//  - kprep4 + kprep_emb + k2 folded into one routed launch kP.

#define B 128
#define S 50
#define D 128
#define SAMPLE 12
#define NNEI 8
#define NODES 40000
#define NSC (NODES - 1)
#define LEAK 0.2f
#define TEMPV 0.5f
#define MUV 0.1f
#define NEG_BIG -3.0e38f
#define NUNITS (B * S * 13)  // 83200
#define NGA (NUNITS / 4)     // 20800 blocks, 128 thr = 2 waves x 2 units

typedef const float* fpp;
typedef float* fpw;
typedef unsigned short u16;
typedef __attribute__((ext_vector_type(8))) short bfrag8;
typedef __attribute__((ext_vector_type(4))) float f32x4;

__device__ __forceinline__ float sigm(float x) { return 1.f / (1.f + __expf(-x)); }
__device__ __forceinline__ float tanh_f(float x) { return 1.f - 2.f / (__expf(2.f * x) + 1.f); }
__device__ __forceinline__ float leaky(float x) { return x >= 0.f ? x : LEAK * x; }
__device__ __forceinline__ u16 f2bf(float v) {
  __hip_bfloat16 h = __float2bfloat16(v);
  return *reinterpret_cast<u16*>(&h);
}
__device__ __forceinline__ float lde(const float* p, long i) { return p[i]; }
__device__ __forceinline__ float lde(const u16* p, long i) {
  union { unsigned int u; float f; } c;
  c.u = ((unsigned int)p[i]) << 16;
  return c.f;
}
__device__ __forceinline__ float bfu(short s) {
  union { unsigned u; float f; } c;
  c.u = ((unsigned)(unsigned short)s) << 16;
  return c.f;
}

template <typename ET>
__device__ __forceinline__ bfrag8 load_frag(const ET* __restrict__ emb, long row, int koff) {
  if constexpr (sizeof(ET) == 2) {
    return *(const bfrag8*)(const void*)(emb + row * D + koff);
  } else {
    const float* s = (const float*)(emb + row * D + koff);
    float4 lo = *(const float4*)s;
    float4 hi = *(const float4*)(s + 4);
    bfrag8 b;
    b[0] = (short)f2bf(lo.x); b[1] = (short)f2bf(lo.y);
    b[2] = (short)f2bf(lo.z); b[3] = (short)f2bf(lo.w);
    b[4] = (short)f2bf(hi.x); b[5] = (short)f2bf(hi.y);
    b[6] = (short)f2bf(hi.z); b[7] = (short)f2bf(hi.w);
    return b;
  }
}

__device__ __forceinline__ bfrag8 scale8(bfrag8 r, float4 sa, float4 sb) {
  bfrag8 o;
  o[0] = (short)f2bf(bfu(r[0]) * sa.x); o[1] = (short)f2bf(bfu(r[1]) * sa.y);
  o[2] = (short)f2bf(bfu(r[2]) * sa.z); o[3] = (short)f2bf(bfu(r[3]) * sa.w);
  o[4] = (short)f2bf(bfu(r[4]) * sb.x); o[5] = (short)f2bf(bfu(r[5]) * sb.y);
  o[6] = (short)f2bf(bfu(r[6]) * sb.z); o[7] = (short)f2bf(bfu(r[7]) * sb.w);
  return o;
}

// --------------------------- LDS overlays ---------------------------------
struct __align__(16) SMk5 { float xi[D]; float ak[4][D]; float alpha[56]; float part[4][2][64]; };
struct __align__(16) SMk7 { float hi[D]; float part[2][64]; };
struct __align__(16) SMga { u16 nvs[2][2][12 * 136]; };  // [wave][unit], rows 0..11 only
struct __align__(16) SMgb {
  u16 nvs[16 * 136];
  float ev[13 * 128];
  float agg1[128];
  float red[2][16];
  float nw[16];
  int svidx[16];
};
union __align__(16) SMF1 { SMk5 a; SMk7 b; SMga c; };
union __align__(16) SMF2 { SMk5 a; SMgb d; };

// ---------------------------------------------------------------------------
// KPREP_EMB: emb fp32 -> bf16 copy in ws (4 elems/thread). (fallback path)
__global__ __launch_bounds__(256) void kprep_emb(fpp emb, u16* __restrict__ out) {
  long i = ((long)blockIdx.x * 256 + threadIdx.x) * 4;
  if (i + 3 >= (long)NODES * D) return;
  float4 v = *(const float4*)(emb + i);
  out[i + 0] = f2bf(v.x); out[i + 1] = f2bf(v.y);
  out[i + 2] = f2bf(v.z); out[i + 3] = f2bf(v.w);
}

// ---------------------------------------------------------------------------
// prep4 body (device): four weight tensors -> bf16 B-fragment order.
__device__ __forceinline__ void dev_prep4(int i, fpp gw1, fpp gw3,
                                          u16* __restrict__ p1a,
                                          u16* __restrict__ p1b,
                                          u16* __restrict__ p3a,
                                          u16* __restrict__ p3b) {
  fpp W; u16* dst; int KS;
  if (i < 16384)      { W = gw1;             dst = p1a; KS = 4; }
  else if (i < 32768) { W = gw1 + 129 * 128; dst = p1b; KS = 4; i -= 16384; }
  else if (i < 65536) { W = gw3;             dst = p3a; KS = 8; i -= 32768; }
  else                { W = gw3 + 256 * 128; dst = p3b; KS = 8; i -= 65536; }
  int e = i & 7;
  int lane = (i >> 3) & 63;
  int rest = i >> 9;
  int ks = rest % KS, nt = rest / KS;
  int k = ks * 32 + ((lane >> 4) << 3) + e;
  int n = (nt << 4) + (lane & 15);
  dst[i] = f2bf(W[(long)k * 128 + n]);
}

__global__ __launch_bounds__(256) void kprep4(fpp gw1, fpp gw3,
                                              u16* __restrict__ p1a,
                                              u16* __restrict__ p1b,
                                              u16* __restrict__ p3a,
                                              u16* __restrict__ p3b) {
  dev_prep4(blockIdx.x * 256 + threadIdx.x, gw1, gw3, p1a, p1b, p3a, p3b);
}

// ---------------------------------------------------------------------------
// k2 body (device): sess[b,:] = sum_s emb[item[b,s]]*mi / sum_s mi
__device__ __forceinline__ void dev_k2(const int* __restrict__ inputs,
                                       const int* __restrict__ item,
                                       fpp emb, fpw sess, int b, int d) {
  float acc = 0.f, ms = 0.f;
  for (int s = 0; s < S; s++) {
    int inp = inputs[b * S + s];
    float m = (inp != 0) ? 1.f : 0.f;
    int it = item[b * S + s];
    acc += emb[(long)it * D + d] * m;
    ms += m;
  }
  sess[(long)b * D + d] = acc / ms;
}

__global__ __launch_bounds__(128) void k2_sess(const int* __restrict__ inputs,
                                               const int* __restrict__ item,
                                               fpp emb, fpw sess) {
  dev_k2(inputs, item, emb, sess, blockIdx.x, threadIdx.x);
}

// ---------------------------------------------------------------------------
// KP: fused prep — prep4 (384 blk) U prep_emb (5000 blk) U k2 (128 blk).
__global__ __launch_bounds__(256) void kP(fpp gw1, fpp gw3,
                                          u16* __restrict__ p1a, u16* __restrict__ p1b,
                                          u16* __restrict__ p3a, u16* __restrict__ p3b,
                                          fpp emb, u16* __restrict__ embbf,
                                          const int* __restrict__ inputs,
                                          const int* __restrict__ item, fpw sess) {
  int bid = blockIdx.x;
  int t = threadIdx.x;
  if (bid < 384) {
    dev_prep4(bid * 256 + t, gw1, gw3, p1a, p1b, p3a, p3b);
  } else if (bid < 5384) {
    long i = ((long)(bid - 384) * 256 + t) * 4;
    if (i + 3 < (long)NODES * D) {
      float4 v = *(const float4*)(emb + i);
      embbf[i + 0] = f2bf(v.x); embbf[i + 1] = f2bf(v.y);
      embbf[i + 2] = f2bf(v.z); embbf[i + 3] = f2bf(v.w);
    }
  } else {
    if (t < 128) dev_k2(inputs, item, emb, sess, bid - 5384, t);
  }
}

// ---------------------------------------------------------------------------
// K1: h = emb[inputs]; hf1/hf2 pools; attr gate. Block per (b,s), 128 thr.
template <typename ET>
__global__ __launch_bounds__(128) void k1_gather(
    const int* __restrict__ inputs, const int* __restrict__ as0,
    const int* __restrict__ as1, const int* __restrict__ ss0,
    const int* __restrict__ ss1, const ET* __restrict__ emb, fpp attr_w,
    fpw h, fpw hf1, fpw hf2, float* __restrict__ mi, fpw xA, fpw mir) {
  int bs = blockIdx.x;
  int d = threadIdx.x;
  __shared__ float h_s[D], hf1_s[D];
  int inp = inputs[bs];
  float hv = lde(emb, (long)inp * D + d);
  const int* lists[4] = {as0, as1, ss0, ss1};
  float p[4];
#pragma unroll
  for (int l = 0; l < 4; l++) {
    float sum = 0.f, cnt = 0.f;
    const int* L = lists[l] + (long)bs * NNEI;
#pragma unroll
    for (int n = 0; n < NNEI; n++) {
      int idx = L[n];
      if (idx != 0) { sum += lde(emb, (long)idx * D + d); cnt += 1.f; }
    }
    p[l] = sum / (cnt + 1e-8f);
  }
  float hf1v = 0.5f * (p[0] + p[1]);
  float hf2v = 0.5f * (p[2] + p[3]);
  h_s[d] = hv;
  hf1_s[d] = hf1v;
  __syncthreads();
  float acc = 0.f;
  for (int k = 0; k < D; k++)
    acc += h_s[k] * attr_w[(long)k * D + d] + hf1_s[k] * attr_w[(long)(D + k) * D + d];
  float g = sigm(acc);
  float hfv = g * hv + (1.f - g) * hf1v;
  long o = (long)bs * D + d;
  h[o] = hv; hf1[o] = hf1v; hf2[o] = hf2v; xA[o] = hv; mir[o] = hfv;
  if (d == 0) mi[bs] = (inp != 0) ? 1.f : 0.f;
}

// ---------------------------------------------------------------------------
// dev_kga2: TWO phase-A units per wave (B-frags loaded once, used twice).
// Per-unit math verbatim from the verified R16 kGA_unit; nvs rows 0..11 only
// (store predicated on mrow<12 — rows >=12 were never read).
template <typename ET>
__device__ __forceinline__ void dev_kga2(
    u16* __restrict__ nvs0, u16* __restrict__ nvs1,
    const int* __restrict__ inputs, const int* __restrict__ adj_all, fpp num,
    const ET* __restrict__ emb, fpp sess, fpp W1a, fpp W2a,
    const u16* __restrict__ p1a, u16* __restrict__ aggws, int gu0, int lane) {
  int q = lane >> 4;
  int mrow = lane & 15;
  float wl8[8], w28[8];
#pragma unroll
  for (int nt = 0; nt < 8; nt++) {
    int col = nt * 16 + mrow;
    wl8[nt] = W1a[(long)D * D + col];
    w28[nt] = W2a[col];
  }
  bfrag8 sA[2][4];
  float nwq[2][4];
#pragma unroll
  for (int g = 0; g < 2; g++) {
    int gu = gu0 + g;
    int bs = gu / 13;
    int u = gu - bs * 13;
    int b = bs / S;
    int src0 = inputs[bs];
    int srcu = (u == 0) ? src0 : adj_all[(long)src0 * SAMPLE + (u - 1)];
    int rid = adj_all[(long)srcu * SAMPLE + (mrow < 12 ? mrow : 0)];
#pragma unroll
    for (int i = 0; i < 4; i++)
      nwq[g][i] = (q < 3) ? num[(long)srcu * SAMPLE + q * 4 + i] : 0.f;
    const float* sessb = sess + (long)b * D;
    u16* nb = g ? nvs1 : nvs0;
    bfrag8 raw[4];
#pragma unroll
    for (int ks = 0; ks < 4; ks++)
      raw[ks] = load_frag(emb, (long)rid, ks * 32 + q * 8);
    if (mrow < 12) {
#pragma unroll
      for (int ks = 0; ks < 4; ks++)
        *(bfrag8*)(nb + mrow * 136 + ks * 32 + q * 8) = raw[ks];
    }
#pragma unroll
    for (int ks = 0; ks < 4; ks++) {
      float4 sa = *(const float4*)(sessb + ks * 32 + q * 8);
      float4 sb = *(const float4*)(sessb + ks * 32 + q * 8 + 4);
      sA[g][ks] = scale8(raw[ks], sa, sb);
    }
  }
  float lp[2][4] = {{0.f, 0.f, 0.f, 0.f}, {0.f, 0.f, 0.f, 0.f}};
#pragma unroll
  for (int nt = 0; nt < 8; nt++) {
    f32x4 acc0 = (f32x4){0.f, 0.f, 0.f, 0.f};
    f32x4 acc1 = (f32x4){0.f, 0.f, 0.f, 0.f};
#pragma unroll
    for (int ks = 0; ks < 4; ks++) {
      bfrag8 bb = *(const bfrag8*)(p1a + ks * 512 + lane * 8 + nt * 2048);
      acc0 = __builtin_amdgcn_mfma_f32_16x16x32_bf16(sA[0][ks], bb, acc0, 0, 0, 0);
      acc1 = __builtin_amdgcn_mfma_f32_16x16x32_bf16(sA[1][ks], bb, acc1, 0, 0, 0);
    }
#pragma unroll
    for (int i = 0; i < 4; i++) {
      lp[0][i] += leaky(acc0[i] + nwq[0][i] * wl8[nt]) * w28[nt];
      lp[1][i] += leaky(acc1[i] + nwq[1][i] * wl8[nt]) * w28[nt];
    }
  }
#pragma unroll
  for (int off = 1; off <= 8; off <<= 1)
#pragma unroll
    for (int g = 0; g < 2; g++)
#pragma unroll
      for (int i = 0; i < 4; i++) lp[g][i] += __shfl_xor(lp[g][i], off, 64);
#pragma unroll
  for (int g = 0; g < 2; g++) {
    float m4 = (q < 3) ? fmaxf(fmaxf(lp[g][0], lp[g][1]), fmaxf(lp[g][2], lp[g][3]))
                       : NEG_BIG;
    m4 = fmaxf(m4, __shfl_xor(m4, 16, 64));
    m4 = fmaxf(m4, __shfl_xor(m4, 32, 64));
    float e0 = 0.f, e1 = 0.f, e2 = 0.f, e3 = 0.f, ssum = 0.f;
    if (q < 3) {
      e0 = __expf(lp[g][0] - m4); e1 = __expf(lp[g][1] - m4);
      e2 = __expf(lp[g][2] - m4); e3 = __expf(lp[g][3] - m4);
      ssum = e0 + e1 + e2 + e3;
    }
    ssum += __shfl_xor(ssum, 16, 64);
    ssum += __shfl_xor(ssum, 32, 64);
    float inv = 1.f / ssum;
    float al[4] = {e0 * inv, e1 * inv, e2 * inv, e3 * inv};
    float aj[12];
#pragma unroll
    for (int j = 0; j < 12; j++) aj[j] = __shfl(al[j & 3], (j >> 2) << 4, 64);
    const u16* nb = g ? nvs1 : nvs0;
    float a0 = 0.f, a1 = 0.f;
#pragma unroll
    for (int j = 0; j < 12; j++) {
      unsigned pv = *(const unsigned*)(nb + j * 136 + lane * 2);
      union { unsigned u; float f; } lo, hi;
      lo.u = pv << 16; hi.u = pv & 0xffff0000u;
      a0 += aj[j] * lo.f; a1 += aj[j] * hi.f;
    }
    unsigned pk = ((unsigned)f2bf(a1) << 16) | (unsigned)f2bf(a0);
    *(unsigned*)(aggws + (long)(gu0 + g) * 128 + lane * 2) = pk;
  }
}

// ---------------------------------------------------------------------------
// dev_kgb: phases B/C + final per bs at 128 thr (verified body).
template <typename ET>
__device__ __forceinline__ void dev_kgb(
    SMgb& sm, const int* __restrict__ inputs, const int* __restrict__ adj_all,
    fpp num, const ET* __restrict__ emb, fpp sess, fpp W1b, fpp W2b, fpp W3b,
    const u16* __restrict__ p1b, const u16* __restrict__ p3a,
    const u16* __restrict__ aggws, fpw hg, int bs) {
  int b = bs / S;
  int d = threadIdx.x;
  int lane = d & 63;
  int w = d >> 6;
  int q = lane >> 4;
  int mrow = lane & 15;

#pragma unroll
  for (int r = 12; r < 16; r++) {
    sm.nvs[r * 136 + d] = 0;
    if (d < 8) sm.nvs[r * 136 + 128 + d] = 0;
  }
  int src0 = inputs[bs];
  if (d < 16)
    sm.svidx[d] = (d == 0) ? src0 : (d <= 12 ? adj_all[(long)src0 * SAMPLE + d - 1] : 0);
  if (d < SAMPLE) sm.nw[d] = num[(long)src0 * SAMPLE + d];
  float sess_d = sess[(long)b * D + d];
  __syncthreads();

  // ---- Phase B: [sv|agg] (13x256) @ W3a -> ev (tanh)
  {
    long svr = sm.svidx[mrow];
    f32x4 accB[4];
#pragma unroll
    for (int nt = 0; nt < 4; nt++) accB[nt] = (f32x4){0.f, 0.f, 0.f, 0.f};
#pragma unroll
    for (int ks = 0; ks < 4; ks++) {
      bfrag8 a = (bfrag8){0, 0, 0, 0, 0, 0, 0, 0};
      if (mrow < 13) a = load_frag(emb, svr, ks * 32 + q * 8);
      const u16* pb = p3a + (w * 32 + ks) * 512 + lane * 8;
#pragma unroll
      for (int nt = 0; nt < 4; nt++)
        accB[nt] = __builtin_amdgcn_mfma_f32_16x16x32_bf16(
            a, *(const bfrag8*)(pb + nt * 4096), accB[nt], 0, 0, 0);
    }
#pragma unroll
    for (int ks = 4; ks < 8; ks++) {
      bfrag8 a = (bfrag8){0, 0, 0, 0, 0, 0, 0, 0};
      if (mrow < 13)
        a = *(const bfrag8*)(aggws + ((long)bs * 13 + mrow) * 128 + (ks - 4) * 32 + q * 8);
      const u16* pb = p3a + (w * 32 + ks) * 512 + lane * 8;
#pragma unroll
      for (int nt = 0; nt < 4; nt++)
        accB[nt] = __builtin_amdgcn_mfma_f32_16x16x32_bf16(
            a, *(const bfrag8*)(pb + nt * 4096), accB[nt], 0, 0, 0);
    }
#pragma unroll
    for (int nt = 0; nt < 4; nt++) {
      int col = (w * 4 + nt) * 16 + mrow;
#pragma unroll
      for (int i = 0; i < 4; i++) {
        int u2 = q * 4 + i;
        if (u2 < 13) sm.ev[u2 * 128 + col] = tanh_f(accB[nt][i]);
      }
    }
  }
  __syncthreads();

  // ---- Phase C: hop-1 unit ----------------------------------------------
  {
    float w2B[4], wlB[4];
#pragma unroll
    for (int nt = 0; nt < 4; nt++) {
      int col = (w * 4 + nt) * 16 + mrow;
      w2B[nt] = W2b[col];
      wlB[nt] = W1b[(long)D * D + col];
    }
    float evreg[SAMPLE];
#pragma unroll
    for (int j = 0; j < SAMPLE; j++) {
      float e = sm.ev[(1 + j) * 128 + d];
      evreg[j] = e;
      sm.nvs[j * 136 + d] = f2bf(e * sess_d);
    }
    __syncthreads();

    f32x4 acc[4];
#pragma unroll
    for (int nt = 0; nt < 4; nt++) acc[nt] = (f32x4){0.f, 0.f, 0.f, 0.f};
#pragma unroll
    for (int ks = 0; ks < 4; ks++) {
      bfrag8 a = *(const bfrag8*)(sm.nvs + mrow * 136 + q * 8 + ks * 32);
      const u16* pb = p1b + (w * 16 + ks) * 512 + lane * 8;
#pragma unroll
      for (int nt = 0; nt < 4; nt++) {
        bfrag8 bb = *(const bfrag8*)(pb + nt * 2048);
        acc[nt] = __builtin_amdgcn_mfma_f32_16x16x32_bf16(a, bb, acc[nt], 0, 0, 0);
      }
    }
    float lp[4] = {0.f, 0.f, 0.f, 0.f};
    float nwq[4];
#pragma unroll
    for (int i = 0; i < 4; i++) nwq[i] = (q < 3) ? sm.nw[q * 4 + i] : 0.f;
#pragma unroll
    for (int nt = 0; nt < 4; nt++)
#pragma unroll
      for (int i = 0; i < 4; i++)
        lp[i] += leaky(acc[nt][i] + nwq[i] * wlB[nt]) * w2B[nt];
#pragma unroll
    for (int off = 1; off <= 8; off <<= 1)
#pragma unroll
      for (int i = 0; i < 4; i++) lp[i] += __shfl_xor(lp[i], off, 64);
    if (mrow == 0 && q < 3) {
#pragma unroll
      for (int i = 0; i < 4; i++) sm.red[w][q * 4 + i] = lp[i];
    }
    __syncthreads();

    float lg[SAMPLE];
#pragma unroll
    for (int j = 0; j < SAMPLE; j++) lg[j] = sm.red[0][j] + sm.red[1][j];
    float mx = lg[0];
#pragma unroll
    for (int j = 1; j < SAMPLE; j++) mx = fmaxf(mx, lg[j]);
    float se = 0.f;
#pragma unroll
    for (int j = 0; j < SAMPLE; j++) { lg[j] = __expf(lg[j] - mx); se += lg[j]; }
    float inv = 1.f / se;
    float agg1d = 0.f;
#pragma unroll
    for (int j = 0; j < SAMPLE; j++) agg1d += lg[j] * inv * evreg[j];
    sm.agg1[d] = agg1d;
    __syncthreads();

    float accf = 0.f;
#pragma unroll 4
    for (int k4 = 0; k4 < 32; k4++) {
      float4 a4 = *(const float4*)&sm.ev[4 * k4];
      float4 g4 = *(const float4*)&sm.agg1[4 * k4];
      accf += a4.x * W3b[(4 * k4 + 0) * D + d] + a4.y * W3b[(4 * k4 + 1) * D + d] +
              a4.z * W3b[(4 * k4 + 2) * D + d] + a4.w * W3b[(4 * k4 + 3) * D + d] +
              g4.x * W3b[(D + 4 * k4 + 0) * D + d] + g4.y * W3b[(D + 4 * k4 + 1) * D + d] +
              g4.z * W3b[(D + 4 * k4 + 2) * D + d] + g4.w * W3b[(D + 4 * k4 + 3) * D + d];
    }
    hg[(long)bs * D + d] = tanh_f(accf);
  }
}

// ---------------------------------------------------------------------------
// dev_k5ab: fused local-attention + mirror gate (+highway on fin=1).
__device__ __forceinline__ void dev_k5ab(SMk5& sm, fpp x, const int* __restrict__ adj,
                                         fpp a_loc, fpp w1, fpp w2, fpw xout,
                                         fpw mir, fpp hw, fpp h, fpw x_dot,
                                         float* __restrict__ h_local, int bs, int fin) {
  int b = bs / S;
  int row = bs % S;
  int tid = threadIdx.x;
  long idx = ((long)b * S + row) * D + tid;
  sm.xi[tid] = x[idx];
#pragma unroll
  for (int k = 0; k < 4; k++) sm.ak[k][tid] = a_loc[(long)k * D + tid];
  __syncthreads();
  {
    int j = tid & 63, hf = tid >> 6;
    float a0 = 0.f, a1 = 0.f, a2 = 0.f, a3 = 0.f;
    if (j < S) {
      const float* xj = x + ((long)b * S + j) * D + hf * 64;
      int off = hf * 64;
      for (int dd = 0; dd < 64; dd++) {
        float prod = sm.xi[off + dd] * xj[dd];
        a0 += prod * sm.ak[0][off + dd];
        a1 += prod * sm.ak[1][off + dd];
        a2 += prod * sm.ak[2][off + dd];
        a3 += prod * sm.ak[3][off + dd];
      }
    }
    sm.part[0][hf][j] = a0; sm.part[1][hf][j] = a1;
    sm.part[2][hf][j] = a2; sm.part[3][hf][j] = a3;
  }
  __syncthreads();
  if (tid < 64) {
    int j = tid;
    float att;
    if (j < S) {
      float acc0 = sm.part[0][0][j] + sm.part[0][1][j];
      float acc1 = sm.part[1][0][j] + sm.part[1][1][j];
      float acc2 = sm.part[2][0][j] + sm.part[2][1][j];
      float acc3 = sm.part[3][0][j] + sm.part[3][1][j];
      int av = adj[((long)b * S + row) * S + j];
      att = -9e15f;  // reference's own sentinel
      if (av == 1) att = leaky(acc0);
      else if (av == 2) att = leaky(acc1);
      else if (av == 3) att = leaky(acc2);
      else if (av == 4) att = leaky(acc3);
    } else {
      att = NEG_BIG;
    }
    float mx = att;
#pragma unroll
    for (int o = 32; o > 0; o >>= 1) mx = fmaxf(mx, __shfl_xor(mx, o, 64));
    float e = __expf(att - mx);
    float ssum = e;
#pragma unroll
    for (int o = 32; o > 0; o >>= 1) ssum += __shfl_xor(ssum, o, 64);
    if (j < S) sm.alpha[j] = e / ssum;
  }
  __syncthreads();
  float xn = 0.f;
  for (int j = 0; j < S; j++) xn += sm.alpha[j] * x[((long)b * S + j) * D + tid];
  float mv = mir[idx];
  sm.ak[0][tid] = xn;
  sm.ak[1][tid] = mv;
  __syncthreads();
  float a2m = 0.f;
  for (int k = 0; k < D; k++)
    a2m += sm.ak[0][k] * w1[(long)k * D + tid] + sm.ak[1][k] * w2[(long)k * D + tid];
  float g = sigm(a2m);
  float xg = g * xn + (1.f - g) * mv;
  if (!fin) {
    xout[idx] = xg;
    mir[idx] = g * mv + (1.f - g) * xn;
    return;
  }
  float hv = h[idx];
  sm.ak[2][tid] = hv;
  sm.ak[3][tid] = xg;
  __syncthreads();
  float a3m = 0.f;
  for (int k = 0; k < D; k++)
    a3m += sm.ak[2][k] * hw[(long)k * D + tid] + sm.ak[3][k] * hw[(long)(D + k) * D + tid];
  float gh = sigm(a3m);
  float xd = gh * hv + (1.f - gh) * xg;
  x_dot[idx] = xd;
  if (row == S - 1) h_local[(long)b * D + tid] = xd;
}

// ---------------------------------------------------------------------------
// dev_k7: simi loss per (b,i). atomicAdd to ws.
__device__ __forceinline__ void dev_k7(SMk7& sm, fpp hf1, fpp hf2,
                                       const int* __restrict__ simi_mask,
                                       float* __restrict__ loss, int bs) {
  int b = bs / S;
  int i = bs % S;
  int t = threadIdx.x;
  sm.hi[t] = hf1[((long)b * S + i) * D + t];
  __syncthreads();
  {
    int j = t & 63, hf = t >> 6;
    float acc = 0.f;
    if (j < S) {
      const float* r = hf2 + ((long)b * S + j) * D + hf * 64;
      int off = hf * 64;
      for (int dd = 0; dd < 64; dd++) acc += sm.hi[off + dd] * r[dd];
    }
    sm.part[hf][j] = acc;
  }
  __syncthreads();
  if (t < 64) {
    int j = t;
    float sim = (j < S) ? (sm.part[0][j] + sm.part[1][j]) * (1.0f / TEMPV) : NEG_BIG;
    float mx = sim;
#pragma unroll
    for (int o = 32; o > 0; o >>= 1) mx = fmaxf(mx, __shfl_xor(mx, o, 64));
    float e = __expf(sim - mx);
    float ssum = e;
#pragma unroll
    for (int o = 32; o > 0; o >>= 1) ssum += __shfl_xor(ssum, o, 64);
    float contrib = 0.f;
    if (j < S) {
      float p = e / ssum;
      float l = -__logf(p + 1e-8f);
      if (simi_mask[((long)b * S + i) * S + j] == 1) contrib = l;
    }
#pragma unroll
    for (int o = 32; o > 0; o >>= 1) contrib += __shfl_xor(contrib, o, 64);
    if (j == 0) atomicAdd(loss, contrib);
  }
}

// ---------------------------------------------------------------------------
// Fused launch 1 (INTERLEAVED): per 21-block group, 13 GA + 8 {k5ab0,k7}.
// 1600 groups: GA 1600*13=20800, other 1600*8=12800 (6400 k5ab0 + 6400 k7).
template <typename ET>
__global__ __launch_bounds__(128) void kF1(
    const int* __restrict__ inputs, const int* __restrict__ adj_all, fpp num,
    const ET* __restrict__ emb, fpp sess, fpp W1a, fpp W2a,
    const u16* __restrict__ p1a, u16* __restrict__ aggws,
    fpp xA, const int* __restrict__ adj, fpp a_loc, fpp mw1, fpp mw2,
    fpw xB, fpw mir,
    fpp hf1, fpp hf2, const int* __restrict__ simi_mask,
    float* __restrict__ loss) {
  __shared__ SMF1 sm;
  int bid = blockIdx.x;
  int grp = bid / 21;
  int r = bid - grp * 21;
  if (r < 13) {
    int ga = grp * 13 + r;
    int t = threadIdx.x;
    int w = t >> 6, lane = t & 63;
    dev_kga2<ET>(sm.c.nvs[w][0], sm.c.nvs[w][1], inputs, adj_all, num, emb,
                 sess, W1a, W2a, p1a, aggws, ga * 4 + w * 2, lane);
  } else {
    int o = grp * 8 + (r - 13);
    if (o & 1)
      dev_k7(sm.b, hf1, hf2, simi_mask, loss, o >> 1);
    else
      dev_k5ab(sm.a, xA, adj, a_loc, mw1, mw2, xB, mir, nullptr, nullptr,
               nullptr, nullptr, o >> 1, 0);
  }
}

// ---------------------------------------------------------------------------
// Fused launch 2 (INTERLEAVED): even -> kGB, odd -> k5ab pass1 (fin).
template <typename ET>
__global__ __launch_bounds__(128) void kF2(
    const int* __restrict__ inputs, const int* __restrict__ adj_all, fpp num,
    const ET* __restrict__ emb, fpp sess, fpp W1b, fpp W2b, fpp W3b,
    const u16* __restrict__ p1b, const u16* __restrict__ p3a,
    const u16* __restrict__ aggws, fpw hg,
    fpp xB, const int* __restrict__ adj, fpp a_loc2, fpp mw1b, fpp mw2b,
    fpw mir, fpp hw, fpp h, fpw x_dot, float* __restrict__ h_local) {
  __shared__ SMF2 sm;
  int bid = blockIdx.x;
  if (bid & 1)
    dev_k5ab(sm.a, xB, adj, a_loc2, mw1b, mw2b, nullptr, mir, hw, h, x_dot,
             h_local, bid >> 1, 1);
  else
    dev_kgb<ET>(sm.d, inputs, adj_all, num, emb, sess, W1b, W2b, W3b, p1b,
                p3a, aggws, hg, bid >> 1);
}

// ---------------------------------------------------------------------------
// Standalone wrappers (fallback path).
__global__ __launch_bounds__(128) void k5ab(fpp x, const int* __restrict__ adj,
                                            fpp a_loc, fpp w1, fpp w2,
                                            fpw xout, fpw mir,
                                            fpp hw, fpp h, fpw x_dot,
                                            float* __restrict__ h_local,
                                            int fin) {
  __shared__ SMk5 sm;
  dev_k5ab(sm, x, adj, a_loc, w1, w2, xout, mir, hw, h, x_dot, h_local,
           blockIdx.x, fin);
}

__global__ __launch_bounds__(128) void k7_simi(fpp hf1, fpp hf2,
                                               const int* __restrict__ simi_mask,
                                               float* __restrict__ loss) {
  __shared__ SMk7 sm;
  dev_k7(sm, hf1, hf2, simi_mask, loss, blockIdx.x);
}

// ---------------------------------------------------------------------------
// KG_MONO: verified monolithic kG (fallback when ws too small for split).
template <typename ET>
__global__ __launch_bounds__(128) void kG_mono(
    const int* __restrict__ inputs, const int* __restrict__ adj_all,
    fpp num, const ET* __restrict__ emb, fpp sess,
    fpp W1a, fpp W2a, fpp W1b, fpp W2b, fpp W3b,
    const u16* __restrict__ p1a, const u16* __restrict__ p1b,
    const u16* __restrict__ p3a, fpw hg) {
  int bs = blockIdx.x;
  int b = bs / S;
  int d = threadIdx.x;
  int lane = d & 63;
  int w = d >> 6;
  int q = lane >> 4;
  int mrow = lane & 15;

  __shared__ __align__(16) u16 nvs_l[16 * 136];
  __shared__ __align__(16) u16 svagg_l[16 * 264];
  __shared__ __align__(16) float ev_l[13 * 128];
  __shared__ __align__(16) float agg1_l[128];
  __shared__ float red_l[2][16];
  __shared__ float nw_l[16];

#pragma unroll
  for (int r = 12; r < 16; r++) {
    nvs_l[r * 136 + d] = 0;
    if (d < 8) nvs_l[r * 136 + 128 + d] = 0;
  }
#pragma unroll
  for (int r = 13; r < 16; r++) {
    svagg_l[r * 264 + d] = 0;
    svagg_l[r * 264 + 128 + d] = 0;
    if (d < 8) svagg_l[r * 264 + 256 + d] = 0;
  }

  float sess_d = sess[(long)b * D + d];
  int src0 = __builtin_amdgcn_readfirstlane(inputs[bs]);
  int n1[SAMPLE];
#pragma unroll
  for (int j = 0; j < SAMPLE; j++)
    n1[j] = __builtin_amdgcn_readfirstlane(adj_all[(long)src0 * SAMPLE + j]);
  svagg_l[0 * 264 + d] = f2bf(lde(emb, (long)src0 * D + d));

  float w2A[4], wlA[4], w2B[4], wlB[4];
#pragma unroll
  for (int nt = 0; nt < 4; nt++) {
    int col = (w * 4 + nt) * 16 + mrow;
    w2A[nt] = W2a[col];
    wlA[nt] = W1a[(long)D * D + col];
    w2B[nt] = W2b[col];
    wlB[nt] = W1b[(long)D * D + col];
  }

  float pre[SAMPLE], pnw = 0.f;
  {
#pragma unroll
    for (int j = 0; j < SAMPLE; j++)
      pre[j] = lde(emb, (long)n1[j] * D + d);
    if (d < SAMPLE) pnw = num[(long)src0 * SAMPLE + d];
  }
  for (int u = 0; u < 13; u++) {
    if (d < SAMPLE) nw_l[d] = pnw;
    float nvreg[SAMPLE];
#pragma unroll
    for (int j = 0; j < SAMPLE; j++) {
      nvreg[j] = pre[j];
      nvs_l[j * 136 + d] = f2bf(pre[j] * sess_d);
    }
    if (u == 0) {
#pragma unroll
      for (int j = 0; j < SAMPLE; j++)
        svagg_l[(1 + j) * 264 + d] = f2bf(nvreg[j]);
    }
    __syncthreads();
    if (u < 12) {
      int srcn = n1[u];
#pragma unroll
      for (int j = 0; j < SAMPLE; j++) {
        int nj = __builtin_amdgcn_readfirstlane(adj_all[(long)srcn * SAMPLE + j]);
        pre[j] = lde(emb, (long)nj * D + d);
      }
      if (d < SAMPLE) pnw = num[(long)srcn * SAMPLE + d];
    }
    f32x4 acc[4];
#pragma unroll
    for (int nt = 0; nt < 4; nt++) acc[nt] = (f32x4){0.f, 0.f, 0.f, 0.f};
#pragma unroll
    for (int ks = 0; ks < 4; ks++) {
      bfrag8 a = *(const bfrag8*)(nvs_l + mrow * 136 + q * 8 + ks * 32);
      const u16* pb = p1a + (w * 16 + ks) * 512 + lane * 8;
#pragma unroll
      for (int nt = 0; nt < 4; nt++) {
        bfrag8 bb = *(const bfrag8*)(pb + nt * 2048);
        acc[nt] = __builtin_amdgcn_mfma_f32_16x16x32_bf16(a, bb, acc[nt], 0, 0, 0);
      }
    }
    float lp[4] = {0.f, 0.f, 0.f, 0.f};
    float nwq[4];
#pragma unroll
    for (int i = 0; i < 4; i++) nwq[i] = (q < 3) ? nw_l[q * 4 + i] : 0.f;
#pragma unroll
    for (int nt = 0; nt < 4; nt++)
#pragma unroll
      for (int i = 0; i < 4; i++)
        lp[i] += leaky(acc[nt][i] + nwq[i] * wlA[nt]) * w2A[nt];
#pragma unroll
    for (int off = 1; off <= 8; off <<= 1)
#pragma unroll
      for (int i = 0; i < 4; i++) lp[i] += __shfl_xor(lp[i], off, 64);
    if (mrow == 0 && q < 3) {
#pragma unroll
      for (int i = 0; i < 4; i++) red_l[w][q * 4 + i] = lp[i];
    }
    __syncthreads();
    float lg[SAMPLE];
#pragma unroll
    for (int j = 0; j < SAMPLE; j++) lg[j] = red_l[0][j] + red_l[1][j];
    float mx = lg[0];
#pragma unroll
    for (int j = 1; j < SAMPLE; j++) mx = fmaxf(mx, lg[j]);
    float se = 0.f;
#pragma unroll
    for (int j = 0; j < SAMPLE; j++) { lg[j] = __expf(lg[j] - mx); se += lg[j]; }
    float inv = 1.f / se;
    float aggd = 0.f;
#pragma unroll
    for (int j = 0; j < SAMPLE; j++) aggd += lg[j] * inv * nvreg[j];
    svagg_l[u * 264 + 128 + d] = f2bf(aggd);
  }
  __syncthreads();

  {
    f32x4 accB[4];
#pragma unroll
    for (int nt = 0; nt < 4; nt++) accB[nt] = (f32x4){0.f, 0.f, 0.f, 0.f};
#pragma unroll
    for (int ks = 0; ks < 8; ks++) {
      bfrag8 a = *(const bfrag8*)(svagg_l + mrow * 264 + q * 8 + ks * 32);
      const u16* pb = p3a + (w * 32 + ks) * 512 + lane * 8;
#pragma unroll
      for (int nt = 0; nt < 4; nt++) {
        bfrag8 bb = *(const bfrag8*)(pb + nt * 4096);
        accB[nt] = __builtin_amdgcn_mfma_f32_16x16x32_bf16(a, bb, accB[nt], 0, 0, 0);
      }
    }
#pragma unroll
    for (int nt = 0; nt < 4; nt++) {
      int col = (w * 4 + nt) * 16 + mrow;
#pragma unroll
      for (int i = 0; i < 4; i++) {
        int u2 = q * 4 + i;
        if (u2 < 13) ev_l[u2 * 128 + col] = tanh_f(accB[nt][i]);
      }
    }
    __syncthreads();
  }

  {
    float evreg[SAMPLE];
#pragma unroll
    for (int j = 0; j < SAMPLE; j++) {
      float e = ev_l[(1 + j) * 128 + d];
      evreg[j] = e;
      nvs_l[j * 136 + d] = f2bf(e * sess_d);
    }
    if (d < SAMPLE) nw_l[d] = num[(long)src0 * SAMPLE + d];
    __syncthreads();

    f32x4 acc[4];
#pragma unroll
    for (int nt = 0; nt < 4; nt++) acc[nt] = (f32x4){0.f, 0.f, 0.f, 0.f};
#pragma unroll
    for (int ks = 0; ks < 4; ks++) {
      bfrag8 a = *(const bfrag8*)(nvs_l + mrow * 136 + q * 8 + ks * 32);
      const u16* pb = p1b + (w * 16 + ks) * 512 + lane * 8;
#pragma unroll
      for (int nt = 0; nt < 4; nt++) {
        bfrag8 bb = *(const bfrag8*)(pb + nt * 2048);
        acc[nt] = __builtin_amdgcn_mfma_f32_16x16x32_bf16(a, bb, acc[nt], 0, 0, 0);
      }
    }
    float lp[4] = {0.f, 0.f, 0.f, 0.f};
    float nwq[4];
#pragma unroll
    for (int i = 0; i < 4; i++) nwq[i] = (q < 3) ? nw_l[q * 4 + i] : 0.f;
#pragma unroll
    for (int nt = 0; nt < 4; nt++)
#pragma unroll
      for (int i = 0; i < 4; i++)
        lp[i] += leaky(acc[nt][i] + nwq[i] * wlB[nt]) * w2B[nt];
#pragma unroll
    for (int off = 1; off <= 8; off <<= 1)
#pragma unroll
      for (int i = 0; i < 4; i++) lp[i] += __shfl_xor(lp[i], off, 64);
    if (mrow == 0 && q < 3) {
#pragma unroll
      for (int i = 0; i < 4; i++) red_l[w][q * 4 + i] = lp[i];
    }
    __syncthreads();

    float lg[SAMPLE];
#pragma unroll
    for (int j = 0; j < SAMPLE; j++) lg[j] = red_l[0][j] + red_l[1][j];
    float mx = lg[0];
#pragma unroll
    for (int j = 1; j < SAMPLE; j++) mx = fmaxf(mx, lg[j]);
    float se = 0.f;
#pragma unroll
    for (int j = 0; j < SAMPLE; j++) { lg[j] = __expf(lg[j] - mx); se += lg[j]; }
    float inv = 1.f / se;
    float agg1d = 0.f;
#pragma unroll
    for (int j = 0; j < SAMPLE; j++) agg1d += lg[j] * inv * evreg[j];
    agg1_l[d] = agg1d;
    __syncthreads();

    float accf = 0.f;
#pragma unroll 4
    for (int k4 = 0; k4 < 32; k4++) {
      float4 a4 = *(const float4*)&ev_l[4 * k4];
      float4 g4 = *(const float4*)&agg1_l[4 * k4];
      accf += a4.x * W3b[(4 * k4 + 0) * D + d] + a4.y * W3b[(4 * k4 + 1) * D + d] +
              a4.z * W3b[(4 * k4 + 2) * D + d] + a4.w * W3b[(4 * k4 + 3) * D + d] +
              g4.x * W3b[(D + 4 * k4 + 0) * D + d] + g4.y * W3b[(D + 4 * k4 + 1) * D + d] +
              g4.z * W3b[(D + 4 * k4 + 2) * D + d] + g4.w * W3b[(D + 4 * k4 + 3) * D + d];
    }
    hg[(long)bs * D + d] = tanh_f(accf);
  }
}

// ---------------------------------------------------------------------------
// K8: GLU epilogue per batch, 512 threads = 4 s-groups (serial 50 -> 13).
__global__ __launch_bounds__(512) void k8_glu(
    fpp hg, fpp x_dot, fpp pos, fpp h_local, const float* __restrict__ mi,
    fpp glu1, fpp glu2, fpp glu4, fpp glu4b, fpp w_s, fpp gate_w, fpw zh) {
  int b = blockIdx.x;
  int t = threadIdx.x;
  int d = t & 127;
  int g = t >> 7;   // s-group 0..3
  __shared__ float hs_s[D], hl_s[D];
  __shared__ float hp_g[4][D], part[4][D], zg_g[4][D];
  __shared__ float red2[4][2];
  float msf = 0.f;
  for (int s = 0; s < S; s++) msf += mi[b * S + s];
  float hsacc = 0.f;
  for (int s = g * 13; s < min(S, g * 13 + 13); s++)
    hsacc += hg[((long)b * S + s) * D + d] * mi[b * S + s];
  part[g][d] = hsacc;
  if (g == 1) hl_s[d] = h_local[(long)b * D + d];
  __syncthreads();
  if (g == 0) hs_s[d] = (part[0][d] + part[1][d] + part[2][d] + part[3][d]) / msf;
  __syncthreads();
  float c = glu4b[d];
  for (int k = 0; k < D; k++)
    c += hs_s[k] * glu2[(long)k * D + d] + hl_s[k] * glu4[(long)k * D + d];
  float wsd = w_s[d];
  float zg = 0.f;
  for (int it = 0; it < 13; it++) {
    int s = g * 13 + it;
    bool act = s < S;
    float hp = 0.f;
    if (act) {
      hp = x_dot[((long)b * S + s) * D + d] + pos[(long)s * D + d];
      hp_g[g][d] = hp;
    }
    __syncthreads();
    if (act) {
      float acc = c;
      for (int k = 0; k < D; k++) acc += hp_g[g][k] * glu1[(long)k * D + d];
      float v = sigm(acc) * wsd;
#pragma unroll
      for (int o = 32; o > 0; o >>= 1) v += __shfl_down(v, o, 64);
      if ((t & 63) == 0) red2[g][(t >> 6) & 1] = v;
    }
    __syncthreads();
    if (act) {
      float beta = (red2[g][0] + red2[g][1]) * mi[b * S + s];
      zg += beta * hp;
    }
    __syncthreads();
  }
  zg_g[g][d] = zg;
  __syncthreads();
  if (g == 0) {
    float zgf = zg_g[0][d] + zg_g[1][d] + zg_g[2][d] + zg_g[3][d];
    hp_g[0][d] = zgf;
  }
  __syncthreads();
  if (g == 0) {
    float zgf = hp_g[0][d];
    float acc = 0.f;
    for (int k = 0; k < D; k++)
      acc += hp_g[0][k] * gate_w[(long)k * D + d] +
             hl_s[k] * gate_w[(long)(D + k) * D + d];
    float gf = sigm(acc) * MUV;
    zh[(long)b * D + d] = gf * hl_s[d] + (1.f - gf) * zgf;
  }
}

// ---------------------------------------------------------------------------
// K9: scores = zh(128x128) @ emb[1:]^T via bf16 MFMA.
template <typename ET>
__global__ __launch_bounds__(256) void k9_scores(fpp zh, const ET* __restrict__ emb,
                                                 fpp loss, float* __restrict__ out) {
  int t = threadIdx.x;
  if (blockIdx.x == 0 && t == 0) out[0] = loss[0] * (1.0f / (float)B);
  int lane = t & 63;
  int w = t >> 6;
  int q = lane >> 4;
  int mrow = lane & 15;
  long n = (long)blockIdx.x * 64 + w * 16 + mrow;
  bool valid = n < NSC;
  long nrow = valid ? (n + 1) : 1;
  bfrag8 bfr[4];
#pragma unroll
  for (int ks = 0; ks < 4; ks++) {
    if constexpr (sizeof(ET) == 2) {
      bfr[ks] = *(const bfrag8*)(const void*)(emb + nrow * D + ks * 32 + q * 8);
    } else {
      const float* src = (const float*)(emb + nrow * D + ks * 32 + q * 8);
      float4 lo = *(const float4*)src;
      float4 hi = *(const float4*)(src + 4);
      bfrag8 bb;
      bb[0] = (short)f2bf(lo.x); bb[1] = (short)f2bf(lo.y);
      bb[2] = (short)f2bf(lo.z); bb[3] = (short)f2bf(lo.w);
      bb[4] = (short)f2bf(hi.x); bb[5] = (short)f2bf(hi.y);
      bb[6] = (short)f2bf(hi.z); bb[7] = (short)f2bf(hi.w);
      bfr[ks] = bb;
    }
  }
#pragma unroll
  for (int mt = 0; mt < 8; mt++) {
    f32x4 acc = (f32x4){0.f, 0.f, 0.f, 0.f};
#pragma unroll
    for (int ks = 0; ks < 4; ks++) {
      const float* za = zh + (long)(mt * 16 + mrow) * D + ks * 32 + q * 8;
      float4 lo = *(const float4*)za;
      float4 hi = *(const float4*)(za + 4);
      bfrag8 a;
      a[0] = (short)f2bf(lo.x); a[1] = (short)f2bf(lo.y);
      a[2] = (short)f2bf(lo.z); a[3] = (short)f2bf(lo.w);
      a[4] = (short)f2bf(hi.x); a[5] = (short)f2bf(hi.y);
      a[6] = (short)f2bf(hi.z); a[7] = (short)f2bf(hi.w);
      acc = __builtin_amdgcn_mfma_f32_16x16x32_bf16(a, bfr[ks], acc, 0, 0, 0);
    }
    if (valid) {
#pragma unroll
      for (int i = 0; i < 4; i++) {
        int m = mt * 16 + q * 4 + i;
        out[1 + (long)m * NSC + n] = acc[i];
      }
    }
  }
}

// ---------------------------------------------------------------------------
extern "C" void kernel_launch(void* const* d_in, const int* in_sizes, int n_in,
                              void* d_out, int out_size, void* d_ws, size_t ws_size,
                              hipStream_t stream) {
  (void)in_sizes; (void)n_in; (void)out_size;
  const int* inputs = (const int*)d_in[0];
  const int* adj = (const int*)d_in[1];
  const int* item = (const int*)d_in[2];
  const int* simi_mask = (const int*)d_in[3];
  const int* as0 = (const int*)d_in[4];
  const int* as1 = (const int*)d_in[5];
  const int* ss0 = (const int*)d_in[6];
  const int* ss1 = (const int*)d_in[7];
  // d_in[8]: last_item_mask — structurally [:, -1]; hardcoded in k5ab(fin).
  const int* adj_all = (const int*)d_in[9];
  fpp num = (fpp)d_in[10];
  fpp emb = (fpp)d_in[11];
  fpp pos = (fpp)d_in[12];
  fpp a_local = (fpp)d_in[13];
  fpp mir_w1 = (fpp)d_in[14];
  fpp mir_w2 = (fpp)d_in[15];
  fpp gw1 = (fpp)d_in[16];
  fpp gw2 = (fpp)d_in[17];
  fpp gw3 = (fpp)d_in[18];
  fpp attr_w = (fpp)d_in[19];
  fpp highway_w = (fpp)d_in[20];
  fpp glu1 = (fpp)d_in[21];
  fpp glu2 = (fpp)d_in[22];
  fpp glu4 = (fpp)d_in[23];
  fpp glu4b = (fpp)d_in[24];
  fpp w_s = (fpp)d_in[25];
  fpp gate_w = (fpp)d_in[26];

  // fp32 scratch inside d_out: 6 * 819200 = 4,915,200 elts <= 5,119,873.
  float* ob = (float*)d_out;
  constexpr long BSD_ = (long)B * S * D;  // 819200
  fpw s_h = ob + 0 * BSD_;
  fpw s_hf1 = ob + 1 * BSD_;  // later x_dot
  fpw s_hf2 = ob + 2 * BSD_;  // later h_global
  fpw s_mir = ob + 3 * BSD_;
  fpw s_xA = ob + 4 * BSD_;
  fpw s_xB = ob + 5 * BSD_;

  // d_ws layout: small fp32 state (loss at ws[0]) .. float 72000; prepped
  // weight frags at byte 288,000; bf16 emb (10.24 MB) at byte 491,520;
  // split-kG agg buffer (21.3 MB bf16) at byte 10,731,520 (guarded).
  float* ws = (float*)d_ws;
  float* w_loss = ws + 0;
  float* w_mi = ws + 16;                // B*S
  float* w_sess = w_mi + (long)B * S;   // B*D
  float* w_hl = w_sess + (long)B * D;   // B*D
  float* w_zh = w_hl + (long)B * D;     // B*D
  u16* p1a = (u16*)(ws + 72000);
  u16* p1b = (u16*)(ws + 72000 + 8192);
  u16* p3a = (u16*)(ws + 72000 + 16384);
  u16* p3b = (u16*)(ws + 72000 + 32768);
  u16* embbf = (u16*)((char*)d_ws + 491520);
  u16* aggws = (u16*)((char*)d_ws + 10731520);
  bool useBF = ws_size >= (size_t)12 * 1024 * 1024;
  bool useSplit = useBF && ws_size >= ((size_t)32 << 20);

  hipMemsetAsync((void*)w_loss, 0, sizeof(float), stream);

  if (useSplit) {
    // Fused prep: prep4 U emb->bf16 U k2_sess (all independent).
    kP<<<5512, 256, 0, stream>>>(gw1, gw3, p1a, p1b, p3a, p3b, emb, embbf,
                                 inputs, item, w_sess);
    k1_gather<u16><<<B * S, 128, 0, stream>>>(inputs, as0, as1, ss0, ss1,
                                              embbf, attr_w, s_h, s_hf1, s_hf2,
                                              w_mi, s_xA, s_mir);
    // kF1 interleaved: 1600 groups x (13 GA + 8 {k5ab0,k7}).
    kF1<u16><<<33600, 128, 0, stream>>>(
        inputs, adj_all, num, embbf, w_sess, gw1, gw2, p1a, aggws,
        s_xA, adj, a_local, mir_w1, mir_w2, s_xB, s_mir,
        s_hf1, s_hf2, simi_mask, w_loss);
    // kF2 interleaved: even kGB, odd k5ab1.
    kF2<u16><<<2 * B * S, 128, 0, stream>>>(
        inputs, adj_all, num, embbf, w_sess, gw1 + 129 * 128, gw2 + 128,
        gw3 + 256 * 128, p1b, p3a, aggws, s_hf2 /* h_global */,
        s_xB, adj, a_local + 4 * D, mir_w1 + (long)D * D,
        mir_w2 + (long)D * D, s_mir, highway_w, s_h, s_hf1 /* x_dot */, w_hl);
  } else {
    // Fallback: verified mono path.
    kprep4<<<384, 256, 0, stream>>>(gw1, gw3, p1a, p1b, p3a, p3b);
    if (useBF)
      kprep_emb<<<(NODES * D / 4 + 255) / 256, 256, 0, stream>>>(emb, embbf);
    if (useBF)
      k1_gather<u16><<<B * S, 128, 0, stream>>>(inputs, as0, as1, ss0, ss1,
                                                embbf, attr_w, s_h, s_hf1,
                                                s_hf2, w_mi, s_xA, s_mir);
    else
      k1_gather<float><<<B * S, 128, 0, stream>>>(inputs, as0, as1, ss0, ss1,
                                                  emb, attr_w, s_h, s_hf1,
                                                  s_hf2, w_mi, s_xA, s_mir);
    k7_simi<<<B * S, 128, 0, stream>>>(s_hf1, s_hf2, simi_mask, w_loss);
    k2_sess<<<B, 128, 0, stream>>>(inputs, item, emb, w_sess);
    if (useBF)
      kG_mono<u16><<<B * S, 128, 0, stream>>>(inputs, adj_all, num, embbf,
                                              w_sess, gw1, gw2,
                                              gw1 + 129 * 128, gw2 + 128,
                                              gw3 + 256 * 128, p1a, p1b, p3a,
                                              s_hf2 /* h_global */);
    else
      kG_mono<float><<<B * S, 128, 0, stream>>>(inputs, adj_all, num, emb,
                                                w_sess, gw1, gw2,
                                                gw1 + 129 * 128, gw2 + 128,
                                                gw3 + 256 * 128, p1a, p1b,
                                                p3a, s_hf2 /* h_global */);
    k5ab<<<B * S, 128, 0, stream>>>(s_xA, adj, a_local, mir_w1, mir_w2,
                                    s_xB, s_mir, highway_w, s_h, s_hf1, w_hl, 0);
    k5ab<<<B * S, 128, 0, stream>>>(s_xB, adj, a_local + 4 * D,
                                    mir_w1 + (long)D * D, mir_w2 + (long)D * D,
                                    s_xA, s_mir, highway_w, s_h,
                                    s_hf1 /* x_dot */, w_hl, 1);
  }

  k8_glu<<<B, 512, 0, stream>>>(s_hf2 /* h_global */, s_hf1 /* x_dot */, pos,
                                w_hl, w_mi, glu1, glu2, glu4, glu4b, w_s,
                                gate_w, w_zh);
  if (useBF)
    k9_scores<u16><<<(NSC + 63) / 64, 256, 0, stream>>>(w_zh, embbf, w_loss,
                                                        (float*)d_out);
  else
    k9_scores<float><<<(NSC + 63) / 64, 256, 0, stream>>>(w_zh, emb, w_loss,
                                                          (float*)d_out);
}

// Round 8
// 627.537 us; speedup vs baseline: 1.3038x; 1.0598x over previous
//
#include <hip/hip_runtime.h>
#include <hip/hip_bf16.h>
#include <type_traits>

// CombineGraph forward. B=128,S=50,D=128,NODES=40000,SAMPLE=12,NNEI=8,HOP=2.
// Round 20: resubmission of R19 (container failed twice -> no measurement).
// kP precomputes srcu[gu] (unit source node) with one thread per unit -> GA
// chain shrinks from inputs->adj_all->adj_all->emb (4 levels) to
// srcu->rid/nw->emb (2 levels); kGB's svidx comes straight from the table.
// nvs store un-branched via duplicate-row select (rows 12..15 always dead).
// All consumed values bit-identical to the verified R18 path.

#define B 128
#define S 50
#define D 128
#define SAMPLE 12
#define NNEI 8
#define NODES 40000
#define NSC (NODES - 1)
#define LEAK 0.2f
#define TEMPV 0.5f
#define MUV 0.1f
#define NEG_BIG -3.0e38f
#define NUNITS (B * S * 13)  // 83200
#define NGA (NUNITS / 4)     // 20800 blocks, 128 thr = 2 waves x 2 units

typedef const float* fpp;
typedef float* fpw;
typedef unsigned short u16;
typedef __attribute__((ext_vector_type(8))) short bfrag8;
typedef __attribute__((ext_vector_type(4))) float f32x4;

__device__ __forceinline__ float sigm(float x) { return 1.f / (1.f + __expf(-x)); }
__device__ __forceinline__ float tanh_f(float x) { return 1.f - 2.f / (__expf(2.f * x) + 1.f); }
__device__ __forceinline__ float leaky(float x) { return x >= 0.f ? x : LEAK * x; }
__device__ __forceinline__ u16 f2bf(float v) {
  __hip_bfloat16 h = __float2bfloat16(v);
  return *reinterpret_cast<u16*>(&h);
}
__device__ __forceinline__ float lde(const float* p, long i) { return p[i]; }
__device__ __forceinline__ float lde(const u16* p, long i) {
  union { unsigned int u; float f; } c;
  c.u = ((unsigned int)p[i]) << 16;
  return c.f;
}
__device__ __forceinline__ float bfu(short s) {
  union { unsigned u; float f; } c;
  c.u = ((unsigned)(unsigned short)s) << 16;
  return c.f;
}

template <typename ET>
__device__ __forceinline__ bfrag8 load_frag(const ET* __restrict__ emb, long row, int koff) {
  if constexpr (sizeof(ET) == 2) {
    return *(const bfrag8*)(const void*)(emb + row * D + koff);
  } else {
    const float* s = (const float*)(emb + row * D + koff);
    float4 lo = *(const float4*)s;
    float4 hi = *(const float4*)(s + 4);
    bfrag8 b;
    b[0] = (short)f2bf(lo.x); b[1] = (short)f2bf(lo.y);
    b[2] = (short)f2bf(lo.z); b[3] = (short)f2bf(lo.w);
    b[4] = (short)f2bf(hi.x); b[5] = (short)f2bf(hi.y);
    b[6] = (short)f2bf(hi.z); b[7] = (short)f2bf(hi.w);
    return b;
  }
}

__device__ __forceinline__ bfrag8 scale8(bfrag8 r, float4 sa, float4 sb) {
  bfrag8 o;
  o[0] = (short)f2bf(bfu(r[0]) * sa.x); o[1] = (short)f2bf(bfu(r[1]) * sa.y);
  o[2] = (short)f2bf(bfu(r[2]) * sa.z); o[3] = (short)f2bf(bfu(r[3]) * sa.w);
  o[4] = (short)f2bf(bfu(r[4]) * sb.x); o[5] = (short)f2bf(bfu(r[5]) * sb.y);
  o[6] = (short)f2bf(bfu(r[6]) * sb.z); o[7] = (short)f2bf(bfu(r[7]) * sb.w);
  return o;
}

// --------------------------- LDS overlays ---------------------------------
struct __align__(16) SMk5 { float xi[D]; float ak[4][D]; float alpha[56]; float part[4][2][64]; };
struct __align__(16) SMk7 { float hi[D]; float part[2][64]; };
struct __align__(16) SMga { u16 nvs[2][2][12 * 136]; };  // [wave][unit], rows 0..11
struct __align__(16) SMgb {
  u16 nvs[16 * 136];
  float ev[13 * 128];
  float agg1[128];
  float red[2][16];
  float nw[16];
  int svidx[16];
};
union __align__(16) SMF1 { SMk5 a; SMk7 b; SMga c; };
union __align__(16) SMF2 { SMk5 a; SMgb d; };

// ---------------------------------------------------------------------------
// KPREP_EMB: emb fp32 -> bf16 copy in ws (fallback path).
__global__ __launch_bounds__(256) void kprep_emb(fpp emb, u16* __restrict__ out) {
  long i = ((long)blockIdx.x * 256 + threadIdx.x) * 4;
  if (i + 3 >= (long)NODES * D) return;
  float4 v = *(const float4*)(emb + i);
  out[i + 0] = f2bf(v.x); out[i + 1] = f2bf(v.y);
  out[i + 2] = f2bf(v.z); out[i + 3] = f2bf(v.w);
}

// ---------------------------------------------------------------------------
// prep4 body (device): four weight tensors -> bf16 B-fragment order.
__device__ __forceinline__ void dev_prep4(int i, fpp gw1, fpp gw3,
                                          u16* __restrict__ p1a,
                                          u16* __restrict__ p1b,
                                          u16* __restrict__ p3a,
                                          u16* __restrict__ p3b) {
  fpp W; u16* dst; int KS;
  if (i < 16384)      { W = gw1;             dst = p1a; KS = 4; }
  else if (i < 32768) { W = gw1 + 129 * 128; dst = p1b; KS = 4; i -= 16384; }
  else if (i < 65536) { W = gw3;             dst = p3a; KS = 8; i -= 32768; }
  else                { W = gw3 + 256 * 128; dst = p3b; KS = 8; i -= 65536; }
  int e = i & 7;
  int lane = (i >> 3) & 63;
  int rest = i >> 9;
  int ks = rest % KS, nt = rest / KS;
  int k = ks * 32 + ((lane >> 4) << 3) + e;
  int n = (nt << 4) + (lane & 15);
  dst[i] = f2bf(W[(long)k * 128 + n]);
}

__global__ __launch_bounds__(256) void kprep4(fpp gw1, fpp gw3,
                                              u16* __restrict__ p1a,
                                              u16* __restrict__ p1b,
                                              u16* __restrict__ p3a,
                                              u16* __restrict__ p3b) {
  dev_prep4(blockIdx.x * 256 + threadIdx.x, gw1, gw3, p1a, p1b, p3a, p3b);
}

// ---------------------------------------------------------------------------
// k2 body (device): sess[b,:] = sum_s emb[item[b,s]]*mi / sum_s mi
__device__ __forceinline__ void dev_k2(const int* __restrict__ inputs,
                                       const int* __restrict__ item,
                                       fpp emb, fpw sess, int b, int d) {
  float acc = 0.f, ms = 0.f;
  for (int s = 0; s < S; s++) {
    int inp = inputs[b * S + s];
    float m = (inp != 0) ? 1.f : 0.f;
    int it = item[b * S + s];
    acc += emb[(long)it * D + d] * m;
    ms += m;
  }
  sess[(long)b * D + d] = acc / ms;
}

__global__ __launch_bounds__(128) void k2_sess(const int* __restrict__ inputs,
                                               const int* __restrict__ item,
                                               fpp emb, fpw sess) {
  dev_k2(inputs, item, emb, sess, blockIdx.x, threadIdx.x);
}

// ---------------------------------------------------------------------------
// KP: fused prep — prep4 (384) U emb->bf16 (5000) U k2 (128) U srcu (325).
// srcu[gu] = source node of unit (bs,u): u==0 ? inputs[bs]
//                                        : adj_all[inputs[bs]*12 + u-1].
__global__ __launch_bounds__(256) void kP(fpp gw1, fpp gw3,
                                          u16* __restrict__ p1a, u16* __restrict__ p1b,
                                          u16* __restrict__ p3a, u16* __restrict__ p3b,
                                          fpp emb, u16* __restrict__ embbf,
                                          const int* __restrict__ inputs,
                                          const int* __restrict__ item, fpw sess,
                                          const int* __restrict__ adj_all,
                                          int* __restrict__ srcu_t) {
  int bid = blockIdx.x;
  int t = threadIdx.x;
  if (bid < 384) {
    dev_prep4(bid * 256 + t, gw1, gw3, p1a, p1b, p3a, p3b);
  } else if (bid < 5384) {
    long i = ((long)(bid - 384) * 256 + t) * 4;
    if (i + 3 < (long)NODES * D) {
      float4 v = *(const float4*)(emb + i);
      embbf[i + 0] = f2bf(v.x); embbf[i + 1] = f2bf(v.y);
      embbf[i + 2] = f2bf(v.z); embbf[i + 3] = f2bf(v.w);
    }
  } else if (bid < 5512) {
    if (t < 128) dev_k2(inputs, item, emb, sess, bid - 5384, t);
  } else {
    int gu = (bid - 5512) * 256 + t;
    if (gu < NUNITS) {
      int bs = gu / 13;
      int u = gu - bs * 13;
      int src0 = inputs[bs];
      srcu_t[gu] = (u == 0) ? src0 : adj_all[(long)src0 * SAMPLE + (u - 1)];
    }
  }
}

// ---------------------------------------------------------------------------
// K1: h = emb[inputs]; hf1/hf2 pools; attr gate. Block per (b,s), 128 thr.
template <typename ET>
__global__ __launch_bounds__(128) void k1_gather(
    const int* __restrict__ inputs, const int* __restrict__ as0,
    const int* __restrict__ as1, const int* __restrict__ ss0,
    const int* __restrict__ ss1, const ET* __restrict__ emb, fpp attr_w,
    fpw h, fpw hf1, fpw hf2, float* __restrict__ mi, fpw xA, fpw mir) {
  int bs = blockIdx.x;
  int d = threadIdx.x;
  __shared__ float h_s[D], hf1_s[D];
  int inp = inputs[bs];
  float hv = lde(emb, (long)inp * D + d);
  const int* lists[4] = {as0, as1, ss0, ss1};
  float p[4];
#pragma unroll
  for (int l = 0; l < 4; l++) {
    float sum = 0.f, cnt = 0.f;
    const int* L = lists[l] + (long)bs * NNEI;
#pragma unroll
    for (int n = 0; n < NNEI; n++) {
      int idx = L[n];
      if (idx != 0) { sum += lde(emb, (long)idx * D + d); cnt += 1.f; }
    }
    p[l] = sum / (cnt + 1e-8f);
  }
  float hf1v = 0.5f * (p[0] + p[1]);
  float hf2v = 0.5f * (p[2] + p[3]);
  h_s[d] = hv;
  hf1_s[d] = hf1v;
  __syncthreads();
  float acc = 0.f;
  for (int k = 0; k < D; k++)
    acc += h_s[k] * attr_w[(long)k * D + d] + hf1_s[k] * attr_w[(long)(D + k) * D + d];
  float g = sigm(acc);
  float hfv = g * hv + (1.f - g) * hf1v;
  long o = (long)bs * D + d;
  h[o] = hv; hf1[o] = hf1v; hf2[o] = hf2v; xA[o] = hv; mir[o] = hfv;
  if (d == 0) mi[bs] = (inp != 0) ? 1.f : 0.f;
}

// ---------------------------------------------------------------------------
// dev_kga2: TWO phase-A units per wave. srcu precomputed -> chain is
// srcu (coalesced) -> rid/nw -> emb. nvs store un-branched: lanes mrow>=12
// duplicate rows 0..3 (identical bytes; those tile rows are dead via q==3).
template <typename ET>
__device__ __forceinline__ void dev_kga2(
    u16* __restrict__ nvs0, u16* __restrict__ nvs1,
    const int* __restrict__ srcu_t, const int* __restrict__ adj_all, fpp num,
    const ET* __restrict__ emb, fpp sess, fpp W1a, fpp W2a,
    const u16* __restrict__ p1a, u16* __restrict__ aggws, int gu0, int lane) {
  int q = lane >> 4;
  int mrow = lane & 15;
  int r12 = (mrow < 12) ? mrow : mrow - 12;
  float wl8[8], w28[8];
#pragma unroll
  for (int nt = 0; nt < 8; nt++) {
    int col = nt * 16 + mrow;
    wl8[nt] = W1a[(long)D * D + col];
    w28[nt] = W2a[col];
  }
  bfrag8 sA[2][4];
  float nwq[2][4];
#pragma unroll
  for (int g = 0; g < 2; g++) {
    int gu = gu0 + g;
    int b = gu / 650;  // = (gu/13)/S
    int srcu = srcu_t[gu];
    int rid = adj_all[(long)srcu * SAMPLE + r12];
#pragma unroll
    for (int i = 0; i < 4; i++)
      nwq[g][i] = (q < 3) ? num[(long)srcu * SAMPLE + q * 4 + i] : 0.f;
    const float* sessb = sess + (long)b * D;
    u16* nb = g ? nvs1 : nvs0;
    bfrag8 raw[4];
#pragma unroll
    for (int ks = 0; ks < 4; ks++)
      raw[ks] = load_frag(emb, (long)rid, ks * 32 + q * 8);
#pragma unroll
    for (int ks = 0; ks < 4; ks++)
      *(bfrag8*)(nb + r12 * 136 + ks * 32 + q * 8) = raw[ks];
#pragma unroll
    for (int ks = 0; ks < 4; ks++) {
      float4 sa = *(const float4*)(sessb + ks * 32 + q * 8);
      float4 sb = *(const float4*)(sessb + ks * 32 + q * 8 + 4);
      sA[g][ks] = scale8(raw[ks], sa, sb);
    }
  }
  float lp[2][4] = {{0.f, 0.f, 0.f, 0.f}, {0.f, 0.f, 0.f, 0.f}};
#pragma unroll
  for (int nt = 0; nt < 8; nt++) {
    f32x4 acc0 = (f32x4){0.f, 0.f, 0.f, 0.f};
    f32x4 acc1 = (f32x4){0.f, 0.f, 0.f, 0.f};
#pragma unroll
    for (int ks = 0; ks < 4; ks++) {
      bfrag8 bb = *(const bfrag8*)(p1a + ks * 512 + lane * 8 + nt * 2048);
      acc0 = __builtin_amdgcn_mfma_f32_16x16x32_bf16(sA[0][ks], bb, acc0, 0, 0, 0);
      acc1 = __builtin_amdgcn_mfma_f32_16x16x32_bf16(sA[1][ks], bb, acc1, 0, 0, 0);
    }
#pragma unroll
    for (int i = 0; i < 4; i++) {
      lp[0][i] += leaky(acc0[i] + nwq[0][i] * wl8[nt]) * w28[nt];
      lp[1][i] += leaky(acc1[i] + nwq[1][i] * wl8[nt]) * w28[nt];
    }
  }
#pragma unroll
  for (int off = 1; off <= 8; off <<= 1)
#pragma unroll
    for (int g = 0; g < 2; g++)
#pragma unroll
      for (int i = 0; i < 4; i++) lp[g][i] += __shfl_xor(lp[g][i], off, 64);
#pragma unroll
  for (int g = 0; g < 2; g++) {
    float m4 = (q < 3) ? fmaxf(fmaxf(lp[g][0], lp[g][1]), fmaxf(lp[g][2], lp[g][3]))
                       : NEG_BIG;
    m4 = fmaxf(m4, __shfl_xor(m4, 16, 64));
    m4 = fmaxf(m4, __shfl_xor(m4, 32, 64));
    float e0 = 0.f, e1 = 0.f, e2 = 0.f, e3 = 0.f, ssum = 0.f;
    if (q < 3) {
      e0 = __expf(lp[g][0] - m4); e1 = __expf(lp[g][1] - m4);
      e2 = __expf(lp[g][2] - m4); e3 = __expf(lp[g][3] - m4);
      ssum = e0 + e1 + e2 + e3;
    }
    ssum += __shfl_xor(ssum, 16, 64);
    ssum += __shfl_xor(ssum, 32, 64);
    float inv = 1.f / ssum;
    float al[4] = {e0 * inv, e1 * inv, e2 * inv, e3 * inv};
    float aj[12];
#pragma unroll
    for (int j = 0; j < 12; j++) aj[j] = __shfl(al[j & 3], (j >> 2) << 4, 64);
    const u16* nb = g ? nvs1 : nvs0;
    float a0 = 0.f, a1 = 0.f;
#pragma unroll
    for (int j = 0; j < 12; j++) {
      unsigned pv = *(const unsigned*)(nb + j * 136 + lane * 2);
      union { unsigned u; float f; } lo, hi;
      lo.u = pv << 16; hi.u = pv & 0xffff0000u;
      a0 += aj[j] * lo.f; a1 += aj[j] * hi.f;
    }
    unsigned pk = ((unsigned)f2bf(a1) << 16) | (unsigned)f2bf(a0);
    *(unsigned*)(aggws + (long)(gu0 + g) * 128 + lane * 2) = pk;
  }
}

// ---------------------------------------------------------------------------
// dev_kgb: phases B/C + final per bs at 128 thr. svidx/nw from srcu table.
template <typename ET>
__device__ __forceinline__ void dev_kgb(
    SMgb& sm, const int* __restrict__ srcu_t,
    fpp num, const ET* __restrict__ emb, fpp sess, fpp W1b, fpp W2b, fpp W3b,
    const u16* __restrict__ p1b, const u16* __restrict__ p3a,
    const u16* __restrict__ aggws, fpw hg, int bs) {
  int b = bs / S;
  int d = threadIdx.x;
  int lane = d & 63;
  int w = d >> 6;
  int q = lane >> 4;
  int mrow = lane & 15;

#pragma unroll
  for (int r = 12; r < 16; r++) {
    sm.nvs[r * 136 + d] = 0;
    if (d < 8) sm.nvs[r * 136 + 128 + d] = 0;
  }
  if (d < 16) sm.svidx[d] = (d < 13) ? srcu_t[bs * 13 + d] : 0;
  if (d < SAMPLE) sm.nw[d] = num[(long)srcu_t[bs * 13] * SAMPLE + d];
  float sess_d = sess[(long)b * D + d];
  __syncthreads();

  // ---- Phase B: [sv|agg] (13x256) @ W3a -> ev (tanh)
  {
    long svr = sm.svidx[mrow];
    f32x4 accB[4];
#pragma unroll
    for (int nt = 0; nt < 4; nt++) accB[nt] = (f32x4){0.f, 0.f, 0.f, 0.f};
#pragma unroll
    for (int ks = 0; ks < 4; ks++) {
      bfrag8 a = (bfrag8){0, 0, 0, 0, 0, 0, 0, 0};
      if (mrow < 13) a = load_frag(emb, svr, ks * 32 + q * 8);
      const u16* pb = p3a + (w * 32 + ks) * 512 + lane * 8;
#pragma unroll
      for (int nt = 0; nt < 4; nt++)
        accB[nt] = __builtin_amdgcn_mfma_f32_16x16x32_bf16(
            a, *(const bfrag8*)(pb + nt * 4096), accB[nt], 0, 0, 0);
    }
#pragma unroll
    for (int ks = 4; ks < 8; ks++) {
      bfrag8 a = (bfrag8){0, 0, 0, 0, 0, 0, 0, 0};
      if (mrow < 13)
        a = *(const bfrag8*)(aggws + ((long)bs * 13 + mrow) * 128 + (ks - 4) * 32 + q * 8);
      const u16* pb = p3a + (w * 32 + ks) * 512 + lane * 8;
#pragma unroll
      for (int nt = 0; nt < 4; nt++)
        accB[nt] = __builtin_amdgcn_mfma_f32_16x16x32_bf16(
            a, *(const bfrag8*)(pb + nt * 4096), accB[nt], 0, 0, 0);
    }
#pragma unroll
    for (int nt = 0; nt < 4; nt++) {
      int col = (w * 4 + nt) * 16 + mrow;
#pragma unroll
      for (int i = 0; i < 4; i++) {
        int u2 = q * 4 + i;
        if (u2 < 13) sm.ev[u2 * 128 + col] = tanh_f(accB[nt][i]);
      }
    }
  }
  __syncthreads();

  // ---- Phase C: hop-1 unit ----------------------------------------------
  {
    float w2B[4], wlB[4];
#pragma unroll
    for (int nt = 0; nt < 4; nt++) {
      int col = (w * 4 + nt) * 16 + mrow;
      w2B[nt] = W2b[col];
      wlB[nt] = W1b[(long)D * D + col];
    }
    float evreg[SAMPLE];
#pragma unroll
    for (int j = 0; j < SAMPLE; j++) {
      float e = sm.ev[(1 + j) * 128 + d];
      evreg[j] = e;
      sm.nvs[j * 136 + d] = f2bf(e * sess_d);
    }
    __syncthreads();

    f32x4 acc[4];
#pragma unroll
    for (int nt = 0; nt < 4; nt++) acc[nt] = (f32x4){0.f, 0.f, 0.f, 0.f};
#pragma unroll
    for (int ks = 0; ks < 4; ks++) {
      bfrag8 a = *(const bfrag8*)(sm.nvs + mrow * 136 + q * 8 + ks * 32);
      const u16* pb = p1b + (w * 16 + ks) * 512 + lane * 8;
#pragma unroll
      for (int nt = 0; nt < 4; nt++) {
        bfrag8 bb = *(const bfrag8*)(pb + nt * 2048);
        acc[nt] = __builtin_amdgcn_mfma_f32_16x16x32_bf16(a, bb, acc[nt], 0, 0, 0);
      }
    }
    float lp[4] = {0.f, 0.f, 0.f, 0.f};
    float nwq[4];
#pragma unroll
    for (int i = 0; i < 4; i++) nwq[i] = (q < 3) ? sm.nw[q * 4 + i] : 0.f;
#pragma unroll
    for (int nt = 0; nt < 4; nt++)
#pragma unroll
      for (int i = 0; i < 4; i++)
        lp[i] += leaky(acc[nt][i] + nwq[i] * wlB[nt]) * w2B[nt];
#pragma unroll
    for (int off = 1; off <= 8; off <<= 1)
#pragma unroll
      for (int i = 0; i < 4; i++) lp[i] += __shfl_xor(lp[i], off, 64);
    if (mrow == 0 && q < 3) {
#pragma unroll
      for (int i = 0; i < 4; i++) sm.red[w][q * 4 + i] = lp[i];
    }
    __syncthreads();

    float lg[SAMPLE];
#pragma unroll
    for (int j = 0; j < SAMPLE; j++) lg[j] = sm.red[0][j] + sm.red[1][j];
    float mx = lg[0];
#pragma unroll
    for (int j = 1; j < SAMPLE; j++) mx = fmaxf(mx, lg[j]);
    float se = 0.f;
#pragma unroll
    for (int j = 0; j < SAMPLE; j++) { lg[j] = __expf(lg[j] - mx); se += lg[j]; }
    float inv = 1.f / se;
    float agg1d = 0.f;
#pragma unroll
    for (int j = 0; j < SAMPLE; j++) agg1d += lg[j] * inv * evreg[j];
    sm.agg1[d] = agg1d;
    __syncthreads();

    float accf = 0.f;
#pragma unroll 4
    for (int k4 = 0; k4 < 32; k4++) {
      float4 a4 = *(const float4*)&sm.ev[4 * k4];
      float4 g4 = *(const float4*)&sm.agg1[4 * k4];
      accf += a4.x * W3b[(4 * k4 + 0) * D + d] + a4.y * W3b[(4 * k4 + 1) * D + d] +
              a4.z * W3b[(4 * k4 + 2) * D + d] + a4.w * W3b[(4 * k4 + 3) * D + d] +
              g4.x * W3b[(D + 4 * k4 + 0) * D + d] + g4.y * W3b[(D + 4 * k4 + 1) * D + d] +
              g4.z * W3b[(D + 4 * k4 + 2) * D + d] + g4.w * W3b[(D + 4 * k4 + 3) * D + d];
    }
    hg[(long)bs * D + d] = tanh_f(accf);
  }
}

// ---------------------------------------------------------------------------
// dev_k5ab: fused local-attention + mirror gate (+highway on fin=1).
__device__ __forceinline__ void dev_k5ab(SMk5& sm, fpp x, const int* __restrict__ adj,
                                         fpp a_loc, fpp w1, fpp w2, fpw xout,
                                         fpw mir, fpp hw, fpp h, fpw x_dot,
                                         float* __restrict__ h_local, int bs, int fin) {
  int b = bs / S;
  int row = bs % S;
  int tid = threadIdx.x;
  long idx = ((long)b * S + row) * D + tid;
  sm.xi[tid] = x[idx];
#pragma unroll
  for (int k = 0; k < 4; k++) sm.ak[k][tid] = a_loc[(long)k * D + tid];
  __syncthreads();
  {
    int j = tid & 63, hf = tid >> 6;
    float a0 = 0.f, a1 = 0.f, a2 = 0.f, a3 = 0.f;
    if (j < S) {
      const float* xj = x + ((long)b * S + j) * D + hf * 64;
      int off = hf * 64;
      for (int dd = 0; dd < 64; dd++) {
        float prod = sm.xi[off + dd] * xj[dd];
        a0 += prod * sm.ak[0][off + dd];
        a1 += prod * sm.ak[1][off + dd];
        a2 += prod * sm.ak[2][off + dd];
        a3 += prod * sm.ak[3][off + dd];
      }
    }
    sm.part[0][hf][j] = a0; sm.part[1][hf][j] = a1;
    sm.part[2][hf][j] = a2; sm.part[3][hf][j] = a3;
  }
  __syncthreads();
  if (tid < 64) {
    int j = tid;
    float att;
    if (j < S) {
      float acc0 = sm.part[0][0][j] + sm.part[0][1][j];
      float acc1 = sm.part[1][0][j] + sm.part[1][1][j];
      float acc2 = sm.part[2][0][j] + sm.part[2][1][j];
      float acc3 = sm.part[3][0][j] + sm.part[3][1][j];
      int av = adj[((long)b * S + row) * S + j];
      att = -9e15f;  // reference's own sentinel
      if (av == 1) att = leaky(acc0);
      else if (av == 2) att = leaky(acc1);
      else if (av == 3) att = leaky(acc2);
      else if (av == 4) att = leaky(acc3);
    } else {
      att = NEG_BIG;
    }
    float mx = att;
#pragma unroll
    for (int o = 32; o > 0; o >>= 1) mx = fmaxf(mx, __shfl_xor(mx, o, 64));
    float e = __expf(att - mx);
    float ssum = e;
#pragma unroll
    for (int o = 32; o > 0; o >>= 1) ssum += __shfl_xor(ssum, o, 64);
    if (j < S) sm.alpha[j] = e / ssum;
  }
  __syncthreads();
  float xn = 0.f;
  for (int j = 0; j < S; j++) xn += sm.alpha[j] * x[((long)b * S + j) * D + tid];
  float mv = mir[idx];
  sm.ak[0][tid] = xn;
  sm.ak[1][tid] = mv;
  __syncthreads();
  float a2m = 0.f;
  for (int k = 0; k < D; k++)
    a2m += sm.ak[0][k] * w1[(long)k * D + tid] + sm.ak[1][k] * w2[(long)k * D + tid];
  float g = sigm(a2m);
  float xg = g * xn + (1.f - g) * mv;
  if (!fin) {
    xout[idx] = xg;
    mir[idx] = g * mv + (1.f - g) * xn;
    return;
  }
  float hv = h[idx];
  sm.ak[2][tid] = hv;
  sm.ak[3][tid] = xg;
  __syncthreads();
  float a3m = 0.f;
  for (int k = 0; k < D; k++)
    a3m += sm.ak[2][k] * hw[(long)k * D + tid] + sm.ak[3][k] * hw[(long)(D + k) * D + tid];
  float gh = sigm(a3m);
  float xd = gh * hv + (1.f - gh) * xg;
  x_dot[idx] = xd;
  if (row == S - 1) h_local[(long)b * D + tid] = xd;
}

// ---------------------------------------------------------------------------
// dev_k7: simi loss per (b,i). atomicAdd to ws.
__device__ __forceinline__ void dev_k7(SMk7& sm, fpp hf1, fpp hf2,
                                       const int* __restrict__ simi_mask,
                                       float* __restrict__ loss, int bs) {
  int b = bs / S;
  int i = bs % S;
  int t = threadIdx.x;
  sm.hi[t] = hf1[((long)b * S + i) * D + t];
  __syncthreads();
  {
    int j = t & 63, hf = t >> 6;
    float acc = 0.f;
    if (j < S) {
      const float* r = hf2 + ((long)b * S + j) * D + hf * 64;
      int off = hf * 64;
      for (int dd = 0; dd < 64; dd++) acc += sm.hi[off + dd] * r[dd];
    }
    sm.part[hf][j] = acc;
  }
  __syncthreads();
  if (t < 64) {
    int j = t;
    float sim = (j < S) ? (sm.part[0][j] + sm.part[1][j]) * (1.0f / TEMPV) : NEG_BIG;
    float mx = sim;
#pragma unroll
    for (int o = 32; o > 0; o >>= 1) mx = fmaxf(mx, __shfl_xor(mx, o, 64));
    float e = __expf(sim - mx);
    float ssum = e;
#pragma unroll
    for (int o = 32; o > 0; o >>= 1) ssum += __shfl_xor(ssum, o, 64);
    float contrib = 0.f;
    if (j < S) {
      float p = e / ssum;
      float l = -__logf(p + 1e-8f);
      if (simi_mask[((long)b * S + i) * S + j] == 1) contrib = l;
    }
#pragma unroll
    for (int o = 32; o > 0; o >>= 1) contrib += __shfl_xor(contrib, o, 64);
    if (j == 0) atomicAdd(loss, contrib);
  }
}

// ---------------------------------------------------------------------------
// Fused launch 1 (INTERLEAVED): per 21-block group, 13 GA + 8 {k5ab0,k7}.
template <typename ET>
__global__ __launch_bounds__(128) void kF1(
    const int* __restrict__ srcu_t, const int* __restrict__ adj_all, fpp num,
    const ET* __restrict__ emb, fpp sess, fpp W1a, fpp W2a,
    const u16* __restrict__ p1a, u16* __restrict__ aggws,
    fpp xA, const int* __restrict__ adj, fpp a_loc, fpp mw1, fpp mw2,
    fpw xB, fpw mir,
    fpp hf1, fpp hf2, const int* __restrict__ simi_mask,
    float* __restrict__ loss) {
  __shared__ SMF1 sm;
  int bid = blockIdx.x;
  int grp = bid / 21;
  int r = bid - grp * 21;
  if (r < 13) {
    int ga = grp * 13 + r;
    int t = threadIdx.x;
    int w = t >> 6, lane = t & 63;
    dev_kga2<ET>(sm.c.nvs[w][0], sm.c.nvs[w][1], srcu_t, adj_all, num, emb,
                 sess, W1a, W2a, p1a, aggws, ga * 4 + w * 2, lane);
  } else {
    int o = grp * 8 + (r - 13);
    if (o & 1)
      dev_k7(sm.b, hf1, hf2, simi_mask, loss, o >> 1);
    else
      dev_k5ab(sm.a, xA, adj, a_loc, mw1, mw2, xB, mir, nullptr, nullptr,
               nullptr, nullptr, o >> 1, 0);
  }
}

// ---------------------------------------------------------------------------
// Fused launch 2 (INTERLEAVED): even -> kGB, odd -> k5ab pass1 (fin).
template <typename ET>
__global__ __launch_bounds__(128) void kF2(
    const int* __restrict__ srcu_t, fpp num,
    const ET* __restrict__ emb, fpp sess, fpp W1b, fpp W2b, fpp W3b,
    const u16* __restrict__ p1b, const u16* __restrict__ p3a,
    const u16* __restrict__ aggws, fpw hg,
    fpp xB, const int* __restrict__ adj, fpp a_loc2, fpp mw1b, fpp mw2b,
    fpw mir, fpp hw, fpp h, fpw x_dot, float* __restrict__ h_local) {
  __shared__ SMF2 sm;
  int bid = blockIdx.x;
  if (bid & 1)
    dev_k5ab(sm.a, xB, adj, a_loc2, mw1b, mw2b, nullptr, mir, hw, h, x_dot,
             h_local, bid >> 1, 1);
  else
    dev_kgb<ET>(sm.d, srcu_t, num, emb, sess, W1b, W2b, W3b, p1b,
                p3a, aggws, hg, bid >> 1);
}

// ---------------------------------------------------------------------------
// Standalone wrappers (fallback path).
__global__ __launch_bounds__(128) void k5ab(fpp x, const int* __restrict__ adj,
                                            fpp a_loc, fpp w1, fpp w2,
                                            fpw xout, fpw mir,
                                            fpp hw, fpp h, fpw x_dot,
                                            float* __restrict__ h_local,
                                            int fin) {
  __shared__ SMk5 sm;
  dev_k5ab(sm, x, adj, a_loc, w1, w2, xout, mir, hw, h, x_dot, h_local,
           blockIdx.x, fin);
}

__global__ __launch_bounds__(128) void k7_simi(fpp hf1, fpp hf2,
                                               const int* __restrict__ simi_mask,
                                               float* __restrict__ loss) {
  __shared__ SMk7 sm;
  dev_k7(sm, hf1, hf2, simi_mask, loss, blockIdx.x);
}

// ---------------------------------------------------------------------------
// KG_MONO: verified monolithic kG (fallback when ws too small for split).
template <typename ET>
__global__ __launch_bounds__(128) void kG_mono(
    const int* __restrict__ inputs, const int* __restrict__ adj_all,
    fpp num, const ET* __restrict__ emb, fpp sess,
    fpp W1a, fpp W2a, fpp W1b, fpp W2b, fpp W3b,
    const u16* __restrict__ p1a, const u16* __restrict__ p1b,
    const u16* __restrict__ p3a, fpw hg) {
  int bs = blockIdx.x;
  int b = bs / S;
  int d = threadIdx.x;
  int lane = d & 63;
  int w = d >> 6;
  int q = lane >> 4;
  int mrow = lane & 15;

  __shared__ __align__(16) u16 nvs_l[16 * 136];
  __shared__ __align__(16) u16 svagg_l[16 * 264];
  __shared__ __align__(16) float ev_l[13 * 128];
  __shared__ __align__(16) float agg1_l[128];
  __shared__ float red_l[2][16];
  __shared__ float nw_l[16];

#pragma unroll
  for (int r = 12; r < 16; r++) {
    nvs_l[r * 136 + d] = 0;
    if (d < 8) nvs_l[r * 136 + 128 + d] = 0;
  }
#pragma unroll
  for (int r = 13; r < 16; r++) {
    svagg_l[r * 264 + d] = 0;
    svagg_l[r * 264 + 128 + d] = 0;
    if (d < 8) svagg_l[r * 264 + 256 + d] = 0;
  }

  float sess_d = sess[(long)b * D + d];
  int src0 = __builtin_amdgcn_readfirstlane(inputs[bs]);
  int n1[SAMPLE];
#pragma unroll
  for (int j = 0; j < SAMPLE; j++)
    n1[j] = __builtin_amdgcn_readfirstlane(adj_all[(long)src0 * SAMPLE + j]);
  svagg_l[0 * 264 + d] = f2bf(lde(emb, (long)src0 * D + d));

  float w2A[4], wlA[4], w2B[4], wlB[4];
#pragma unroll
  for (int nt = 0; nt < 4; nt++) {
    int col = (w * 4 + nt) * 16 + mrow;
    w2A[nt] = W2a[col];
    wlA[nt] = W1a[(long)D * D + col];
    w2B[nt] = W2b[col];
    wlB[nt] = W1b[(long)D * D + col];
  }

  float pre[SAMPLE], pnw = 0.f;
  {
#pragma unroll
    for (int j = 0; j < SAMPLE; j++)
      pre[j] = lde(emb, (long)n1[j] * D + d);
    if (d < SAMPLE) pnw = num[(long)src0 * SAMPLE + d];
  }
  for (int u = 0; u < 13; u++) {
    if (d < SAMPLE) nw_l[d] = pnw;
    float nvreg[SAMPLE];
#pragma unroll
    for (int j = 0; j < SAMPLE; j++) {
      nvreg[j] = pre[j];
      nvs_l[j * 136 + d] = f2bf(pre[j] * sess_d);
    }
    if (u == 0) {
#pragma unroll
      for (int j = 0; j < SAMPLE; j++)
        svagg_l[(1 + j) * 264 + d] = f2bf(nvreg[j]);
    }
    __syncthreads();
    if (u < 12) {
      int srcn = n1[u];
#pragma unroll
      for (int j = 0; j < SAMPLE; j++) {
        int nj = __builtin_amdgcn_readfirstlane(adj_all[(long)srcn * SAMPLE + j]);
        pre[j] = lde(emb, (long)nj * D + d);
      }
      if (d < SAMPLE) pnw = num[(long)srcn * SAMPLE + d];
    }
    f32x4 acc[4];
#pragma unroll
    for (int nt = 0; nt < 4; nt++) acc[nt] = (f32x4){0.f, 0.f, 0.f, 0.f};
#pragma unroll
    for (int ks = 0; ks < 4; ks++) {
      bfrag8 a = *(const bfrag8*)(nvs_l + mrow * 136 + q * 8 + ks * 32);
      const u16* pb = p1a + (w * 16 + ks) * 512 + lane * 8;
#pragma unroll
      for (int nt = 0; nt < 4; nt++) {
        bfrag8 bb = *(const bfrag8*)(pb + nt * 2048);
        acc[nt] = __builtin_amdgcn_mfma_f32_16x16x32_bf16(a, bb, acc[nt], 0, 0, 0);
      }
    }
    float lp[4] = {0.f, 0.f, 0.f, 0.f};
    float nwq[4];
#pragma unroll
    for (int i = 0; i < 4; i++) nwq[i] = (q < 3) ? nw_l[q * 4 + i] : 0.f;
#pragma unroll
    for (int nt = 0; nt < 4; nt++)
#pragma unroll
      for (int i = 0; i < 4; i++)
        lp[i] += leaky(acc[nt][i] + nwq[i] * wlA[nt]) * w2A[nt];
#pragma unroll
    for (int off = 1; off <= 8; off <<= 1)
#pragma unroll
      for (int i = 0; i < 4; i++) lp[i] += __shfl_xor(lp[i], off, 64);
    if (mrow == 0 && q < 3) {
#pragma unroll
      for (int i = 0; i < 4; i++) red_l[w][q * 4 + i] = lp[i];
    }
    __syncthreads();
    float lg[SAMPLE];
#pragma unroll
    for (int j = 0; j < SAMPLE; j++) lg[j] = red_l[0][j] + red_l[1][j];
    float mx = lg[0];
#pragma unroll
    for (int j = 1; j < SAMPLE; j++) mx = fmaxf(mx, lg[j]);
    float se = 0.f;
#pragma unroll
    for (int j = 0; j < SAMPLE; j++) { lg[j] = __expf(lg[j] - mx); se += lg[j]; }
    float inv = 1.f / se;
    float aggd = 0.f;
#pragma unroll
    for (int j = 0; j < SAMPLE; j++) aggd += lg[j] * inv * nvreg[j];
    svagg_l[u * 264 + 128 + d] = f2bf(aggd);
  }
  __syncthreads();

  {
    f32x4 accB[4];
#pragma unroll
    for (int nt = 0; nt < 4; nt++) accB[nt] = (f32x4){0.f, 0.f, 0.f, 0.f};
#pragma unroll
    for (int ks = 0; ks < 8; ks++) {
      bfrag8 a = *(const bfrag8*)(svagg_l + mrow * 264 + q * 8 + ks * 32);
      const u16* pb = p3a + (w * 32 + ks) * 512 + lane * 8;
#pragma unroll
      for (int nt = 0; nt < 4; nt++) {
        bfrag8 bb = *(const bfrag8*)(pb + nt * 4096);
        accB[nt] = __builtin_amdgcn_mfma_f32_16x16x32_bf16(a, bb, accB[nt], 0, 0, 0);
      }
    }
#pragma unroll
    for (int nt = 0; nt < 4; nt++) {
      int col = (w * 4 + nt) * 16 + mrow;
#pragma unroll
      for (int i = 0; i < 4; i++) {
        int u2 = q * 4 + i;
        if (u2 < 13) ev_l[u2 * 128 + col] = tanh_f(accB[nt][i]);
      }
    }
    __syncthreads();
  }

  {
    float evreg[SAMPLE];
#pragma unroll
    for (int j = 0; j < SAMPLE; j++) {
      float e = ev_l[(1 + j) * 128 + d];
      evreg[j] = e;
      nvs_l[j * 136 + d] = f2bf(e * sess_d);
    }
    if (d < SAMPLE) nw_l[d] = num[(long)src0 * SAMPLE + d];
    __syncthreads();

    f32x4 acc[4];
#pragma unroll
    for (int nt = 0; nt < 4; nt++) acc[nt] = (f32x4){0.f, 0.f, 0.f, 0.f};
#pragma unroll
    for (int ks = 0; ks < 4; ks++) {
      bfrag8 a = *(const bfrag8*)(nvs_l + mrow * 136 + q * 8 + ks * 32);
      const u16* pb = p1b + (w * 16 + ks) * 512 + lane * 8;
#pragma unroll
      for (int nt = 0; nt < 4; nt++) {
        bfrag8 bb = *(const bfrag8*)(pb + nt * 2048);
        acc[nt] = __builtin_amdgcn_mfma_f32_16x16x32_bf16(a, bb, acc[nt], 0, 0, 0);
      }
    }
    float lp[4] = {0.f, 0.f, 0.f, 0.f};
    float nwq[4];
#pragma unroll
    for (int i = 0; i < 4; i++) nwq[i] = (q < 3) ? nw_l[q * 4 + i] : 0.f;
#pragma unroll
    for (int nt = 0; nt < 4; nt++)
#pragma unroll
      for (int i = 0; i < 4; i++)
        lp[i] += leaky(acc[nt][i] + nwq[i] * wlB[nt]) * w2B[nt];
#pragma unroll
    for (int off = 1; off <= 8; off <<= 1)
#pragma unroll
      for (int i = 0; i < 4; i++) lp[i] += __shfl_xor(lp[i], off, 64);
    if (mrow == 0 && q < 3) {
#pragma unroll
      for (int i = 0; i < 4; i++) red_l[w][q * 4 + i] = lp[i];
    }
    __syncthreads();

    float lg[SAMPLE];
#pragma unroll
    for (int j = 0; j < SAMPLE; j++) lg[j] = red_l[0][j] + red_l[1][j];
    float mx = lg[0];
#pragma unroll
    for (int j = 1; j < SAMPLE; j++) mx = fmaxf(mx, lg[j]);
    float se = 0.f;
#pragma unroll
    for (int j = 0; j < SAMPLE; j++) { lg[j] = __expf(lg[j] - mx); se += lg[j]; }
    float inv = 1.f / se;
    float agg1d = 0.f;
#pragma unroll
    for (int j = 0; j < SAMPLE; j++) agg1d += lg[j] * inv * evreg[j];
    agg1_l[d] = agg1d;
    __syncthreads();

    float accf = 0.f;
#pragma unroll 4
    for (int k4 = 0; k4 < 32; k4++) {
      float4 a4 = *(const float4*)&ev_l[4 * k4];
      float4 g4 = *(const float4*)&agg1_l[4 * k4];
      accf += a4.x * W3b[(4 * k4 + 0) * D + d] + a4.y * W3b[(4 * k4 + 1) * D + d] +
              a4.z * W3b[(4 * k4 + 2) * D + d] + a4.w * W3b[(4 * k4 + 3) * D + d] +
              g4.x * W3b[(D + 4 * k4 + 0) * D + d] + g4.y * W3b[(D + 4 * k4 + 1) * D + d] +
              g4.z * W3b[(D + 4 * k4 + 2) * D + d] + g4.w * W3b[(D + 4 * k4 + 3) * D + d];
    }
    hg[(long)bs * D + d] = tanh_f(accf);
  }
}

// ---------------------------------------------------------------------------
// K8: GLU epilogue per batch, 512 threads = 4 s-groups (serial 50 -> 13).
__global__ __launch_bounds__(512) void k8_glu(
    fpp hg, fpp x_dot, fpp pos, fpp h_local, const float* __restrict__ mi,
    fpp glu1, fpp glu2, fpp glu4, fpp glu4b, fpp w_s, fpp gate_w, fpw zh) {
  int b = blockIdx.x;
  int t = threadIdx.x;
  int d = t & 127;
  int g = t >> 7;   // s-group 0..3
  __shared__ float hs_s[D], hl_s[D];
  __shared__ float hp_g[4][D], part[4][D], zg_g[4][D];
  __shared__ float red2[4][2];
  float msf = 0.f;
  for (int s = 0; s < S; s++) msf += mi[b * S + s];
  float hsacc = 0.f;
  for (int s = g * 13; s < min(S, g * 13 + 13); s++)
    hsacc += hg[((long)b * S + s) * D + d] * mi[b * S + s];
  part[g][d] = hsacc;
  if (g == 1) hl_s[d] = h_local[(long)b * D + d];
  __syncthreads();
  if (g == 0) hs_s[d] = (part[0][d] + part[1][d] + part[2][d] + part[3][d]) / msf;
  __syncthreads();
  float c = glu4b[d];
  for (int k = 0; k < D; k++)
    c += hs_s[k] * glu2[(long)k * D + d] + hl_s[k] * glu4[(long)k * D + d];
  float wsd = w_s[d];
  float zg = 0.f;
  for (int it = 0; it < 13; it++) {
    int s = g * 13 + it;
    bool act = s < S;
    float hp = 0.f;
    if (act) {
      hp = x_dot[((long)b * S + s) * D + d] + pos[(long)s * D + d];
      hp_g[g][d] = hp;
    }
    __syncthreads();
    if (act) {
      float acc = c;
      for (int k = 0; k < D; k++) acc += hp_g[g][k] * glu1[(long)k * D + d];
      float v = sigm(acc) * wsd;
#pragma unroll
      for (int o = 32; o > 0; o >>= 1) v += __shfl_down(v, o, 64);
      if ((t & 63) == 0) red2[g][(t >> 6) & 1] = v;
    }
    __syncthreads();
    if (act) {
      float beta = (red2[g][0] + red2[g][1]) * mi[b * S + s];
      zg += beta * hp;
    }
    __syncthreads();
  }
  zg_g[g][d] = zg;
  __syncthreads();
  if (g == 0) {
    float zgf = zg_g[0][d] + zg_g[1][d] + zg_g[2][d] + zg_g[3][d];
    hp_g[0][d] = zgf;
  }
  __syncthreads();
  if (g == 0) {
    float zgf = hp_g[0][d];
    float acc = 0.f;
    for (int k = 0; k < D; k++)
      acc += hp_g[0][k] * gate_w[(long)k * D + d] +
             hl_s[k] * gate_w[(long)(D + k) * D + d];
    float gf = sigm(acc) * MUV;
    zh[(long)b * D + d] = gf * hl_s[d] + (1.f - gf) * zgf;
  }
}

// ---------------------------------------------------------------------------
// K9: scores = zh(128x128) @ emb[1:]^T via bf16 MFMA.
template <typename ET>
__global__ __launch_bounds__(256) void k9_scores(fpp zh, const ET* __restrict__ emb,
                                                 fpp loss, float* __restrict__ out) {
  int t = threadIdx.x;
  if (blockIdx.x == 0 && t == 0) out[0] = loss[0] * (1.0f / (float)B);
  int lane = t & 63;
  int w = t >> 6;
  int q = lane >> 4;
  int mrow = lane & 15;
  long n = (long)blockIdx.x * 64 + w * 16 + mrow;
  bool valid = n < NSC;
  long nrow = valid ? (n + 1) : 1;
  bfrag8 bfr[4];
#pragma unroll
  for (int ks = 0; ks < 4; ks++) {
    if constexpr (sizeof(ET) == 2) {
      bfr[ks] = *(const bfrag8*)(const void*)(emb + nrow * D + ks * 32 + q * 8);
    } else {
      const float* src = (const float*)(emb + nrow * D + ks * 32 + q * 8);
      float4 lo = *(const float4*)src;
      float4 hi = *(const float4*)(src + 4);
      bfrag8 bb;
      bb[0] = (short)f2bf(lo.x); bb[1] = (short)f2bf(lo.y);
      bb[2] = (short)f2bf(lo.z); bb[3] = (short)f2bf(lo.w);
      bb[4] = (short)f2bf(hi.x); bb[5] = (short)f2bf(hi.y);
      bb[6] = (short)f2bf(hi.z); bb[7] = (short)f2bf(hi.w);
      bfr[ks] = bb;
    }
  }
#pragma unroll
  for (int mt = 0; mt < 8; mt++) {
    f32x4 acc = (f32x4){0.f, 0.f, 0.f, 0.f};
#pragma unroll
    for (int ks = 0; ks < 4; ks++) {
      const float* za = zh + (long)(mt * 16 + mrow) * D + ks * 32 + q * 8;
      float4 lo = *(const float4*)za;
      float4 hi = *(const float4*)(za + 4);
      bfrag8 a;
      a[0] = (short)f2bf(lo.x); a[1] = (short)f2bf(lo.y);
      a[2] = (short)f2bf(lo.z); a[3] = (short)f2bf(lo.w);
      a[4] = (short)f2bf(hi.x); a[5] = (short)f2bf(hi.y);
      a[6] = (short)f2bf(hi.z); a[7] = (short)f2bf(hi.w);
      acc = __builtin_amdgcn_mfma_f32_16x16x32_bf16(a, bfr[ks], acc, 0, 0, 0);
    }
    if (valid) {
#pragma unroll
      for (int i = 0; i < 4; i++) {
        int m = mt * 16 + q * 4 + i;
        out[1 + (long)m * NSC + n] = acc[i];
      }
    }
  }
}

// ---------------------------------------------------------------------------
extern "C" void kernel_launch(void* const* d_in, const int* in_sizes, int n_in,
                              void* d_out, int out_size, void* d_ws, size_t ws_size,
                              hipStream_t stream) {
  (void)in_sizes; (void)n_in; (void)out_size;
  const int* inputs = (const int*)d_in[0];
  const int* adj = (const int*)d_in[1];
  const int* item = (const int*)d_in[2];
  const int* simi_mask = (const int*)d_in[3];
  const int* as0 = (const int*)d_in[4];
  const int* as1 = (const int*)d_in[5];
  const int* ss0 = (const int*)d_in[6];
  const int* ss1 = (const int*)d_in[7];
  // d_in[8]: last_item_mask — structurally [:, -1]; hardcoded in k5ab(fin).
  const int* adj_all = (const int*)d_in[9];
  fpp num = (fpp)d_in[10];
  fpp emb = (fpp)d_in[11];
  fpp pos = (fpp)d_in[12];
  fpp a_local = (fpp)d_in[13];
  fpp mir_w1 = (fpp)d_in[14];
  fpp mir_w2 = (fpp)d_in[15];
  fpp gw1 = (fpp)d_in[16];
  fpp gw2 = (fpp)d_in[17];
  fpp gw3 = (fpp)d_in[18];
  fpp attr_w = (fpp)d_in[19];
  fpp highway_w = (fpp)d_in[20];
  fpp glu1 = (fpp)d_in[21];
  fpp glu2 = (fpp)d_in[22];
  fpp glu4 = (fpp)d_in[23];
  fpp glu4b = (fpp)d_in[24];
  fpp w_s = (fpp)d_in[25];
  fpp gate_w = (fpp)d_in[26];

  // fp32 scratch inside d_out: 6 * 819200 = 4,915,200 elts; srcu table
  // (83,200 ints) at float index 4,915,200 — ends at 4,998,400 < 5,119,873;
  // consumed by kF1/kF2 then overwritten by k9 at the end.
  float* ob = (float*)d_out;
  constexpr long BSD_ = (long)B * S * D;  // 819200
  fpw s_h = ob + 0 * BSD_;
  fpw s_hf1 = ob + 1 * BSD_;  // later x_dot
  fpw s_hf2 = ob + 2 * BSD_;  // later h_global
  fpw s_mir = ob + 3 * BSD_;
  fpw s_xA = ob + 4 * BSD_;
  fpw s_xB = ob + 5 * BSD_;
  int* srcu_t = (int*)(ob + 6 * BSD_);

  // d_ws layout: small fp32 state (loss at ws[0]) .. float 72000; prepped
  // weight frags at byte 288,000; bf16 emb (10.24 MB) at byte 491,520;
  // split-kG agg buffer (21.3 MB bf16) at byte 10,731,520 (guarded).
  float* ws = (float*)d_ws;
  float* w_loss = ws + 0;
  float* w_mi = ws + 16;                // B*S
  float* w_sess = w_mi + (long)B * S;   // B*D
  float* w_hl = w_sess + (long)B * D;   // B*D
  float* w_zh = w_hl + (long)B * D;     // B*D
  u16* p1a = (u16*)(ws + 72000);
  u16* p1b = (u16*)(ws + 72000 + 8192);
  u16* p3a = (u16*)(ws + 72000 + 16384);
  u16* p3b = (u16*)(ws + 72000 + 32768);
  u16* embbf = (u16*)((char*)d_ws + 491520);
  u16* aggws = (u16*)((char*)d_ws + 10731520);
  bool useBF = ws_size >= (size_t)12 * 1024 * 1024;
  bool useSplit = useBF && ws_size >= ((size_t)32 << 20);

  hipMemsetAsync((void*)w_loss, 0, sizeof(float), stream);

  if (useSplit) {
    // Fused prep: prep4 U emb->bf16 U k2_sess U srcu precompute.
    kP<<<5837, 256, 0, stream>>>(gw1, gw3, p1a, p1b, p3a, p3b, emb, embbf,
                                 inputs, item, w_sess, adj_all, srcu_t);
    k1_gather<u16><<<B * S, 128, 0, stream>>>(inputs, as0, as1, ss0, ss1,
                                              embbf, attr_w, s_h, s_hf1, s_hf2,
                                              w_mi, s_xA, s_mir);
    // kF1 interleaved: 1600 groups x (13 GA + 8 {k5ab0,k7}).
    kF1<u16><<<33600, 128, 0, stream>>>(
        srcu_t, adj_all, num, embbf, w_sess, gw1, gw2, p1a, aggws,
        s_xA, adj, a_local, mir_w1, mir_w2, s_xB, s_mir,
        s_hf1, s_hf2, simi_mask, w_loss);
    // kF2 interleaved: even kGB, odd k5ab1.
    kF2<u16><<<2 * B * S, 128, 0, stream>>>(
        srcu_t, num, embbf, w_sess, gw1 + 129 * 128, gw2 + 128,
        gw3 + 256 * 128, p1b, p3a, aggws, s_hf2 /* h_global */,
        s_xB, adj, a_local + 4 * D, mir_w1 + (long)D * D,
        mir_w2 + (long)D * D, s_mir, highway_w, s_h, s_hf1 /* x_dot */, w_hl);
  } else {
    // Fallback: verified mono path.
    kprep4<<<384, 256, 0, stream>>>(gw1, gw3, p1a, p1b, p3a, p3b);
    if (useBF)
      kprep_emb<<<(NODES * D / 4 + 255) / 256, 256, 0, stream>>>(emb, embbf);
    if (useBF)
      k1_gather<u16><<<B * S, 128, 0, stream>>>(inputs, as0, as1, ss0, ss1,
                                                embbf, attr_w, s_h, s_hf1,
                                                s_hf2, w_mi, s_xA, s_mir);
    else
      k1_gather<float><<<B * S, 128, 0, stream>>>(inputs, as0, as1, ss0, ss1,
                                                  emb, attr_w, s_h, s_hf1,
                                                  s_hf2, w_mi, s_xA, s_mir);
    k7_simi<<<B * S, 128, 0, stream>>>(s_hf1, s_hf2, simi_mask, w_loss);
    k2_sess<<<B, 128, 0, stream>>>(inputs, item, emb, w_sess);
    if (useBF)
      kG_mono<u16><<<B * S, 128, 0, stream>>>(inputs, adj_all, num, embbf,
                                              w_sess, gw1, gw2,
                                              gw1 + 129 * 128, gw2 + 128,
                                              gw3 + 256 * 128, p1a, p1b, p3a,
                                              s_hf2 /* h_global */);
    else
      kG_mono<float><<<B * S, 128, 0, stream>>>(inputs, adj_all, num, emb,
                                                w_sess, gw1, gw2,
                                                gw1 + 129 * 128, gw2 + 128,
                                                gw3 + 256 * 128, p1a, p1b,
                                                p3a, s_hf2 /* h_global */);
    k5ab<<<B * S, 128, 0, stream>>>(s_xA, adj, a_local, mir_w1, mir_w2,
                                    s_xB, s_mir, highway_w, s_h, s_hf1, w_hl, 0);
    k5ab<<<B * S, 128, 0, stream>>>(s_xB, adj, a_local + 4 * D,
                                    mir_w1 + (long)D * D, mir_w2 + (long)D * D,
                                    s_xA, s_mir, highway_w, s_h,
                                    s_hf1 /* x_dot */, w_hl, 1);
  }

  k8_glu<<<B, 512, 0, stream>>>(s_hf2 /* h_global */, s_hf1 /* x_dot */, pos,
                                w_hl, w_mi, glu1, glu2, glu4, glu4b, w_s,
                                gate_w, w_zh);
  if (useBF)
    k9_scores<u16><<<(NSC + 63) / 64, 256, 0, stream>>>(w_zh, embbf, w_loss,
                                                        (float*)d_out);
  else
    k9_scores<float><<<(NSC + 63) / 64, 256, 0, stream>>>(w_zh, emb, w_loss,
                                                          (float*)d_out);
}

// Round 9
// 624.245 us; speedup vs baseline: 1.3107x; 1.0053x over previous
//
#include <hip/hip_runtime.h>
#include <hip/hip_bf16.h>
#include <type_traits>

// CombineGraph forward. B=128,S=50,D=128,NODES=40000,SAMPLE=12,NNEI=8,HOP=2.
// Round 21: kill the remaining scattered index loads in GA. kP precomputes
// rid_t[gu*12+j] = adj_all[srcu*12+j] and nw_t[gu*12+j] = num[srcu*12+j]
// (chain recomputed inline per element, 998,400-way parallel). GA's chain
// becomes coalesced-rid -> emb gather (2 levels, first coalesced); kGB's nw
// load becomes coalesced too. Values bit-identical; ws tiers: >=41MiB full
// (rid tables), >=32MiB R20-verified split, else mono.

#define B 128
#define S 50
#define D 128
#define SAMPLE 12
#define NNEI 8
#define NODES 40000
#define NSC (NODES - 1)
#define LEAK 0.2f
#define TEMPV 0.5f
#define MUV 0.1f
#define NEG_BIG -3.0e38f
#define NUNITS (B * S * 13)  // 83200
#define NGA (NUNITS / 4)     // 20800 GA blocks, 128 thr = 2 waves x 2 units

typedef const float* fpp;
typedef float* fpw;
typedef unsigned short u16;
typedef __attribute__((ext_vector_type(8))) short bfrag8;
typedef __attribute__((ext_vector_type(4))) float f32x4;

__device__ __forceinline__ float sigm(float x) { return 1.f / (1.f + __expf(-x)); }
__device__ __forceinline__ float tanh_f(float x) { return 1.f - 2.f / (__expf(2.f * x) + 1.f); }
__device__ __forceinline__ float leaky(float x) { return x >= 0.f ? x : LEAK * x; }
__device__ __forceinline__ u16 f2bf(float v) {
  __hip_bfloat16 h = __float2bfloat16(v);
  return *reinterpret_cast<u16*>(&h);
}
__device__ __forceinline__ float lde(const float* p, long i) { return p[i]; }
__device__ __forceinline__ float lde(const u16* p, long i) {
  union { unsigned int u; float f; } c;
  c.u = ((unsigned int)p[i]) << 16;
  return c.f;
}
__device__ __forceinline__ float bfu(short s) {
  union { unsigned u; float f; } c;
  c.u = ((unsigned)(unsigned short)s) << 16;
  return c.f;
}

template <typename ET>
__device__ __forceinline__ bfrag8 load_frag(const ET* __restrict__ emb, long row, int koff) {
  if constexpr (sizeof(ET) == 2) {
    return *(const bfrag8*)(const void*)(emb + row * D + koff);
  } else {
    const float* s = (const float*)(emb + row * D + koff);
    float4 lo = *(const float4*)s;
    float4 hi = *(const float4*)(s + 4);
    bfrag8 b;
    b[0] = (short)f2bf(lo.x); b[1] = (short)f2bf(lo.y);
    b[2] = (short)f2bf(lo.z); b[3] = (short)f2bf(lo.w);
    b[4] = (short)f2bf(hi.x); b[5] = (short)f2bf(hi.y);
    b[6] = (short)f2bf(hi.z); b[7] = (short)f2bf(hi.w);
    return b;
  }
}

__device__ __forceinline__ bfrag8 scale8(bfrag8 r, float4 sa, float4 sb) {
  bfrag8 o;
  o[0] = (short)f2bf(bfu(r[0]) * sa.x); o[1] = (short)f2bf(bfu(r[1]) * sa.y);
  o[2] = (short)f2bf(bfu(r[2]) * sa.z); o[3] = (short)f2bf(bfu(r[3]) * sa.w);
  o[4] = (short)f2bf(bfu(r[4]) * sb.x); o[5] = (short)f2bf(bfu(r[5]) * sb.y);
  o[6] = (short)f2bf(bfu(r[6]) * sb.z); o[7] = (short)f2bf(bfu(r[7]) * sb.w);
  return o;
}

// --------------------------- LDS overlays ---------------------------------
struct __align__(16) SMk5 { float xi[D]; float ak[4][D]; float alpha[56]; float part[4][2][64]; };
struct __align__(16) SMk7 { float hi[D]; float part[2][64]; };
struct __align__(16) SMga { u16 nvs[2][2][12 * 136]; };  // [wave][unit], rows 0..11
struct __align__(16) SMgb {
  u16 nvs[16 * 136];
  float ev[13 * 128];
  float agg1[128];
  float red[2][16];
  float nw[16];
  int svidx[16];
};
union __align__(16) SMF1 { SMk5 a; SMk7 b; SMga c; };
union __align__(16) SMF2 { SMk5 a; SMgb d; };

// ---------------------------------------------------------------------------
// KPREP_EMB: emb fp32 -> bf16 copy in ws (fallback path).
__global__ __launch_bounds__(256) void kprep_emb(fpp emb, u16* __restrict__ out) {
  long i = ((long)blockIdx.x * 256 + threadIdx.x) * 4;
  if (i + 3 >= (long)NODES * D) return;
  float4 v = *(const float4*)(emb + i);
  out[i + 0] = f2bf(v.x); out[i + 1] = f2bf(v.y);
  out[i + 2] = f2bf(v.z); out[i + 3] = f2bf(v.w);
}

// ---------------------------------------------------------------------------
// prep4 body (device): four weight tensors -> bf16 B-fragment order.
__device__ __forceinline__ void dev_prep4(int i, fpp gw1, fpp gw3,
                                          u16* __restrict__ p1a,
                                          u16* __restrict__ p1b,
                                          u16* __restrict__ p3a,
                                          u16* __restrict__ p3b) {
  fpp W; u16* dst; int KS;
  if (i < 16384)      { W = gw1;             dst = p1a; KS = 4; }
  else if (i < 32768) { W = gw1 + 129 * 128; dst = p1b; KS = 4; i -= 16384; }
  else if (i < 65536) { W = gw3;             dst = p3a; KS = 8; i -= 32768; }
  else                { W = gw3 + 256 * 128; dst = p3b; KS = 8; i -= 65536; }
  int e = i & 7;
  int lane = (i >> 3) & 63;
  int rest = i >> 9;
  int ks = rest % KS, nt = rest / KS;
  int k = ks * 32 + ((lane >> 4) << 3) + e;
  int n = (nt << 4) + (lane & 15);
  dst[i] = f2bf(W[(long)k * 128 + n]);
}

__global__ __launch_bounds__(256) void kprep4(fpp gw1, fpp gw3,
                                              u16* __restrict__ p1a,
                                              u16* __restrict__ p1b,
                                              u16* __restrict__ p3a,
                                              u16* __restrict__ p3b) {
  dev_prep4(blockIdx.x * 256 + threadIdx.x, gw1, gw3, p1a, p1b, p3a, p3b);
}

// ---------------------------------------------------------------------------
// k2 body (device): sess[b,:] = sum_s emb[item[b,s]]*mi / sum_s mi
__device__ __forceinline__ void dev_k2(const int* __restrict__ inputs,
                                       const int* __restrict__ item,
                                       fpp emb, fpw sess, int b, int d) {
  float acc = 0.f, ms = 0.f;
  for (int s = 0; s < S; s++) {
    int inp = inputs[b * S + s];
    float m = (inp != 0) ? 1.f : 0.f;
    int it = item[b * S + s];
    acc += emb[(long)it * D + d] * m;
    ms += m;
  }
  sess[(long)b * D + d] = acc / ms;
}

__global__ __launch_bounds__(128) void k2_sess(const int* __restrict__ inputs,
                                               const int* __restrict__ item,
                                               fpp emb, fpw sess) {
  dev_k2(inputs, item, emb, sess, blockIdx.x, threadIdx.x);
}

// ---------------------------------------------------------------------------
// KP: fused prep — prep4 (384) U emb->bf16 (5000) U k2 (128) U srcu (325)
// U rid/nw tables (3900, only when launched with the extra blocks).
// srcu[gu] = u==0 ? inputs[bs] : adj_all[inputs[bs]*12 + u-1].
// rid_t[gu*12+j] = adj_all[srcu*12+j]; nw_t likewise from num (chain
// recomputed inline — no same-launch dependency on srcu_t).
__global__ __launch_bounds__(256) void kP(fpp gw1, fpp gw3,
                                          u16* __restrict__ p1a, u16* __restrict__ p1b,
                                          u16* __restrict__ p3a, u16* __restrict__ p3b,
                                          fpp emb, u16* __restrict__ embbf,
                                          const int* __restrict__ inputs,
                                          const int* __restrict__ item, fpw sess,
                                          const int* __restrict__ adj_all, fpp num,
                                          int* __restrict__ srcu_t,
                                          int* __restrict__ rid_t,
                                          float* __restrict__ nw_t) {
  int bid = blockIdx.x;
  int t = threadIdx.x;
  if (bid < 384) {
    dev_prep4(bid * 256 + t, gw1, gw3, p1a, p1b, p3a, p3b);
  } else if (bid < 5384) {
    long i = ((long)(bid - 384) * 256 + t) * 4;
    if (i + 3 < (long)NODES * D) {
      float4 v = *(const float4*)(emb + i);
      embbf[i + 0] = f2bf(v.x); embbf[i + 1] = f2bf(v.y);
      embbf[i + 2] = f2bf(v.z); embbf[i + 3] = f2bf(v.w);
    }
  } else if (bid < 5512) {
    if (t < 128) dev_k2(inputs, item, emb, sess, bid - 5384, t);
  } else if (bid < 5837) {
    int gu = (bid - 5512) * 256 + t;
    if (gu < NUNITS) {
      int bs = gu / 13;
      int u = gu - bs * 13;
      int src0 = inputs[bs];
      srcu_t[gu] = (u == 0) ? src0 : adj_all[(long)src0 * SAMPLE + (u - 1)];
    }
  } else {
    int e = (bid - 5837) * 256 + t;
    if (e < NUNITS * SAMPLE) {
      int gu = e / 12;
      int j = e - gu * 12;
      int bs = gu / 13;
      int u = gu - bs * 13;
      int src0 = inputs[bs];
      int srcu = (u == 0) ? src0 : adj_all[(long)src0 * SAMPLE + (u - 1)];
      rid_t[e] = adj_all[(long)srcu * SAMPLE + j];
      nw_t[e] = num[(long)srcu * SAMPLE + j];
    }
  }
}

// ---------------------------------------------------------------------------
// K1: h = emb[inputs]; hf1/hf2 pools; attr gate. Block per (b,s), 128 thr.
template <typename ET>
__global__ __launch_bounds__(128) void k1_gather(
    const int* __restrict__ inputs, const int* __restrict__ as0,
    const int* __restrict__ as1, const int* __restrict__ ss0,
    const int* __restrict__ ss1, const ET* __restrict__ emb, fpp attr_w,
    fpw h, fpw hf1, fpw hf2, float* __restrict__ mi, fpw xA, fpw mir) {
  int bs = blockIdx.x;
  int d = threadIdx.x;
  __shared__ float h_s[D], hf1_s[D];
  int inp = inputs[bs];
  float hv = lde(emb, (long)inp * D + d);
  const int* lists[4] = {as0, as1, ss0, ss1};
  float p[4];
#pragma unroll
  for (int l = 0; l < 4; l++) {
    float sum = 0.f, cnt = 0.f;
    const int* L = lists[l] + (long)bs * NNEI;
#pragma unroll
    for (int n = 0; n < NNEI; n++) {
      int idx = L[n];
      if (idx != 0) { sum += lde(emb, (long)idx * D + d); cnt += 1.f; }
    }
    p[l] = sum / (cnt + 1e-8f);
  }
  float hf1v = 0.5f * (p[0] + p[1]);
  float hf2v = 0.5f * (p[2] + p[3]);
  h_s[d] = hv;
  hf1_s[d] = hf1v;
  __syncthreads();
  float acc = 0.f;
  for (int k = 0; k < D; k++)
    acc += h_s[k] * attr_w[(long)k * D + d] + hf1_s[k] * attr_w[(long)(D + k) * D + d];
  float g = sigm(acc);
  float hfv = g * hv + (1.f - g) * hf1v;
  long o = (long)bs * D + d;
  h[o] = hv; hf1[o] = hf1v; hf2[o] = hf2v; xA[o] = hv; mir[o] = hfv;
  if (d == 0) mi[bs] = (inp != 0) ? 1.f : 0.f;
}

// ---------------------------------------------------------------------------
// dev_kga2: TWO phase-A units per wave. RT=true: rid/nw from precomputed
// coalesced tables (chain = rid_t -> emb). RT=false: R20 verified path.
template <typename ET, bool RT>
__device__ __forceinline__ void dev_kga2(
    u16* __restrict__ nvs0, u16* __restrict__ nvs1,
    const int* __restrict__ srcu_t, const int* __restrict__ adj_all, fpp num,
    const int* __restrict__ rid_t, const float* __restrict__ nw_t,
    const ET* __restrict__ emb, fpp sess, fpp W1a, fpp W2a,
    const u16* __restrict__ p1a, u16* __restrict__ aggws, int gu0, int lane) {
  int q = lane >> 4;
  int mrow = lane & 15;
  int r12 = (mrow < 12) ? mrow : mrow - 12;
  float wl8[8], w28[8];
#pragma unroll
  for (int nt = 0; nt < 8; nt++) {
    int col = nt * 16 + mrow;
    wl8[nt] = W1a[(long)D * D + col];
    w28[nt] = W2a[col];
  }
  bfrag8 sA[2][4];
  float nwq[2][4];
#pragma unroll
  for (int g = 0; g < 2; g++) {
    int gu = gu0 + g;
    int b = gu / 650;  // = (gu/13)/S
    int rid;
    if constexpr (RT) {
      rid = rid_t[gu * SAMPLE + r12];
      if (q < 3) {
        float4 nv4 = *(const float4*)(nw_t + (long)gu * SAMPLE + q * 4);
        nwq[g][0] = nv4.x; nwq[g][1] = nv4.y; nwq[g][2] = nv4.z; nwq[g][3] = nv4.w;
      } else {
        nwq[g][0] = nwq[g][1] = nwq[g][2] = nwq[g][3] = 0.f;
      }
    } else {
      int srcu = srcu_t[gu];
      rid = adj_all[(long)srcu * SAMPLE + r12];
#pragma unroll
      for (int i = 0; i < 4; i++)
        nwq[g][i] = (q < 3) ? num[(long)srcu * SAMPLE + q * 4 + i] : 0.f;
    }
    const float* sessb = sess + (long)b * D;
    u16* nb = g ? nvs1 : nvs0;
    bfrag8 raw[4];
#pragma unroll
    for (int ks = 0; ks < 4; ks++)
      raw[ks] = load_frag(emb, (long)rid, ks * 32 + q * 8);
#pragma unroll
    for (int ks = 0; ks < 4; ks++)
      *(bfrag8*)(nb + r12 * 136 + ks * 32 + q * 8) = raw[ks];
#pragma unroll
    for (int ks = 0; ks < 4; ks++) {
      float4 sa = *(const float4*)(sessb + ks * 32 + q * 8);
      float4 sb = *(const float4*)(sessb + ks * 32 + q * 8 + 4);
      sA[g][ks] = scale8(raw[ks], sa, sb);
    }
  }
  float lp[2][4] = {{0.f, 0.f, 0.f, 0.f}, {0.f, 0.f, 0.f, 0.f}};
#pragma unroll
  for (int nt = 0; nt < 8; nt++) {
    f32x4 acc0 = (f32x4){0.f, 0.f, 0.f, 0.f};
    f32x4 acc1 = (f32x4){0.f, 0.f, 0.f, 0.f};
#pragma unroll
    for (int ks = 0; ks < 4; ks++) {
      bfrag8 bb = *(const bfrag8*)(p1a + ks * 512 + lane * 8 + nt * 2048);
      acc0 = __builtin_amdgcn_mfma_f32_16x16x32_bf16(sA[0][ks], bb, acc0, 0, 0, 0);
      acc1 = __builtin_amdgcn_mfma_f32_16x16x32_bf16(sA[1][ks], bb, acc1, 0, 0, 0);
    }
#pragma unroll
    for (int i = 0; i < 4; i++) {
      lp[0][i] += leaky(acc0[i] + nwq[0][i] * wl8[nt]) * w28[nt];
      lp[1][i] += leaky(acc1[i] + nwq[1][i] * wl8[nt]) * w28[nt];
    }
  }
#pragma unroll
  for (int off = 1; off <= 8; off <<= 1)
#pragma unroll
    for (int g = 0; g < 2; g++)
#pragma unroll
      for (int i = 0; i < 4; i++) lp[g][i] += __shfl_xor(lp[g][i], off, 64);
#pragma unroll
  for (int g = 0; g < 2; g++) {
    float m4 = (q < 3) ? fmaxf(fmaxf(lp[g][0], lp[g][1]), fmaxf(lp[g][2], lp[g][3]))
                       : NEG_BIG;
    m4 = fmaxf(m4, __shfl_xor(m4, 16, 64));
    m4 = fmaxf(m4, __shfl_xor(m4, 32, 64));
    float e0 = 0.f, e1 = 0.f, e2 = 0.f, e3 = 0.f, ssum = 0.f;
    if (q < 3) {
      e0 = __expf(lp[g][0] - m4); e1 = __expf(lp[g][1] - m4);
      e2 = __expf(lp[g][2] - m4); e3 = __expf(lp[g][3] - m4);
      ssum = e0 + e1 + e2 + e3;
    }
    ssum += __shfl_xor(ssum, 16, 64);
    ssum += __shfl_xor(ssum, 32, 64);
    float inv = 1.f / ssum;
    float al[4] = {e0 * inv, e1 * inv, e2 * inv, e3 * inv};
    float aj[12];
#pragma unroll
    for (int j = 0; j < 12; j++) aj[j] = __shfl(al[j & 3], (j >> 2) << 4, 64);
    const u16* nb = g ? nvs1 : nvs0;
    float a0 = 0.f, a1 = 0.f;
#pragma unroll
    for (int j = 0; j < 12; j++) {
      unsigned pv = *(const unsigned*)(nb + j * 136 + lane * 2);
      union { unsigned u; float f; } lo, hi;
      lo.u = pv << 16; hi.u = pv & 0xffff0000u;
      a0 += aj[j] * lo.f; a1 += aj[j] * hi.f;
    }
    unsigned pk = ((unsigned)f2bf(a1) << 16) | (unsigned)f2bf(a0);
    *(unsigned*)(aggws + (long)(gu0 + g) * 128 + lane * 2) = pk;
  }
}

// ---------------------------------------------------------------------------
// dev_kgb: phases B/C + final per bs at 128 thr. svidx from srcu table; nw
// from nw_t (coalesced) when RT.
template <typename ET, bool RT>
__device__ __forceinline__ void dev_kgb(
    SMgb& sm, const int* __restrict__ srcu_t,
    fpp num, const float* __restrict__ nw_t,
    const ET* __restrict__ emb, fpp sess, fpp W1b, fpp W2b, fpp W3b,
    const u16* __restrict__ p1b, const u16* __restrict__ p3a,
    const u16* __restrict__ aggws, fpw hg, int bs) {
  int b = bs / S;
  int d = threadIdx.x;
  int lane = d & 63;
  int w = d >> 6;
  int q = lane >> 4;
  int mrow = lane & 15;

#pragma unroll
  for (int r = 12; r < 16; r++) {
    sm.nvs[r * 136 + d] = 0;
    if (d < 8) sm.nvs[r * 136 + 128 + d] = 0;
  }
  if (d < 16) sm.svidx[d] = (d < 13) ? srcu_t[bs * 13 + d] : 0;
  if (d < SAMPLE) {
    if constexpr (RT)
      sm.nw[d] = nw_t[(long)(bs * 13) * SAMPLE + d];
    else
      sm.nw[d] = num[(long)srcu_t[bs * 13] * SAMPLE + d];
  }
  float sess_d = sess[(long)b * D + d];
  __syncthreads();

  // ---- Phase B: [sv|agg] (13x256) @ W3a -> ev (tanh)
  {
    long svr = sm.svidx[mrow];
    f32x4 accB[4];
#pragma unroll
    for (int nt = 0; nt < 4; nt++) accB[nt] = (f32x4){0.f, 0.f, 0.f, 0.f};
#pragma unroll
    for (int ks = 0; ks < 4; ks++) {
      bfrag8 a = (bfrag8){0, 0, 0, 0, 0, 0, 0, 0};
      if (mrow < 13) a = load_frag(emb, svr, ks * 32 + q * 8);
      const u16* pb = p3a + (w * 32 + ks) * 512 + lane * 8;
#pragma unroll
      for (int nt = 0; nt < 4; nt++)
        accB[nt] = __builtin_amdgcn_mfma_f32_16x16x32_bf16(
            a, *(const bfrag8*)(pb + nt * 4096), accB[nt], 0, 0, 0);
    }
#pragma unroll
    for (int ks = 4; ks < 8; ks++) {
      bfrag8 a = (bfrag8){0, 0, 0, 0, 0, 0, 0, 0};
      if (mrow < 13)
        a = *(const bfrag8*)(aggws + ((long)bs * 13 + mrow) * 128 + (ks - 4) * 32 + q * 8);
      const u16* pb = p3a + (w * 32 + ks) * 512 + lane * 8;
#pragma unroll
      for (int nt = 0; nt < 4; nt++)
        accB[nt] = __builtin_amdgcn_mfma_f32_16x16x32_bf16(
            a, *(const bfrag8*)(pb + nt * 4096), accB[nt], 0, 0, 0);
    }
#pragma unroll
    for (int nt = 0; nt < 4; nt++) {
      int col = (w * 4 + nt) * 16 + mrow;
#pragma unroll
      for (int i = 0; i < 4; i++) {
        int u2 = q * 4 + i;
        if (u2 < 13) sm.ev[u2 * 128 + col] = tanh_f(accB[nt][i]);
      }
    }
  }
  __syncthreads();

  // ---- Phase C: hop-1 unit ----------------------------------------------
  {
    float w2B[4], wlB[4];
#pragma unroll
    for (int nt = 0; nt < 4; nt++) {
      int col = (w * 4 + nt) * 16 + mrow;
      w2B[nt] = W2b[col];
      wlB[nt] = W1b[(long)D * D + col];
    }
    float evreg[SAMPLE];
#pragma unroll
    for (int j = 0; j < SAMPLE; j++) {
      float e = sm.ev[(1 + j) * 128 + d];
      evreg[j] = e;
      sm.nvs[j * 136 + d] = f2bf(e * sess_d);
    }
    __syncthreads();

    f32x4 acc[4];
#pragma unroll
    for (int nt = 0; nt < 4; nt++) acc[nt] = (f32x4){0.f, 0.f, 0.f, 0.f};
#pragma unroll
    for (int ks = 0; ks < 4; ks++) {
      bfrag8 a = *(const bfrag8*)(sm.nvs + mrow * 136 + q * 8 + ks * 32);
      const u16* pb = p1b + (w * 16 + ks) * 512 + lane * 8;
#pragma unroll
      for (int nt = 0; nt < 4; nt++) {
        bfrag8 bb = *(const bfrag8*)(pb + nt * 2048);
        acc[nt] = __builtin_amdgcn_mfma_f32_16x16x32_bf16(a, bb, acc[nt], 0, 0, 0);
      }
    }
    float lp[4] = {0.f, 0.f, 0.f, 0.f};
    float nwq[4];
#pragma unroll
    for (int i = 0; i < 4; i++) nwq[i] = (q < 3) ? sm.nw[q * 4 + i] : 0.f;
#pragma unroll
    for (int nt = 0; nt < 4; nt++)
#pragma unroll
      for (int i = 0; i < 4; i++)
        lp[i] += leaky(acc[nt][i] + nwq[i] * wlB[nt]) * w2B[nt];
#pragma unroll
    for (int off = 1; off <= 8; off <<= 1)
#pragma unroll
      for (int i = 0; i < 4; i++) lp[i] += __shfl_xor(lp[i], off, 64);
    if (mrow == 0 && q < 3) {
#pragma unroll
      for (int i = 0; i < 4; i++) sm.red[w][q * 4 + i] = lp[i];
    }
    __syncthreads();

    float lg[SAMPLE];
#pragma unroll
    for (int j = 0; j < SAMPLE; j++) lg[j] = sm.red[0][j] + sm.red[1][j];
    float mx = lg[0];
#pragma unroll
    for (int j = 1; j < SAMPLE; j++) mx = fmaxf(mx, lg[j]);
    float se = 0.f;
#pragma unroll
    for (int j = 0; j < SAMPLE; j++) { lg[j] = __expf(lg[j] - mx); se += lg[j]; }
    float inv = 1.f / se;
    float agg1d = 0.f;
#pragma unroll
    for (int j = 0; j < SAMPLE; j++) agg1d += lg[j] * inv * evreg[j];
    sm.agg1[d] = agg1d;
    __syncthreads();

    float accf = 0.f;
#pragma unroll 4
    for (int k4 = 0; k4 < 32; k4++) {
      float4 a4 = *(const float4*)&sm.ev[4 * k4];
      float4 g4 = *(const float4*)&sm.agg1[4 * k4];
      accf += a4.x * W3b[(4 * k4 + 0) * D + d] + a4.y * W3b[(4 * k4 + 1) * D + d] +
              a4.z * W3b[(4 * k4 + 2) * D + d] + a4.w * W3b[(4 * k4 + 3) * D + d] +
              g4.x * W3b[(D + 4 * k4 + 0) * D + d] + g4.y * W3b[(D + 4 * k4 + 1) * D + d] +
              g4.z * W3b[(D + 4 * k4 + 2) * D + d] + g4.w * W3b[(D + 4 * k4 + 3) * D + d];
    }
    hg[(long)bs * D + d] = tanh_f(accf);
  }
}

// ---------------------------------------------------------------------------
// dev_k5ab: fused local-attention + mirror gate (+highway on fin=1).
__device__ __forceinline__ void dev_k5ab(SMk5& sm, fpp x, const int* __restrict__ adj,
                                         fpp a_loc, fpp w1, fpp w2, fpw xout,
                                         fpw mir, fpp hw, fpp h, fpw x_dot,
                                         float* __restrict__ h_local, int bs, int fin) {
  int b = bs / S;
  int row = bs % S;
  int tid = threadIdx.x;
  long idx = ((long)b * S + row) * D + tid;
  sm.xi[tid] = x[idx];
#pragma unroll
  for (int k = 0; k < 4; k++) sm.ak[k][tid] = a_loc[(long)k * D + tid];
  __syncthreads();
  {
    int j = tid & 63, hf = tid >> 6;
    float a0 = 0.f, a1 = 0.f, a2 = 0.f, a3 = 0.f;
    if (j < S) {
      const float* xj = x + ((long)b * S + j) * D + hf * 64;
      int off = hf * 64;
      for (int dd = 0; dd < 64; dd++) {
        float prod = sm.xi[off + dd] * xj[dd];
        a0 += prod * sm.ak[0][off + dd];
        a1 += prod * sm.ak[1][off + dd];
        a2 += prod * sm.ak[2][off + dd];
        a3 += prod * sm.ak[3][off + dd];
      }
    }
    sm.part[0][hf][j] = a0; sm.part[1][hf][j] = a1;
    sm.part[2][hf][j] = a2; sm.part[3][hf][j] = a3;
  }
  __syncthreads();
  if (tid < 64) {
    int j = tid;
    float att;
    if (j < S) {
      float acc0 = sm.part[0][0][j] + sm.part[0][1][j];
      float acc1 = sm.part[1][0][j] + sm.part[1][1][j];
      float acc2 = sm.part[2][0][j] + sm.part[2][1][j];
      float acc3 = sm.part[3][0][j] + sm.part[3][1][j];
      int av = adj[((long)b * S + row) * S + j];
      att = -9e15f;  // reference's own sentinel
      if (av == 1) att = leaky(acc0);
      else if (av == 2) att = leaky(acc1);
      else if (av == 3) att = leaky(acc2);
      else if (av == 4) att = leaky(acc3);
    } else {
      att = NEG_BIG;
    }
    float mx = att;
#pragma unroll
    for (int o = 32; o > 0; o >>= 1) mx = fmaxf(mx, __shfl_xor(mx, o, 64));
    float e = __expf(att - mx);
    float ssum = e;
#pragma unroll
    for (int o = 32; o > 0; o >>= 1) ssum += __shfl_xor(ssum, o, 64);
    if (j < S) sm.alpha[j] = e / ssum;
  }
  __syncthreads();
  float xn = 0.f;
  for (int j = 0; j < S; j++) xn += sm.alpha[j] * x[((long)b * S + j) * D + tid];
  float mv = mir[idx];
  sm.ak[0][tid] = xn;
  sm.ak[1][tid] = mv;
  __syncthreads();
  float a2m = 0.f;
  for (int k = 0; k < D; k++)
    a2m += sm.ak[0][k] * w1[(long)k * D + tid] + sm.ak[1][k] * w2[(long)k * D + tid];
  float g = sigm(a2m);
  float xg = g * xn + (1.f - g) * mv;
  if (!fin) {
    xout[idx] = xg;
    mir[idx] = g * mv + (1.f - g) * xn;
    return;
  }
  float hv = h[idx];
  sm.ak[2][tid] = hv;
  sm.ak[3][tid] = xg;
  __syncthreads();
  float a3m = 0.f;
  for (int k = 0; k < D; k++)
    a3m += sm.ak[2][k] * hw[(long)k * D + tid] + sm.ak[3][k] * hw[(long)(D + k) * D + tid];
  float gh = sigm(a3m);
  float xd = gh * hv + (1.f - gh) * xg;
  x_dot[idx] = xd;
  if (row == S - 1) h_local[(long)b * D + tid] = xd;
}

// ---------------------------------------------------------------------------
// dev_k7: simi loss per (b,i). atomicAdd to ws.
__device__ __forceinline__ void dev_k7(SMk7& sm, fpp hf1, fpp hf2,
                                       const int* __restrict__ simi_mask,
                                       float* __restrict__ loss, int bs) {
  int b = bs / S;
  int i = bs % S;
  int t = threadIdx.x;
  sm.hi[t] = hf1[((long)b * S + i) * D + t];
  __syncthreads();
  {
    int j = t & 63, hf = t >> 6;
    float acc = 0.f;
    if (j < S) {
      const float* r = hf2 + ((long)b * S + j) * D + hf * 64;
      int off = hf * 64;
      for (int dd = 0; dd < 64; dd++) acc += sm.hi[off + dd] * r[dd];
    }
    sm.part[hf][j] = acc;
  }
  __syncthreads();
  if (t < 64) {
    int j = t;
    float sim = (j < S) ? (sm.part[0][j] + sm.part[1][j]) * (1.0f / TEMPV) : NEG_BIG;
    float mx = sim;
#pragma unroll
    for (int o = 32; o > 0; o >>= 1) mx = fmaxf(mx, __shfl_xor(mx, o, 64));
    float e = __expf(sim - mx);
    float ssum = e;
#pragma unroll
    for (int o = 32; o > 0; o >>= 1) ssum += __shfl_xor(ssum, o, 64);
    float contrib = 0.f;
    if (j < S) {
      float p = e / ssum;
      float l = -__logf(p + 1e-8f);
      if (simi_mask[((long)b * S + i) * S + j] == 1) contrib = l;
    }
#pragma unroll
    for (int o = 32; o > 0; o >>= 1) contrib += __shfl_xor(contrib, o, 64);
    if (j == 0) atomicAdd(loss, contrib);
  }
}

// ---------------------------------------------------------------------------
// Fused launch 1 (INTERLEAVED): per 21-block group, 13 GA + 8 {k5ab0,k7}.
template <typename ET, bool RT>
__global__ __launch_bounds__(128) void kF1(
    const int* __restrict__ srcu_t, const int* __restrict__ adj_all, fpp num,
    const int* __restrict__ rid_t, const float* __restrict__ nw_t,
    const ET* __restrict__ emb, fpp sess, fpp W1a, fpp W2a,
    const u16* __restrict__ p1a, u16* __restrict__ aggws,
    fpp xA, const int* __restrict__ adj, fpp a_loc, fpp mw1, fpp mw2,
    fpw xB, fpw mir,
    fpp hf1, fpp hf2, const int* __restrict__ simi_mask,
    float* __restrict__ loss) {
  __shared__ SMF1 sm;
  int bid = blockIdx.x;
  int grp = bid / 21;
  int r = bid - grp * 21;
  if (r < 13) {
    int ga = grp * 13 + r;
    int t = threadIdx.x;
    int w = t >> 6, lane = t & 63;
    dev_kga2<ET, RT>(sm.c.nvs[w][0], sm.c.nvs[w][1], srcu_t, adj_all, num,
                     rid_t, nw_t, emb, sess, W1a, W2a, p1a, aggws,
                     ga * 4 + w * 2, lane);
  } else {
    int o = grp * 8 + (r - 13);
    if (o & 1)
      dev_k7(sm.b, hf1, hf2, simi_mask, loss, o >> 1);
    else
      dev_k5ab(sm.a, xA, adj, a_loc, mw1, mw2, xB, mir, nullptr, nullptr,
               nullptr, nullptr, o >> 1, 0);
  }
}

// ---------------------------------------------------------------------------
// Fused launch 2 (INTERLEAVED): even -> kGB, odd -> k5ab pass1 (fin).
template <typename ET, bool RT>
__global__ __launch_bounds__(128) void kF2(
    const int* __restrict__ srcu_t, fpp num, const float* __restrict__ nw_t,
    const ET* __restrict__ emb, fpp sess, fpp W1b, fpp W2b, fpp W3b,
    const u16* __restrict__ p1b, const u16* __restrict__ p3a,
    const u16* __restrict__ aggws, fpw hg,
    fpp xB, const int* __restrict__ adj, fpp a_loc2, fpp mw1b, fpp mw2b,
    fpw mir, fpp hw, fpp h, fpw x_dot, float* __restrict__ h_local) {
  __shared__ SMF2 sm;
  int bid = blockIdx.x;
  if (bid & 1)
    dev_k5ab(sm.a, xB, adj, a_loc2, mw1b, mw2b, nullptr, mir, hw, h, x_dot,
             h_local, bid >> 1, 1);
  else
    dev_kgb<ET, RT>(sm.d, srcu_t, num, nw_t, emb, sess, W1b, W2b, W3b, p1b,
                    p3a, aggws, hg, bid >> 1);
}

// ---------------------------------------------------------------------------
// Standalone wrappers (fallback path).
__global__ __launch_bounds__(128) void k5ab(fpp x, const int* __restrict__ adj,
                                            fpp a_loc, fpp w1, fpp w2,
                                            fpw xout, fpw mir,
                                            fpp hw, fpp h, fpw x_dot,
                                            float* __restrict__ h_local,
                                            int fin) {
  __shared__ SMk5 sm;
  dev_k5ab(sm, x, adj, a_loc, w1, w2, xout, mir, hw, h, x_dot, h_local,
           blockIdx.x, fin);
}

__global__ __launch_bounds__(128) void k7_simi(fpp hf1, fpp hf2,
                                               const int* __restrict__ simi_mask,
                                               float* __restrict__ loss) {
  __shared__ SMk7 sm;
  dev_k7(sm, hf1, hf2, simi_mask, loss, blockIdx.x);
}

// ---------------------------------------------------------------------------
// KG_MONO: verified monolithic kG (fallback when ws too small for split).
template <typename ET>
__global__ __launch_bounds__(128) void kG_mono(
    const int* __restrict__ inputs, const int* __restrict__ adj_all,
    fpp num, const ET* __restrict__ emb, fpp sess,
    fpp W1a, fpp W2a, fpp W1b, fpp W2b, fpp W3b,
    const u16* __restrict__ p1a, const u16* __restrict__ p1b,
    const u16* __restrict__ p3a, fpw hg) {
  int bs = blockIdx.x;
  int b = bs / S;
  int d = threadIdx.x;
  int lane = d & 63;
  int w = d >> 6;
  int q = lane >> 4;
  int mrow = lane & 15;

  __shared__ __align__(16) u16 nvs_l[16 * 136];
  __shared__ __align__(16) u16 svagg_l[16 * 264];
  __shared__ __align__(16) float ev_l[13 * 128];
  __shared__ __align__(16) float agg1_l[128];
  __shared__ float red_l[2][16];
  __shared__ float nw_l[16];

#pragma unroll
  for (int r = 12; r < 16; r++) {
    nvs_l[r * 136 + d] = 0;
    if (d < 8) nvs_l[r * 136 + 128 + d] = 0;
  }
#pragma unroll
  for (int r = 13; r < 16; r++) {
    svagg_l[r * 264 + d] = 0;
    svagg_l[r * 264 + 128 + d] = 0;
    if (d < 8) svagg_l[r * 264 + 256 + d] = 0;
  }

  float sess_d = sess[(long)b * D + d];
  int src0 = __builtin_amdgcn_readfirstlane(inputs[bs]);
  int n1[SAMPLE];
#pragma unroll
  for (int j = 0; j < SAMPLE; j++)
    n1[j] = __builtin_amdgcn_readfirstlane(adj_all[(long)src0 * SAMPLE + j]);
  svagg_l[0 * 264 + d] = f2bf(lde(emb, (long)src0 * D + d));

  float w2A[4], wlA[4], w2B[4], wlB[4];
#pragma unroll
  for (int nt = 0; nt < 4; nt++) {
    int col = (w * 4 + nt) * 16 + mrow;
    w2A[nt] = W2a[col];
    wlA[nt] = W1a[(long)D * D + col];
    w2B[nt] = W2b[col];
    wlB[nt] = W1b[(long)D * D + col];
  }

  float pre[SAMPLE], pnw = 0.f;
  {
#pragma unroll
    for (int j = 0; j < SAMPLE; j++)
      pre[j] = lde(emb, (long)n1[j] * D + d);
    if (d < SAMPLE) pnw = num[(long)src0 * SAMPLE + d];
  }
  for (int u = 0; u < 13; u++) {
    if (d < SAMPLE) nw_l[d] = pnw;
    float nvreg[SAMPLE];
#pragma unroll
    for (int j = 0; j < SAMPLE; j++) {
      nvreg[j] = pre[j];
      nvs_l[j * 136 + d] = f2bf(pre[j] * sess_d);
    }
    if (u == 0) {
#pragma unroll
      for (int j = 0; j < SAMPLE; j++)
        svagg_l[(1 + j) * 264 + d] = f2bf(nvreg[j]);
    }
    __syncthreads();
    if (u < 12) {
      int srcn = n1[u];
#pragma unroll
      for (int j = 0; j < SAMPLE; j++) {
        int nj = __builtin_amdgcn_readfirstlane(adj_all[(long)srcn * SAMPLE + j]);
        pre[j] = lde(emb, (long)nj * D + d);
      }
      if (d < SAMPLE) pnw = num[(long)srcn * SAMPLE + d];
    }
    f32x4 acc[4];
#pragma unroll
    for (int nt = 0; nt < 4; nt++) acc[nt] = (f32x4){0.f, 0.f, 0.f, 0.f};
#pragma unroll
    for (int ks = 0; ks < 4; ks++) {
      bfrag8 a = *(const bfrag8*)(nvs_l + mrow * 136 + q * 8 + ks * 32);
      const u16* pb = p1a + (w * 16 + ks) * 512 + lane * 8;
#pragma unroll
      for (int nt = 0; nt < 4; nt++) {
        bfrag8 bb = *(const bfrag8*)(pb + nt * 2048);
        acc[nt] = __builtin_amdgcn_mfma_f32_16x16x32_bf16(a, bb, acc[nt], 0, 0, 0);
      }
    }
    float lp[4] = {0.f, 0.f, 0.f, 0.f};
    float nwq[4];
#pragma unroll
    for (int i = 0; i < 4; i++) nwq[i] = (q < 3) ? nw_l[q * 4 + i] : 0.f;
#pragma unroll
    for (int nt = 0; nt < 4; nt++)
#pragma unroll
      for (int i = 0; i < 4; i++)
        lp[i] += leaky(acc[nt][i] + nwq[i] * wlA[nt]) * w2A[nt];
#pragma unroll
    for (int off = 1; off <= 8; off <<= 1)
#pragma unroll
      for (int i = 0; i < 4; i++) lp[i] += __shfl_xor(lp[i], off, 64);
    if (mrow == 0 && q < 3) {
#pragma unroll
      for (int i = 0; i < 4; i++) red_l[w][q * 4 + i] = lp[i];
    }
    __syncthreads();
    float lg[SAMPLE];
#pragma unroll
    for (int j = 0; j < SAMPLE; j++) lg[j] = red_l[0][j] + red_l[1][j];
    float mx = lg[0];
#pragma unroll
    for (int j = 1; j < SAMPLE; j++) mx = fmaxf(mx, lg[j]);
    float se = 0.f;
#pragma unroll
    for (int j = 0; j < SAMPLE; j++) { lg[j] = __expf(lg[j] - mx); se += lg[j]; }
    float inv = 1.f / se;
    float aggd = 0.f;
#pragma unroll
    for (int j = 0; j < SAMPLE; j++) aggd += lg[j] * inv * nvreg[j];
    svagg_l[u * 264 + 128 + d] = f2bf(aggd);
  }
  __syncthreads();

  {
    f32x4 accB[4];
#pragma unroll
    for (int nt = 0; nt < 4; nt++) accB[nt] = (f32x4){0.f, 0.f, 0.f, 0.f};
#pragma unroll
    for (int ks = 0; ks < 8; ks++) {
      bfrag8 a = *(const bfrag8*)(svagg_l + mrow * 264 + q * 8 + ks * 32);
      const u16* pb = p3a + (w * 32 + ks) * 512 + lane * 8;
#pragma unroll
      for (int nt = 0; nt < 4; nt++) {
        bfrag8 bb = *(const bfrag8*)(pb + nt * 4096);
        accB[nt] = __builtin_amdgcn_mfma_f32_16x16x32_bf16(a, bb, accB[nt], 0, 0, 0);
      }
    }
#pragma unroll
    for (int nt = 0; nt < 4; nt++) {
      int col = (w * 4 + nt) * 16 + mrow;
#pragma unroll
      for (int i = 0; i < 4; i++) {
        int u2 = q * 4 + i;
        if (u2 < 13) ev_l[u2 * 128 + col] = tanh_f(accB[nt][i]);
      }
    }
    __syncthreads();
  }

  {
    float evreg[SAMPLE];
#pragma unroll
    for (int j = 0; j < SAMPLE; j++) {
      float e = ev_l[(1 + j) * 128 + d];
      evreg[j] = e;
      nvs_l[j * 136 + d] = f2bf(e * sess_d);
    }
    if (d < SAMPLE) nw_l[d] = num[(long)src0 * SAMPLE + d];
    __syncthreads();

    f32x4 acc[4];
#pragma unroll
    for (int nt = 0; nt < 4; nt++) acc[nt] = (f32x4){0.f, 0.f, 0.f, 0.f};
#pragma unroll
    for (int ks = 0; ks < 4; ks++) {
      bfrag8 a = *(const bfrag8*)(nvs_l + mrow * 136 + q * 8 + ks * 32);
      const u16* pb = p1b + (w * 16 + ks) * 512 + lane * 8;
#pragma unroll
      for (int nt = 0; nt < 4; nt++) {
        bfrag8 bb = *(const bfrag8*)(pb + nt * 2048);
        acc[nt] = __builtin_amdgcn_mfma_f32_16x16x32_bf16(a, bb, acc[nt], 0, 0, 0);
      }
    }
    float lp[4] = {0.f, 0.f, 0.f, 0.f};
    float nwq[4];
#pragma unroll
    for (int i = 0; i < 4; i++) nwq[i] = (q < 3) ? nw_l[q * 4 + i] : 0.f;
#pragma unroll
    for (int nt = 0; nt < 4; nt++)
#pragma unroll
      for (int i = 0; i < 4; i++)
        lp[i] += leaky(acc[nt][i] + nwq[i] * wlB[nt]) * w2B[nt];
#pragma unroll
    for (int off = 1; off <= 8; off <<= 1)
#pragma unroll
      for (int i = 0; i < 4; i++) lp[i] += __shfl_xor(lp[i], off, 64);
    if (mrow == 0 && q < 3) {
#pragma unroll
      for (int i = 0; i < 4; i++) red_l[w][q * 4 + i] = lp[i];
    }
    __syncthreads();

    float lg[SAMPLE];
#pragma unroll
    for (int j = 0; j < SAMPLE; j++) lg[j] = red_l[0][j] + red_l[1][j];
    float mx = lg[0];
#pragma unroll
    for (int j = 1; j < SAMPLE; j++) mx = fmaxf(mx, lg[j]);
    float se = 0.f;
#pragma unroll
    for (int j = 0; j < SAMPLE; j++) { lg[j] = __expf(lg[j] - mx); se += lg[j]; }
    float inv = 1.f / se;
    float agg1d = 0.f;
#pragma unroll
    for (int j = 0; j < SAMPLE; j++) agg1d += lg[j] * inv * evreg[j];
    agg1_l[d] = agg1d;
    __syncthreads();

    float accf = 0.f;
#pragma unroll 4
    for (int k4 = 0; k4 < 32; k4++) {
      float4 a4 = *(const float4*)&ev_l[4 * k4];
      float4 g4 = *(const float4*)&agg1_l[4 * k4];
      accf += a4.x * W3b[(4 * k4 + 0) * D + d] + a4.y * W3b[(4 * k4 + 1) * D + d] +
              a4.z * W3b[(4 * k4 + 2) * D + d] + a4.w * W3b[(4 * k4 + 3) * D + d] +
              g4.x * W3b[(D + 4 * k4 + 0) * D + d] + g4.y * W3b[(D + 4 * k4 + 1) * D + d] +
              g4.z * W3b[(D + 4 * k4 + 2) * D + d] + g4.w * W3b[(D + 4 * k4 + 3) * D + d];
    }
    hg[(long)bs * D + d] = tanh_f(accf);
  }
}

// ---------------------------------------------------------------------------
// K8: GLU epilogue per batch, 512 threads = 4 s-groups (serial 50 -> 13).
__global__ __launch_bounds__(512) void k8_glu(
    fpp hg, fpp x_dot, fpp pos, fpp h_local, const float* __restrict__ mi,
    fpp glu1, fpp glu2, fpp glu4, fpp glu4b, fpp w_s, fpp gate_w, fpw zh) {
  int b = blockIdx.x;
  int t = threadIdx.x;
  int d = t & 127;
  int g = t >> 7;   // s-group 0..3
  __shared__ float hs_s[D], hl_s[D];
  __shared__ float hp_g[4][D], part[4][D], zg_g[4][D];
  __shared__ float red2[4][2];
  float msf = 0.f;
  for (int s = 0; s < S; s++) msf += mi[b * S + s];
  float hsacc = 0.f;
  for (int s = g * 13; s < min(S, g * 13 + 13); s++)
    hsacc += hg[((long)b * S + s) * D + d] * mi[b * S + s];
  part[g][d] = hsacc;
  if (g == 1) hl_s[d] = h_local[(long)b * D + d];
  __syncthreads();
  if (g == 0) hs_s[d] = (part[0][d] + part[1][d] + part[2][d] + part[3][d]) / msf;
  __syncthreads();
  float c = glu4b[d];
  for (int k = 0; k < D; k++)
    c += hs_s[k] * glu2[(long)k * D + d] + hl_s[k] * glu4[(long)k * D + d];
  float wsd = w_s[d];
  float zg = 0.f;
  for (int it = 0; it < 13; it++) {
    int s = g * 13 + it;
    bool act = s < S;
    float hp = 0.f;
    if (act) {
      hp = x_dot[((long)b * S + s) * D + d] + pos[(long)s * D + d];
      hp_g[g][d] = hp;
    }
    __syncthreads();
    if (act) {
      float acc = c;
      for (int k = 0; k < D; k++) acc += hp_g[g][k] * glu1[(long)k * D + d];
      float v = sigm(acc) * wsd;
#pragma unroll
      for (int o = 32; o > 0; o >>= 1) v += __shfl_down(v, o, 64);
      if ((t & 63) == 0) red2[g][(t >> 6) & 1] = v;
    }
    __syncthreads();
    if (act) {
      float beta = (red2[g][0] + red2[g][1]) * mi[b * S + s];
      zg += beta * hp;
    }
    __syncthreads();
  }
  zg_g[g][d] = zg;
  __syncthreads();
  if (g == 0) {
    float zgf = zg_g[0][d] + zg_g[1][d] + zg_g[2][d] + zg_g[3][d];
    hp_g[0][d] = zgf;
  }
  __syncthreads();
  if (g == 0) {
    float zgf = hp_g[0][d];
    float acc = 0.f;
    for (int k = 0; k < D; k++)
      acc += hp_g[0][k] * gate_w[(long)k * D + d] +
             hl_s[k] * gate_w[(long)(D + k) * D + d];
    float gf = sigm(acc) * MUV;
    zh[(long)b * D + d] = gf * hl_s[d] + (1.f - gf) * zgf;
  }
}

// ---------------------------------------------------------------------------
// K9: scores = zh(128x128) @ emb[1:]^T via bf16 MFMA.
template <typename ET>
__global__ __launch_bounds__(256) void k9_scores(fpp zh, const ET* __restrict__ emb,
                                                 fpp loss, float* __restrict__ out) {
  int t = threadIdx.x;
  if (blockIdx.x == 0 && t == 0) out[0] = loss[0] * (1.0f / (float)B);
  int lane = t & 63;
  int w = t >> 6;
  int q = lane >> 4;
  int mrow = lane & 15;
  long n = (long)blockIdx.x * 64 + w * 16 + mrow;
  bool valid = n < NSC;
  long nrow = valid ? (n + 1) : 1;
  bfrag8 bfr[4];
#pragma unroll
  for (int ks = 0; ks < 4; ks++) {
    if constexpr (sizeof(ET) == 2) {
      bfr[ks] = *(const bfrag8*)(const void*)(emb + nrow * D + ks * 32 + q * 8);
    } else {
      const float* src = (const float*)(emb + nrow * D + ks * 32 + q * 8);
      float4 lo = *(const float4*)src;
      float4 hi = *(const float4*)(src + 4);
      bfrag8 bb;
      bb[0] = (short)f2bf(lo.x); bb[1] = (short)f2bf(lo.y);
      bb[2] = (short)f2bf(lo.z); bb[3] = (short)f2bf(lo.w);
      bb[4] = (short)f2bf(hi.x); bb[5] = (short)f2bf(hi.y);
      bb[6] = (short)f2bf(hi.z); bb[7] = (short)f2bf(hi.w);
      bfr[ks] = bb;
    }
  }
#pragma unroll
  for (int mt = 0; mt < 8; mt++) {
    f32x4 acc = (f32x4){0.f, 0.f, 0.f, 0.f};
#pragma unroll
    for (int ks = 0; ks < 4; ks++) {
      const float* za = zh + (long)(mt * 16 + mrow) * D + ks * 32 + q * 8;
      float4 lo = *(const float4*)za;
      float4 hi = *(const float4*)(za + 4);
      bfrag8 a;
      a[0] = (short)f2bf(lo.x); a[1] = (short)f2bf(lo.y);
      a[2] = (short)f2bf(lo.z); a[3] = (short)f2bf(lo.w);
      a[4] = (short)f2bf(hi.x); a[5] = (short)f2bf(hi.y);
      a[6] = (short)f2bf(hi.z); a[7] = (short)f2bf(hi.w);
      acc = __builtin_amdgcn_mfma_f32_16x16x32_bf16(a, bfr[ks], acc, 0, 0, 0);
    }
    if (valid) {
#pragma unroll
      for (int i = 0; i < 4; i++) {
        int m = mt * 16 + q * 4 + i;
        out[1 + (long)m * NSC + n] = acc[i];
      }
    }
  }
}

// ---------------------------------------------------------------------------
extern "C" void kernel_launch(void* const* d_in, const int* in_sizes, int n_in,
                              void* d_out, int out_size, void* d_ws, size_t ws_size,
                              hipStream_t stream) {
  (void)in_sizes; (void)n_in; (void)out_size;
  const int* inputs = (const int*)d_in[0];
  const int* adj = (const int*)d_in[1];
  const int* item = (const int*)d_in[2];
  const int* simi_mask = (const int*)d_in[3];
  const int* as0 = (const int*)d_in[4];
  const int* as1 = (const int*)d_in[5];
  const int* ss0 = (const int*)d_in[6];
  const int* ss1 = (const int*)d_in[7];
  // d_in[8]: last_item_mask — structurally [:, -1]; hardcoded in k5ab(fin).
  const int* adj_all = (const int*)d_in[9];
  fpp num = (fpp)d_in[10];
  fpp emb = (fpp)d_in[11];
  fpp pos = (fpp)d_in[12];
  fpp a_local = (fpp)d_in[13];
  fpp mir_w1 = (fpp)d_in[14];
  fpp mir_w2 = (fpp)d_in[15];
  fpp gw1 = (fpp)d_in[16];
  fpp gw2 = (fpp)d_in[17];
  fpp gw3 = (fpp)d_in[18];
  fpp attr_w = (fpp)d_in[19];
  fpp highway_w = (fpp)d_in[20];
  fpp glu1 = (fpp)d_in[21];
  fpp glu2 = (fpp)d_in[22];
  fpp glu4 = (fpp)d_in[23];
  fpp glu4b = (fpp)d_in[24];
  fpp w_s = (fpp)d_in[25];
  fpp gate_w = (fpp)d_in[26];

  // fp32 scratch inside d_out: 6 * 819200 = 4,915,200 elts; srcu table
  // (83,200 ints) at float index 4,915,200 — ends at 4,998,400 < 5,119,873;
  // consumed by kF1/kF2 then overwritten by k9 at the end.
  float* ob = (float*)d_out;
  constexpr long BSD_ = (long)B * S * D;  // 819200
  fpw s_h = ob + 0 * BSD_;
  fpw s_hf1 = ob + 1 * BSD_;  // later x_dot
  fpw s_hf2 = ob + 2 * BSD_;  // later h_global
  fpw s_mir = ob + 3 * BSD_;
  fpw s_xA = ob + 4 * BSD_;
  fpw s_xB = ob + 5 * BSD_;
  int* srcu_t = (int*)(ob + 6 * BSD_);

  // d_ws layout: small fp32 state (loss at ws[0]) .. float 72000; prepped
  // weight frags at byte 288,000; bf16 emb (10.24 MB) at byte 491,520;
  // aggws (21.3 MB bf16) at byte 10,731,520; rid_t (4 MB int) at byte
  // 32,030,720; nw_t (4 MB float) at byte 36,024,320 (ends 40,017,920).
  float* ws = (float*)d_ws;
  float* w_loss = ws + 0;
  float* w_mi = ws + 16;                // B*S
  float* w_sess = w_mi + (long)B * S;   // B*D
  float* w_hl = w_sess + (long)B * D;   // B*D
  float* w_zh = w_hl + (long)B * D;     // B*D
  u16* p1a = (u16*)(ws + 72000);
  u16* p1b = (u16*)(ws + 72000 + 8192);
  u16* p3a = (u16*)(ws + 72000 + 16384);
  u16* p3b = (u16*)(ws + 72000 + 32768);
  u16* embbf = (u16*)((char*)d_ws + 491520);
  u16* aggws = (u16*)((char*)d_ws + 10731520);
  int* rid_t = (int*)((char*)d_ws + 32030720);
  float* nw_t = (float*)((char*)d_ws + 36024320);
  bool useBF = ws_size >= (size_t)12 * 1024 * 1024;
  bool useSplit = useBF && ws_size >= ((size_t)32 << 20);
  bool useRT = useSplit && ws_size >= (size_t)40100000;

  hipMemsetAsync((void*)w_loss, 0, sizeof(float), stream);

  if (useSplit) {
    // Fused prep: prep4 U emb->bf16 U k2_sess U srcu U (rid/nw tables).
    int kpGrid = useRT ? 9737 : 5837;
    kP<<<kpGrid, 256, 0, stream>>>(gw1, gw3, p1a, p1b, p3a, p3b, emb, embbf,
                                   inputs, item, w_sess, adj_all, num,
                                   srcu_t, rid_t, nw_t);
    k1_gather<u16><<<B * S, 128, 0, stream>>>(inputs, as0, as1, ss0, ss1,
                                              embbf, attr_w, s_h, s_hf1, s_hf2,
                                              w_mi, s_xA, s_mir);
    if (useRT) {
      kF1<u16, true><<<33600, 128, 0, stream>>>(
          srcu_t, adj_all, num, rid_t, nw_t, embbf, w_sess, gw1, gw2, p1a,
          aggws, s_xA, adj, a_local, mir_w1, mir_w2, s_xB, s_mir,
          s_hf1, s_hf2, simi_mask, w_loss);
      kF2<u16, true><<<2 * B * S, 128, 0, stream>>>(
          srcu_t, num, nw_t, embbf, w_sess, gw1 + 129 * 128, gw2 + 128,
          gw3 + 256 * 128, p1b, p3a, aggws, s_hf2 /* h_global */,
          s_xB, adj, a_local + 4 * D, mir_w1 + (long)D * D,
          mir_w2 + (long)D * D, s_mir, highway_w, s_h, s_hf1 /* x_dot */,
          w_hl);
    } else {
      kF1<u16, false><<<33600, 128, 0, stream>>>(
          srcu_t, adj_all, num, rid_t, nw_t, embbf, w_sess, gw1, gw2, p1a,
          aggws, s_xA, adj, a_local, mir_w1, mir_w2, s_xB, s_mir,
          s_hf1, s_hf2, simi_mask, w_loss);
      kF2<u16, false><<<2 * B * S, 128, 0, stream>>>(
          srcu_t, num, nw_t, embbf, w_sess, gw1 + 129 * 128, gw2 + 128,
          gw3 + 256 * 128, p1b, p3a, aggws, s_hf2 /* h_global */,
          s_xB, adj, a_local + 4 * D, mir_w1 + (long)D * D,
          mir_w2 + (long)D * D, s_mir, highway_w, s_h, s_hf1 /* x_dot */,
          w_hl);
    }
  } else {
    // Fallback: verified mono path.
    kprep4<<<384, 256, 0, stream>>>(gw1, gw3, p1a, p1b, p3a, p3b);
    if (useBF)
      kprep_emb<<<(NODES * D / 4 + 255) / 256, 256, 0, stream>>>(emb, embbf);
    if (useBF)
      k1_gather<u16><<<B * S, 128, 0, stream>>>(inputs, as0, as1, ss0, ss1,
                                                embbf, attr_w, s_h, s_hf1,
                                                s_hf2, w_mi, s_xA, s_mir);
    else
      k1_gather<float><<<B * S, 128, 0, stream>>>(inputs, as0, as1, ss0, ss1,
                                                  emb, attr_w, s_h, s_hf1,
                                                  s_hf2, w_mi, s_xA, s_mir);
    k7_simi<<<B * S, 128, 0, stream>>>(s_hf1, s_hf2, simi_mask, w_loss);
    k2_sess<<<B, 128, 0, stream>>>(inputs, item, emb, w_sess);
    if (useBF)
      kG_mono<u16><<<B * S, 128, 0, stream>>>(inputs, adj_all, num, embbf,
                                              w_sess, gw1, gw2,
                                              gw1 + 129 * 128, gw2 + 128,
                                              gw3 + 256 * 128, p1a, p1b, p3a,
                                              s_hf2 /* h_global */);
    else
      kG_mono<float><<<B * S, 128, 0, stream>>>(inputs, adj_all, num, emb,
                                                w_sess, gw1, gw2,
                                                gw1 + 129 * 128, gw2 + 128,
                                                gw3 + 256 * 128, p1a, p1b,
                                                p3a, s_hf2 /* h_global */);
    k5ab<<<B * S, 128, 0, stream>>>(s_xA, adj, a_local, mir_w1, mir_w2,
                                    s_xB, s_mir, highway_w, s_h, s_hf1, w_hl, 0);
    k5ab<<<B * S, 128, 0, stream>>>(s_xB, adj, a_local + 4 * D,
                                    mir_w1 + (long)D * D, mir_w2 + (long)D * D,
                                    s_xA, s_mir, highway_w, s_h,
                                    s_hf1 /* x_dot */, w_hl, 1);
  }

  k8_glu<<<B, 512, 0, stream>>>(s_hf2 /* h_global */, s_hf1 /* x_dot */, pos,
                                w_hl, w_mi, glu1, glu2, glu4, glu4b, w_s,
                                gate_w, w_zh);
  if (useBF)
    k9_scores<u16><<<(NSC + 63) / 64, 256, 0, stream>>>(w_zh, embbf, w_loss,
                                                        (float*)d_out);
  else
    k9_scores<float><<<(NSC + 63) / 64, 256, 0, stream>>>(w_zh, emb, w_loss,
                                                          (float*)d_out);
}